// Round 4
// baseline (6299.459 us; speedup 1.0000x reference)
//
#include <hip/hip_runtime.h>
#include <hip/hip_bf16.h>
#include <math.h>

typedef __hip_bfloat16 bf16;

#define NLANES 12
#define NHEADS 4
#define HOUT   32
#define EMBD   128
#define HIDD   64
#define GRUH   32

// Flag-dispatched load: f32 or bf16 element i of array p. Flag is block-uniform.
__device__ __forceinline__ float ldf(const void* p, int i, unsigned isf32) {
  if (isf32) return ((const float*)p)[i];
  return __bfloat162float(((const bf16*)p)[i]);
}

struct Ptrs { const void* p[24]; };

// ---------------------------------------------------------------------------
// Dtype detector (unchanged from round 3 — produced correct-finite input reads).
// ---------------------------------------------------------------------------
__global__ __launch_bounds__(64) void detect_kernel(Ptrs ptrs, unsigned* flags) {
  int i = threadIdx.x;
  if (i >= 24) return;
  const unsigned short* u = (const unsigned short*)ptrs.p[i];
  int pass = 0;
  for (int j = 0; j < 64; j++) {
    unsigned short v = u[j];
    unsigned e = (v >> 7) & 0xFF;
    if (v == 0 || v == 0x8000 || (e >= 97 && e <= 132)) pass++;
  }
  int pairsNZ = 0, evenZ = 0;
  for (int j = 0; j < 32; j++) {
    unsigned short a = u[2 * j], b = u[2 * j + 1];
    if (a || b) { pairsNZ++; if (a == 0) evenZ++; }
  }
  unsigned isf32 = (pass < 55) || (pairsNZ > 0 && evenZ * 5 >= pairsNZ * 4);
  flags[i] = isf32 ? 1u : 0u;
}

// ---------------------------------------------------------------------------
// One block (256 threads) per sample. OUTPUT IS FLOAT32 (reference dtype).
// ---------------------------------------------------------------------------
__global__ __launch_bounds__(256) void fused_kernel(
    Ptrs ptrs, const unsigned* __restrict__ flags, float* __restrict__ out)
{
  const int b = blockIdx.x;
  const int t = threadIdx.x;

  __shared__ unsigned sflag[24];
  __shared__ float sx[5][48];
  __shared__ __align__(16) float sWh[2][NHEADS][NLANES][HOUT];
  __shared__ float ses[2][NHEADS][NLANES];
  __shared__ float sed[2][NHEADS][NLANES];
  __shared__ __align__(16) float satt[2][NHEADS][NLANES][NLANES];
  __shared__ __align__(16) float scat[NLANES][256];
  __shared__ float emb5[5][EMBD];
  __shared__ float spart[2][EMBD];
  __shared__ float s_x[4][HIDD];
  __shared__ float s_gi[96], s_gh[96];
  __shared__ float s_hf[GRUH], s_hb[GRUH];

  if (t < 24) sflag[t] = flags[t];
  __syncthreads();

  const void* self_f  = ptrs.p[0];
  const void* nbr_f   = ptrs.p[1];
  const void* maskp   = ptrs.p[2];
  const void* dirsp   = ptrs.p[3];
  const void* W_coop  = ptrs.p[4];
  const void* as_coop = ptrs.p[5];
  const void* ad_coop = ptrs.p[6];
  const void* W_conf  = ptrs.p[7];
  const void* as_conf = ptrs.p[8];
  const void* ad_conf = ptrs.p[9];
  const void* W_fuse  = ptrs.p[10];
  const void* b_fuse  = ptrs.p[11];
  const void* W_proj  = ptrs.p[12];
  const void* b_proj  = ptrs.p[13];
  const void* Wih_f   = ptrs.p[14];
  const void* Whh_f   = ptrs.p[15];
  const void* bih_f   = ptrs.p[16];
  const void* bhh_f   = ptrs.p[17];
  const void* Wih_b   = ptrs.p[18];
  const void* Whh_b   = ptrs.p[19];
  const void* bih_b   = ptrs.p[20];
  const void* bhh_b   = ptrs.p[21];
  const void* W_out   = ptrs.p[22];
  const void* b_out   = ptrs.p[23];

  // ---- stage all 5 nodes' features ----
  if (t < 240) {
    int slot = t / 48, f = t - slot * 48;
    float v = (slot == 0) ? ldf(self_f, b * 48 + f, sflag[0])
                          : ldf(nbr_f, (b * 4 + (slot - 1)) * 48 + f, sflag[1]);
    sx[slot][f] = v;
  }
  __syncthreads();

  for (int slot = 0; slot < 5; slot++) {
    const float* x = sx[slot];

    // ---- Wh[s][h][l][o] = sum_f x[l][f] * W_s[h][f][o] ----
    for (int idx = t; idx < 3072; idx += 256) {
      int s  = idx / 1536;
      int r  = idx - s * 1536;
      int h  = r / 384;
      int r2 = r - h * 384;
      int l  = r2 >> 5;
      int o  = r2 & 31;
      const void* W = (s == 0) ? W_coop : W_conf;
      unsigned fw   = (s == 0) ? sflag[4] : sflag[7];
      int base = h * 128 + o;
      sWh[s][h][l][o] = x[l*4+0]*ldf(W, base,      fw)
                      + x[l*4+1]*ldf(W, base + 32, fw)
                      + x[l*4+2]*ldf(W, base + 64, fw)
                      + x[l*4+3]*ldf(W, base + 96, fw);
    }
    __syncthreads();

    // ---- attention logits ----
    if (t < 96) {
      int s = t / 48;
      int r = t - s * 48;
      int h = r / 12;
      int l = r - h * 12;
      const void* as_ = (s == 0) ? as_coop : as_conf;
      const void* ad_ = (s == 0) ? ad_coop : ad_conf;
      unsigned fs = (s == 0) ? sflag[5] : sflag[8];
      unsigned fd = (s == 0) ? sflag[6] : sflag[9];
      const float* wh = sWh[s][h][l];
      float es = 0.f, ed = 0.f;
#pragma unroll
      for (int o = 0; o < 32; o++) {
        es += wh[o] * ldf(as_, h * 32 + o, fs);
        ed += wh[o] * ldf(ad_, h * 32 + o, fd);
      }
      ses[s][h][l] = es;
      sed[s][h][l] = ed;
    }
    __syncthreads();

    // ---- masked softmax (coop: own 3-block; conf: the other 9 lanes) ----
    if (t < 96) {
      int s = t / 48;
      int r = t - s * 48;
      int h = r / 12;
      int i = r - h * 12;
      int blk = i / 3;
      float esi = ses[s][h][i];
      float ev[12];
      float m = -1e30f;
#pragma unroll
      for (int j = 0; j < 12; j++) {
        bool allowed = (s == 0) ? ((j / 3) == blk) : ((j / 3) != blk);
        float e = esi + sed[s][h][j];
        e = e > 0.f ? e : 0.2f * e;            // leaky_relu(0.2)
        if (!allowed) e = -1e30f;
        ev[j] = e;
        m = fmaxf(m, e);
      }
      float sum = 0.f;
#pragma unroll
      for (int j = 0; j < 12; j++) {
        float a = (ev[j] > -1e29f) ? __expf(ev[j] - m) : 0.f;
        ev[j] = a;
        sum += a;
      }
      float inv = 1.f / sum;
#pragma unroll
      for (int j = 0; j < 12; j++) satt[s][h][i][j] = ev[j] * inv;
    }
    __syncthreads();

    // ---- att @ Wh, ELU, into concat buffer ----
    for (int idx = t; idx < 3072; idx += 256) {
      int s  = idx / 1536;
      int r  = idx - s * 1536;
      int i  = r >> 7;
      int co = r & 127;
      int h  = co >> 5;
      int o  = co & 31;
      const float* att = satt[s][h][i];
      float acc = 0.f;
#pragma unroll
      for (int j = 0; j < 12; j++) acc += att[j] * sWh[s][h][j][o];
      acc = acc > 0.f ? acc : (__expf(acc) - 1.f);   // ELU
      scat[i][s * 128 + co] = acc;
    }
    __syncthreads();

    // ---- fuse GEMM: (12 x 256) @ (256 x 128), ELU, partial lane-sum ----
    {
      const int c  = t & 127;
      const int lg = t >> 7;
      unsigned fWf = sflag[10];
      float acc[6];
#pragma unroll
      for (int li = 0; li < 6; li++) acc[li] = 0.f;
      for (int k = 0; k < 256; k += 4) {
        float w0 = ldf(W_fuse, (k + 0) * 128 + c, fWf);
        float w1 = ldf(W_fuse, (k + 1) * 128 + c, fWf);
        float w2 = ldf(W_fuse, (k + 2) * 128 + c, fWf);
        float w3 = ldf(W_fuse, (k + 3) * 128 + c, fWf);
#pragma unroll
        for (int li = 0; li < 6; li++) {
          const float4 cv = *(const float4*)&scat[lg * 6 + li][k];
          acc[li] += cv.x * w0 + cv.y * w1 + cv.z * w2 + cv.w * w3;
        }
      }
      float bc = ldf(b_fuse, c, sflag[11]);
      float msum = 0.f;
#pragma unroll
      for (int li = 0; li < 6; li++) {
        float v = acc[li] + bc;
        v = v > 0.f ? v : (__expf(v) - 1.f);   // ELU
        msum += v;
      }
      spart[lg][c] = msum;
    }
    __syncthreads();
    if (t < 128) emb5[slot][t] = (spart[0][t] + spart[1][t]) * (1.f / 12.f);
    __syncthreads();
  }

  // ---- proj ----
  {
    int k = t >> 6;
    int j = t & 63;
    if (k < 4) {
      const float* er = emb5[1 + k];
      float acc = ldf(b_proj, j, sflag[13]);
      for (int i = 0; i < 128; i++) acc += er[i] * ldf(W_proj, i * 64 + j, sflag[12]);
      acc += ldf(dirsp, b * 4 + k, sflag[3]) * ldf(W_proj, 128 * 64 + j, sflag[12]);
      acc = fmaxf(acc, 0.f) * ldf(maskp, b * 4 + k, sflag[2]);
      s_x[k][j] = acc;
    }
  }
  if (t < GRUH) { s_hf[t] = 0.f; s_hb[t] = 0.f; }
  __syncthreads();

  // ---- forward GRU ----
  for (int k = 0; k < 4; k++) {
    if (t < 96) {
      float gi = ldf(bih_f, t, sflag[16]);
      float gh = ldf(bhh_f, t, sflag[17]);
      for (int i = 0; i < HIDD; i++) gi += s_x[k][i] * ldf(Wih_f, i * 96 + t, sflag[14]);
      for (int i = 0; i < GRUH; i++) gh += s_hf[i] * ldf(Whh_f, i * 96 + t, sflag[15]);
      s_gi[t] = gi; s_gh[t] = gh;
    }
    __syncthreads();
    if (t < GRUH) {
      float r  = 1.f / (1.f + __expf(-(s_gi[t] + s_gh[t])));
      float z  = 1.f / (1.f + __expf(-(s_gi[32 + t] + s_gh[32 + t])));
      float nn = tanhf(s_gi[64 + t] + r * s_gh[64 + t]);
      s_hf[t] = (1.f - z) * nn + z * s_hf[t];
    }
    __syncthreads();
  }
  // ---- backward GRU ----
  for (int k = 3; k >= 0; k--) {
    if (t < 96) {
      float gi = ldf(bih_b, t, sflag[20]);
      float gh = ldf(bhh_b, t, sflag[21]);
      for (int i = 0; i < HIDD; i++) gi += s_x[k][i] * ldf(Wih_b, i * 96 + t, sflag[18]);
      for (int i = 0; i < GRUH; i++) gh += s_hb[i] * ldf(Whh_b, i * 96 + t, sflag[19]);
      s_gi[t] = gi; s_gh[t] = gh;
    }
    __syncthreads();
    if (t < GRUH) {
      float r  = 1.f / (1.f + __expf(-(s_gi[t] + s_gh[t])));
      float z  = 1.f / (1.f + __expf(-(s_gi[32 + t] + s_gh[32 + t])));
      float nn = tanhf(s_gi[64 + t] + r * s_gh[64 + t]);
      s_hb[t] = (1.f - z) * nn + z * s_hb[t];
    }
    __syncthreads();
  }

  // ---- output head + self_emb passthrough (FLOAT32 out) ----
  if (t < 64) {
    float acc = ldf(b_out, t, sflag[23]);
    for (int i = 0; i < 128; i++) acc += emb5[0][i] * ldf(W_out, i * 64 + t, sflag[22]);
    for (int i = 0; i < 32;  i++) acc += s_hf[i] * ldf(W_out, (128 + i) * 64 + t, sflag[22]);
    for (int i = 0; i < 32;  i++) acc += s_hb[i] * ldf(W_out, (160 + i) * 64 + t, sflag[22]);
    acc = fmaxf(acc, 0.f);
    out[b * 192 + 128 + t] = acc;
  }
  if (t < 128) out[b * 192 + t] = emb5[0][t];
}

extern "C" void kernel_launch(void* const* d_in, const int* in_sizes, int n_in,
                              void* d_out, int out_size, void* d_ws, size_t ws_size,
                              hipStream_t stream) {
  Ptrs ptrs;
  for (int i = 0; i < 24; i++) ptrs.p[i] = d_in[i];

  unsigned* flags = (unsigned*)d_ws;
  const int B = in_sizes[0] / 48;   // 8192

  detect_kernel<<<1, 64, 0, stream>>>(ptrs, flags);
  fused_kernel<<<B, 256, 0, stream>>>(ptrs, flags, (float*)d_out);
}

// Round 5
// 1385.165 us; speedup vs baseline: 4.5478x; 4.5478x over previous
//
#include <hip/hip_runtime.h>
#include <math.h>

// All inputs verified f32-in-memory (bf16-rounded values; round-4 detector
// evidence: every nonzero array classified f32, output passed at 1.95e-3).

// ---------------------------------------------------------------------------
// Kernel 1: per-node GAT (both streams) + fuse GEMM + ELU + lane-mean.
// One 128-thread block per node n in [0, B*5). LDS ~30.5 KB -> 5 blocks/CU.
// ---------------------------------------------------------------------------
__global__ __launch_bounds__(128) void gat_fuse_kernel(
    const float* __restrict__ self_f,   // (B,48)
    const float* __restrict__ nbr_f,    // (B,4,48)
    const float* __restrict__ W_coop,   // (4,4,32)
    const float* __restrict__ as_coop,  // (4,32)
    const float* __restrict__ ad_coop,  // (4,32)
    const float* __restrict__ W_conf,
    const float* __restrict__ as_conf,
    const float* __restrict__ ad_conf,
    const float* __restrict__ W_fuse,   // (256,128)
    const float* __restrict__ b_fuse,   // (128,)
    float* __restrict__ emb)            // (B,5,128)
{
  const int n = blockIdx.x;
  const int t = threadIdx.x;
  const int b = n / 5;
  const int slot = n - b * 5;

  __shared__ float sx[48];
  __shared__ float sWh[2][4][12][33];     // +1 pad: kills 64-way bank conflict
  __shared__ float ses[2][4][12];
  __shared__ float sed[2][4][12];
  __shared__ float satt[2][4][12][13];    // +1 pad
  __shared__ __align__(16) float scat[12][256];

  if (t < 48)
    sx[t] = (slot == 0) ? self_f[b * 48 + t]
                        : nbr_f[(b * 4 + slot - 1) * 48 + t];
  __syncthreads();

  // ---- Wh[s][h][l][o] = sum_f x[l][f] * W_s[h][f][o]  (3072 vals, 24/thr)
  for (int idx = t; idx < 3072; idx += 128) {
    int s  = idx / 1536;
    int r  = idx - s * 1536;
    int h  = r / 384;
    int r2 = r - h * 384;
    int l  = r2 >> 5;
    int o  = r2 & 31;
    const float* W = (s ? W_conf : W_coop) + h * 128 + o;
    sWh[s][h][l][o] = sx[l*4+0]*W[0]  + sx[l*4+1]*W[32]
                    + sx[l*4+2]*W[64] + sx[l*4+3]*W[96];
  }
  __syncthreads();

  // ---- attention logits (96 triples) ----
  if (t < 96) {
    int s = t / 48;
    int r = t - s * 48;
    int h = r / 12;
    int l = r - h * 12;
    const float* as_ = (s ? as_conf : as_coop) + h * 32;
    const float* ad_ = (s ? ad_conf : ad_coop) + h * 32;
    const float* wh = sWh[s][h][l];
    float es = 0.f, ed = 0.f;
#pragma unroll
    for (int o = 0; o < 32; o++) { es += wh[o]*as_[o]; ed += wh[o]*ad_[o]; }
    ses[s][h][l] = es;
    sed[s][h][l] = ed;
  }
  __syncthreads();

  // ---- masked softmax (coop: own 3-block; conf: other 9 lanes) ----
  if (t < 96) {
    int s = t / 48;
    int r = t - s * 48;
    int h = r / 12;
    int i = r - h * 12;
    int blk = i / 3;
    float esi = ses[s][h][i];
    float ev[12];
    float m = -1e30f;
#pragma unroll
    for (int j = 0; j < 12; j++) {
      bool allowed = (s == 0) ? ((j / 3) == blk) : ((j / 3) != blk);
      float e = esi + sed[s][h][j];
      e = e > 0.f ? e : 0.2f * e;            // leaky_relu(0.2)
      if (!allowed) e = -1e30f;
      ev[j] = e;
      m = fmaxf(m, e);
    }
    float sum = 0.f;
#pragma unroll
    for (int j = 0; j < 12; j++) {
      float a = (ev[j] > -1e29f) ? __expf(ev[j] - m) : 0.f;
      ev[j] = a;
      sum += a;
    }
    float inv = 1.f / sum;
#pragma unroll
    for (int j = 0; j < 12; j++) satt[s][h][i][j] = ev[j] * inv;
  }
  __syncthreads();

  // ---- att @ Wh, ELU, into concat buffer (3072 vals, 24/thr) ----
  for (int idx = t; idx < 3072; idx += 128) {
    int s  = idx / 1536;
    int r  = idx - s * 1536;
    int i  = r >> 7;
    int co = r & 127;
    int h  = co >> 5;
    int o  = co & 31;
    const float* att = satt[s][h][i];
    float acc = 0.f;
#pragma unroll
    for (int j = 0; j < 12; j++) acc += att[j] * sWh[s][h][j][o];
    acc = acc > 0.f ? acc : (__expf(acc) - 1.f);   // ELU
    scat[i][s * 128 + co] = acc;
  }
  __syncthreads();

  // ---- fuse GEMM: (12x256)@(256x128) + ELU + lane-mean. thread = col c ----
  {
    const int c = t;
    float acc[12];
#pragma unroll
    for (int l = 0; l < 12; l++) acc[l] = 0.f;
    for (int k = 0; k < 256; k += 4) {
      float w0 = W_fuse[(k + 0) * 128 + c];
      float w1 = W_fuse[(k + 1) * 128 + c];
      float w2 = W_fuse[(k + 2) * 128 + c];
      float w3 = W_fuse[(k + 3) * 128 + c];
#pragma unroll
      for (int l = 0; l < 12; l++) {
        const float4 cv = *(const float4*)&scat[l][k];  // broadcast read
        acc[l] += cv.x * w0 + cv.y * w1 + cv.z * w2 + cv.w * w3;
      }
    }
    float bc = b_fuse[c];
    float msum = 0.f;
#pragma unroll
    for (int l = 0; l < 12; l++) {
      float v = acc[l] + bc;
      v = v > 0.f ? v : (__expf(v) - 1.f);   // ELU
      msum += v;
    }
    emb[n * 128 + c] = msum * (1.f / 12.f);
  }
}

// ---------------------------------------------------------------------------
// Kernel 2: per-sample head. One 64-thread block (single wave) per sample.
// Lanes 0-31 run the forward GRU, lanes 32-63 the backward GRU concurrently.
// ---------------------------------------------------------------------------
__global__ __launch_bounds__(64) void head_kernel(
    const float* __restrict__ emb,      // (B,5,128)
    const float* __restrict__ maskp,    // (B,4)
    const float* __restrict__ dirsp,    // (B,4)
    const float* __restrict__ W_proj,   // (129,64)
    const float* __restrict__ b_proj,   // (64,)
    const float* __restrict__ Wih_f, const float* __restrict__ Whh_f,
    const float* __restrict__ bih_f, const float* __restrict__ bhh_f,
    const float* __restrict__ Wih_b, const float* __restrict__ Whh_b,
    const float* __restrict__ bih_b, const float* __restrict__ bhh_b,
    const float* __restrict__ W_out,    // (192,64)
    const float* __restrict__ b_out,    // (64,)
    float* __restrict__ out)            // (B,192)
{
  const int b = blockIdx.x;
  const int t = threadIdx.x;   // 0..63
  __shared__ float s_x[4][64];
  __shared__ float s_h[2][32];

  // ---- proj: 4 neighbors x 64 cols, register-blocked over k ----
  {
    float a0 = b_proj[t], a1 = a0, a2 = a0, a3 = a0;
    const float* e1 = emb + (b * 5 + 1) * 128;
    const float* e2 = e1 + 128;
    const float* e3 = e2 + 128;
    const float* e4 = e3 + 128;
    for (int i = 0; i < 128; i++) {
      float w = W_proj[i * 64 + t];
      a0 += e1[i] * w;
      a1 += e2[i] * w;
      a2 += e3[i] * w;
      a3 += e4[i] * w;
    }
    float wl = W_proj[128 * 64 + t];
    a0 = fmaxf(a0 + dirsp[b*4+0] * wl, 0.f) * maskp[b*4+0];
    a1 = fmaxf(a1 + dirsp[b*4+1] * wl, 0.f) * maskp[b*4+1];
    a2 = fmaxf(a2 + dirsp[b*4+2] * wl, 0.f) * maskp[b*4+2];
    a3 = fmaxf(a3 + dirsp[b*4+3] * wl, 0.f) * maskp[b*4+3];
    s_x[0][t] = a0; s_x[1][t] = a1; s_x[2][t] = a2; s_x[3][t] = a3;
  }
  s_h[t >> 5][t & 31] = 0.f;
  __syncthreads();

  // ---- bidirectional GRU, both directions in one wave ----
  const int dir = t >> 5;       // 0 = forward, 1 = backward
  const int u   = t & 31;       // hidden unit
  const float* Wih = dir ? Wih_b : Wih_f;
  const float* Whh = dir ? Whh_b : Whh_f;
  const float* bih = dir ? bih_b : bih_f;
  const float* bhh = dir ? bhh_b : bhh_f;

  for (int step = 0; step < 4; step++) {
    const int k = dir ? (3 - step) : step;
    float gir = bih[u],      ghr = bhh[u];
    float giz = bih[32 + u], ghz = bhh[32 + u];
    float gin = bih[64 + u], ghn = bhh[64 + u];
    for (int i = 0; i < 64; i++) {
      float xv = s_x[k][i];
      const float* wr = Wih + i * 96 + u;
      gir += xv * wr[0];
      giz += xv * wr[32];
      gin += xv * wr[64];
    }
    for (int i = 0; i < 32; i++) {
      float hv = s_h[dir][i];
      const float* wr = Whh + i * 96 + u;
      ghr += hv * wr[0];
      ghz += hv * wr[32];
      ghn += hv * wr[64];
    }
    float r  = 1.f / (1.f + __expf(-(gir + ghr)));
    float z  = 1.f / (1.f + __expf(-(giz + ghz)));
    float nn = tanhf(gin + r * ghn);
    float hnew = (1.f - z) * nn + z * s_h[dir][u];
    __syncthreads();
    s_h[dir][u] = hnew;
    __syncthreads();
  }

  // ---- output head + self_emb passthrough ----
  {
    const float* e0 = emb + b * 5 * 128;
    float acc = b_out[t];
    for (int i = 0; i < 128; i++) acc += e0[i] * W_out[i * 64 + t];
#pragma unroll
    for (int i = 0; i < 32; i++)  acc += s_h[0][i] * W_out[(128 + i) * 64 + t];
#pragma unroll
    for (int i = 0; i < 32; i++)  acc += s_h[1][i] * W_out[(160 + i) * 64 + t];
    out[b * 192 + 128 + t] = fmaxf(acc, 0.f);
    out[b * 192 + t]       = e0[t];
    out[b * 192 + 64 + t]  = e0[64 + t];
  }
}

// ---------------------------------------------------------------------------
extern "C" void kernel_launch(void* const* d_in, const int* in_sizes, int n_in,
                              void* d_out, int out_size, void* d_ws, size_t ws_size,
                              hipStream_t stream) {
  const float* self_f  = (const float*)d_in[0];
  const float* nbr_f   = (const float*)d_in[1];
  const float* maskp   = (const float*)d_in[2];
  const float* dirsp   = (const float*)d_in[3];
  const float* W_coop  = (const float*)d_in[4];
  const float* as_coop = (const float*)d_in[5];
  const float* ad_coop = (const float*)d_in[6];
  const float* W_conf  = (const float*)d_in[7];
  const float* as_conf = (const float*)d_in[8];
  const float* ad_conf = (const float*)d_in[9];
  const float* W_fuse  = (const float*)d_in[10];
  const float* b_fuse  = (const float*)d_in[11];
  const float* W_proj  = (const float*)d_in[12];
  const float* b_proj  = (const float*)d_in[13];
  const float* Wih_f   = (const float*)d_in[14];
  const float* Whh_f   = (const float*)d_in[15];
  const float* bih_f   = (const float*)d_in[16];
  const float* bhh_f   = (const float*)d_in[17];
  const float* Wih_b   = (const float*)d_in[18];
  const float* Whh_b   = (const float*)d_in[19];
  const float* bih_b   = (const float*)d_in[20];
  const float* bhh_b   = (const float*)d_in[21];
  const float* W_out   = (const float*)d_in[22];
  const float* b_out   = (const float*)d_in[23];

  const int B = in_sizes[0] / 48;   // 8192
  float* emb = (float*)d_ws;        // (B,5,128) f32 = 20.97 MB

  gat_fuse_kernel<<<B * 5, 128, 0, stream>>>(
      self_f, nbr_f, W_coop, as_coop, ad_coop,
      W_conf, as_conf, ad_conf, W_fuse, b_fuse, emb);

  head_kernel<<<B, 64, 0, stream>>>(
      emb, maskp, dirsp, W_proj, b_proj,
      Wih_f, Whh_f, bih_f, bhh_f,
      Wih_b, Whh_b, bih_b, bhh_b,
      W_out, b_out, (float*)d_out);
}

// Round 6
// 643.869 us; speedup vs baseline: 9.7838x; 2.1513x over previous
//
#include <hip/hip_runtime.h>
#include <math.h>

typedef short short8 __attribute__((ext_vector_type(8)));
typedef float f32x4  __attribute__((ext_vector_type(4)));

// f32 -> bf16 bits, round-to-nearest-even (inputs are finite; no NaN handling)
__device__ __forceinline__ unsigned short f2b(float f) {
  union { float f; unsigned int u; } x; x.f = f;
  return (unsigned short)((x.u + 0x7FFFu + ((x.u >> 16) & 1u)) >> 16);
}
// bf16 bits -> f32 (exact)
__device__ __forceinline__ float b2f_u(unsigned short u) {
  union { unsigned int u; float f; } x; x.u = ((unsigned int)u) << 16;
  return x.f;
}

// ---------------------------------------------------------------------------
// Prepack W_fuse (256x128 f32, values bf16-clean -> exact cvt) into MFMA
// B-fragment layout for 16x16x32 bf16:
//   frag[((kb*8 + tile)*64 + lane)*8 + j] = bf16(W_fuse[(kb*32+(lane>>4)*8+j)*128 + tile*16+(lane&15)])
// ---------------------------------------------------------------------------
__global__ __launch_bounds__(256) void prepack_kernel(
    const float* __restrict__ Wf, unsigned short* __restrict__ frag) {
  int e = blockIdx.x * 256 + threadIdx.x;   // 0..4095 == (kb*8+tile)*64+lane
  if (e >= 4096) return;
  int kb = e >> 9, tile = (e >> 6) & 7, lane = e & 63;
  int n = tile * 16 + (lane & 15);
  int kbase = kb * 32 + (lane >> 4) * 8;
  unsigned short tmp[8];
#pragma unroll
  for (int j = 0; j < 8; j++) tmp[j] = f2b(Wf[(kbase + j) * 128 + n]);
  short8* dst = (short8*)(frag + e * 8);
  *dst = *(short8*)tmp;
}

// ---------------------------------------------------------------------------
// Kernel 1: per-node GAT (both streams) + MFMA fuse GEMM + ELU + lane-mean.
// One 128-thread block (2 waves) per node. LDS ~23.3 KB -> 6 blocks/CU.
// ---------------------------------------------------------------------------
__global__ __launch_bounds__(128) void gat_fuse_kernel(
    const float* __restrict__ self_f,   // (B,48)
    const float* __restrict__ nbr_f,    // (B,4,48)
    const float* __restrict__ W_coop,   // (4,4,32)
    const float* __restrict__ as_coop,  // (4,32)
    const float* __restrict__ ad_coop,  // (4,32)
    const float* __restrict__ W_conf,
    const float* __restrict__ as_conf,
    const float* __restrict__ ad_conf,
    const unsigned short* __restrict__ fragB,  // prepacked W_fuse (bf16 frags)
    const float* __restrict__ b_fuse,   // (128,)
    float* __restrict__ emb)            // (B,5,128)
{
  const int n = blockIdx.x;
  const int t = threadIdx.x;
  const int b = n / 5;
  const int slot = n - b * 5;

  __shared__ float sx[48];
  __shared__ unsigned short sWhb[2][4][12][33];   // bf16 Wh, +1 pad
  __shared__ float ses[2][4][12];
  __shared__ float sed[2][4][12];
  __shared__ float satt[2][4][12][13];            // +1 pad
  __shared__ __align__(16) unsigned short scatb[16][264]; // bf16 A, pad+8
  __shared__ float sbias[128];
  __shared__ float red[2][4][64];

  // stage features + bias; zero dead A rows 12-15 (M-padding for MFMA)
  if (t < 48)
    sx[t] = (slot == 0) ? self_f[b * 48 + t]
                        : nbr_f[(b * 4 + slot - 1) * 48 + t];
  sbias[t] = b_fuse[t];
  {
    unsigned int* z = (unsigned int*)scatb;       // dwords; rows 12-15 = [1584,2112)
    for (int i = t; i < 528; i += 128) z[1584 + i] = 0u;
  }
  __syncthreads();

  // ---- Wh[s][h][l][o] = sum_f x[l][f] * W_s[h][f][o]  (3072 vals) ----
  for (int idx = t; idx < 3072; idx += 128) {
    int s  = idx / 1536;
    int r  = idx - s * 1536;
    int h  = r / 384;
    int r2 = r - h * 384;
    int l  = r2 >> 5;
    int o  = r2 & 31;
    const float* W = (s ? W_conf : W_coop) + h * 128 + o;
    float acc = sx[l*4+0]*W[0]  + sx[l*4+1]*W[32]
              + sx[l*4+2]*W[64] + sx[l*4+3]*W[96];
    sWhb[s][h][l][o] = f2b(acc);
  }
  __syncthreads();

  // ---- attention logits ----
  if (t < 96) {
    int s = t / 48;
    int r = t - s * 48;
    int h = r / 12;
    int l = r - h * 12;
    const float* as_ = (s ? as_conf : as_coop) + h * 32;
    const float* ad_ = (s ? ad_conf : ad_coop) + h * 32;
    const unsigned short* wh = sWhb[s][h][l];
    float es = 0.f, ed = 0.f;
#pragma unroll
    for (int o = 0; o < 32; o++) {
      float w = b2f_u(wh[o]);
      es += w * as_[o]; ed += w * ad_[o];
    }
    ses[s][h][l] = es;
    sed[s][h][l] = ed;
  }
  __syncthreads();

  // ---- masked softmax ----
  if (t < 96) {
    int s = t / 48;
    int r = t - s * 48;
    int h = r / 12;
    int i = r - h * 12;
    int blk = i / 3;
    float esi = ses[s][h][i];
    float ev[12];
    float m = -1e30f;
#pragma unroll
    for (int j = 0; j < 12; j++) {
      bool allowed = (s == 0) ? ((j / 3) == blk) : ((j / 3) != blk);
      float e = esi + sed[s][h][j];
      e = e > 0.f ? e : 0.2f * e;
      if (!allowed) e = -1e30f;
      ev[j] = e;
      m = fmaxf(m, e);
    }
    float sum = 0.f;
#pragma unroll
    for (int j = 0; j < 12; j++) {
      float a = (ev[j] > -1e29f) ? __expf(ev[j] - m) : 0.f;
      ev[j] = a;
      sum += a;
    }
    float inv = 1.f / sum;
#pragma unroll
    for (int j = 0; j < 12; j++) satt[s][h][i][j] = ev[j] * inv;
  }
  __syncthreads();

  // ---- att @ Wh, ELU -> scat (bf16, A-operand layout scat[m][k]) ----
  for (int idx = t; idx < 3072; idx += 128) {
    int s  = idx / 1536;
    int r  = idx - s * 1536;
    int i  = r >> 7;
    int co = r & 127;
    int h  = co >> 5;
    int o  = co & 31;
    const float* att = satt[s][h][i];
    float acc = 0.f;
#pragma unroll
    for (int j = 0; j < 12; j++) acc += att[j] * b2f_u(sWhb[s][h][j][o]);
    acc = acc > 0.f ? acc : (__expf(acc) - 1.f);
    scatb[i][s * 128 + co] = f2b(acc);
  }
  __syncthreads();

  // ---- fuse GEMM via MFMA: C(16x128) = A(16x256) @ W(256x128) ----
  // wave w covers cols [w*64, w*64+64); 4 N-tiles of 16 per wave.
  {
    const int w = t >> 6, lane = t & 63;
    const int q = lane >> 4, c15 = lane & 15, m16 = lane & 15;
    f32x4 acc0 = {0.f,0.f,0.f,0.f}, acc1 = acc0, acc2 = acc0, acc3 = acc0;
    const int tbase = w * 4;
#pragma unroll
    for (int kb = 0; kb < 8; kb++) {
      short8 a = *(const short8*)&scatb[m16][kb * 32 + (q << 3)];
      const short8* bf = (const short8*)(fragB) + (kb * 8 + tbase) * 64 + lane;
      acc0 = __builtin_amdgcn_mfma_f32_16x16x32_bf16(a, bf[0],   acc0, 0, 0, 0);
      acc1 = __builtin_amdgcn_mfma_f32_16x16x32_bf16(a, bf[64],  acc1, 0, 0, 0);
      acc2 = __builtin_amdgcn_mfma_f32_16x16x32_bf16(a, bf[128], acc2, 0, 0, 0);
      acc3 = __builtin_amdgcn_mfma_f32_16x16x32_bf16(a, bf[192], acc3, 0, 0, 0);
    }
    // epilogue: bias + ELU per element, partial sum over this quad's rows
    // C layout: col = lane&15, row = q*4 + reg. Rows >= 12 (q==3) are padding.
#pragma unroll
    for (int tt = 0; tt < 4; tt++) {
      f32x4 a4 = (tt == 0) ? acc0 : (tt == 1) ? acc1 : (tt == 2) ? acc2 : acc3;
      float p = 0.f;
      if (q < 3) {
        float bcol = sbias[w * 64 + tt * 16 + c15];
#pragma unroll
        for (int r = 0; r < 4; r++) {
          float v = a4[r] + bcol;
          v = v > 0.f ? v : (__expf(v) - 1.f);
          p += v;
        }
      }
      red[w][q][tt * 16 + c15] = p;
    }
  }
  __syncthreads();
  {
    const int w = t >> 6, lane = t & 63;
    float s = red[w][0][lane] + red[w][1][lane] + red[w][2][lane];
    emb[n * 128 + w * 64 + lane] = s * (1.f / 12.f);
  }
}

// ---------------------------------------------------------------------------
// Kernel 2: per-sample head. One 64-thread block (single wave) per sample.
// Lanes 0-31 forward GRU, lanes 32-63 backward GRU concurrently.
// ---------------------------------------------------------------------------
__global__ __launch_bounds__(64) void head_kernel(
    const float* __restrict__ emb,      // (B,5,128)
    const float* __restrict__ maskp,    // (B,4)
    const float* __restrict__ dirsp,    // (B,4)
    const float* __restrict__ W_proj,   // (129,64)
    const float* __restrict__ b_proj,   // (64,)
    const float* __restrict__ Wih_f, const float* __restrict__ Whh_f,
    const float* __restrict__ bih_f, const float* __restrict__ bhh_f,
    const float* __restrict__ Wih_b, const float* __restrict__ Whh_b,
    const float* __restrict__ bih_b, const float* __restrict__ bhh_b,
    const float* __restrict__ W_out,    // (192,64)
    const float* __restrict__ b_out,    // (64,)
    float* __restrict__ out)            // (B,192)
{
  const int b = blockIdx.x;
  const int t = threadIdx.x;   // 0..63
  __shared__ float s_x[4][64];
  __shared__ float s_h[2][32];

  {
    float a0 = b_proj[t], a1 = a0, a2 = a0, a3 = a0;
    const float* e1 = emb + (b * 5 + 1) * 128;
    const float* e2 = e1 + 128;
    const float* e3 = e2 + 128;
    const float* e4 = e3 + 128;
    for (int i = 0; i < 128; i++) {
      float w = W_proj[i * 64 + t];
      a0 += e1[i] * w;
      a1 += e2[i] * w;
      a2 += e3[i] * w;
      a3 += e4[i] * w;
    }
    float wl = W_proj[128 * 64 + t];
    a0 = fmaxf(a0 + dirsp[b*4+0] * wl, 0.f) * maskp[b*4+0];
    a1 = fmaxf(a1 + dirsp[b*4+1] * wl, 0.f) * maskp[b*4+1];
    a2 = fmaxf(a2 + dirsp[b*4+2] * wl, 0.f) * maskp[b*4+2];
    a3 = fmaxf(a3 + dirsp[b*4+3] * wl, 0.f) * maskp[b*4+3];
    s_x[0][t] = a0; s_x[1][t] = a1; s_x[2][t] = a2; s_x[3][t] = a3;
  }
  s_h[t >> 5][t & 31] = 0.f;
  __syncthreads();

  const int dir = t >> 5;
  const int u   = t & 31;
  const float* Wih = dir ? Wih_b : Wih_f;
  const float* Whh = dir ? Whh_b : Whh_f;
  const float* bih = dir ? bih_b : bih_f;
  const float* bhh = dir ? bhh_b : bhh_f;

  for (int step = 0; step < 4; step++) {
    const int k = dir ? (3 - step) : step;
    float gir = bih[u],      ghr = bhh[u];
    float giz = bih[32 + u], ghz = bhh[32 + u];
    float gin = bih[64 + u], ghn = bhh[64 + u];
    for (int i = 0; i < 64; i++) {
      float xv = s_x[k][i];
      const float* wr = Wih + i * 96 + u;
      gir += xv * wr[0];
      giz += xv * wr[32];
      gin += xv * wr[64];
    }
    for (int i = 0; i < 32; i++) {
      float hv = s_h[dir][i];
      const float* wr = Whh + i * 96 + u;
      ghr += hv * wr[0];
      ghz += hv * wr[32];
      ghn += hv * wr[64];
    }
    float r  = 1.f / (1.f + __expf(-(gir + ghr)));
    float z  = 1.f / (1.f + __expf(-(giz + ghz)));
    float nn = tanhf(gin + r * ghn);
    float hnew = (1.f - z) * nn + z * s_h[dir][u];
    __syncthreads();
    s_h[dir][u] = hnew;
    __syncthreads();
  }

  {
    const float* e0 = emb + b * 5 * 128;
    float acc = b_out[t];
    for (int i = 0; i < 128; i++) acc += e0[i] * W_out[i * 64 + t];
#pragma unroll
    for (int i = 0; i < 32; i++)  acc += s_h[0][i] * W_out[(128 + i) * 64 + t];
#pragma unroll
    for (int i = 0; i < 32; i++)  acc += s_h[1][i] * W_out[(160 + i) * 64 + t];
    out[b * 192 + 128 + t] = fmaxf(acc, 0.f);
    out[b * 192 + t]       = e0[t];
    out[b * 192 + 64 + t]  = e0[64 + t];
  }
}

// ---------------------------------------------------------------------------
extern "C" void kernel_launch(void* const* d_in, const int* in_sizes, int n_in,
                              void* d_out, int out_size, void* d_ws, size_t ws_size,
                              hipStream_t stream) {
  const float* self_f  = (const float*)d_in[0];
  const float* nbr_f   = (const float*)d_in[1];
  const float* maskp   = (const float*)d_in[2];
  const float* dirsp   = (const float*)d_in[3];
  const float* W_coop  = (const float*)d_in[4];
  const float* as_coop = (const float*)d_in[5];
  const float* ad_coop = (const float*)d_in[6];
  const float* W_conf  = (const float*)d_in[7];
  const float* as_conf = (const float*)d_in[8];
  const float* ad_conf = (const float*)d_in[9];
  const float* W_fuse  = (const float*)d_in[10];
  const float* b_fuse  = (const float*)d_in[11];
  const float* W_proj  = (const float*)d_in[12];
  const float* b_proj  = (const float*)d_in[13];
  const float* Wih_f   = (const float*)d_in[14];
  const float* Whh_f   = (const float*)d_in[15];
  const float* bih_f   = (const float*)d_in[16];
  const float* bhh_f   = (const float*)d_in[17];
  const float* Wih_b   = (const float*)d_in[18];
  const float* Whh_b   = (const float*)d_in[19];
  const float* bih_b   = (const float*)d_in[20];
  const float* bhh_b   = (const float*)d_in[21];
  const float* W_out   = (const float*)d_in[22];
  const float* b_out   = (const float*)d_in[23];

  const int B = in_sizes[0] / 48;   // 8192
  unsigned short* fragB = (unsigned short*)d_ws;              // 64 KB
  float* emb = (float*)((char*)d_ws + 65536);                 // (B,5,128) f32

  prepack_kernel<<<16, 256, 0, stream>>>(W_fuse, fragB);

  gat_fuse_kernel<<<B * 5, 128, 0, stream>>>(
      self_f, nbr_f, W_coop, as_coop, ad_coop,
      W_conf, as_conf, ad_conf, fragB, b_fuse, emb);

  head_kernel<<<B, 64, 0, stream>>>(
      emb, maskp, dirsp, W_proj, b_proj,
      Wih_f, Whh_f, bih_f, bhh_f,
      Wih_b, Whh_b, bih_b, bhh_b,
      W_out, b_out, (float*)d_out);
}

// Round 7
// 538.948 us; speedup vs baseline: 11.6884x; 1.1947x over previous
//
#include <hip/hip_runtime.h>
#include <math.h>

typedef short short8 __attribute__((ext_vector_type(8)));
typedef float f32x4  __attribute__((ext_vector_type(4)));
typedef unsigned short u16x4 __attribute__((ext_vector_type(4)));

// f32 -> bf16 bits, round-to-nearest-even (finite inputs only)
__device__ __forceinline__ unsigned short f2b(float f) {
  union { float f; unsigned int u; } x; x.f = f;
  return (unsigned short)((x.u + 0x7FFFu + ((x.u >> 16) & 1u)) >> 16);
}
__device__ __forceinline__ float b2f_u(unsigned short u) {
  union { unsigned int u; float f; } x; x.u = ((unsigned int)u) << 16;
  return x.f;
}

// ---------------------------------------------------------------------------
// Prepack:
//  e in [0,4096): W_fuse (256x128) -> B-frags for fuse GEMM (as round 6)
//  e in [4096,6144): W_coop/W_conf (4x4x32) -> B-frags for Wh GEMM, K 4->32 pad
// ---------------------------------------------------------------------------
__global__ __launch_bounds__(256) void prepack_kernel(
    const float* __restrict__ Wf,      // W_fuse (256,128)
    const float* __restrict__ Wc,      // W_coop (4,4,32)
    const float* __restrict__ Wn,      // W_conf (4,4,32)
    unsigned short* __restrict__ fragB,   // 4096*8 u16
    unsigned short* __restrict__ fragW) { // 2048*8 u16
  int e = blockIdx.x * 256 + threadIdx.x;
  if (e < 4096) {
    int kb = e >> 9, tile = (e >> 6) & 7, lane = e & 63;
    int n = tile * 16 + (lane & 15);
    int kbase = kb * 32 + (lane >> 4) * 8;
    unsigned short tmp[8];
#pragma unroll
    for (int j = 0; j < 8; j++) tmp[j] = f2b(Wf[(kbase + j) * 128 + n]);
    *(short8*)(fragB + e * 8) = *(short8*)tmp;
  } else if (e < 6144) {
    int i = e - 4096;
    int s = i >> 10, tile = (i >> 6) & 15, lane = i & 63;
    int c15 = lane & 15, quad = lane >> 4;
    int n = tile * 16 + c15, h = n >> 5, o = n & 31;
    const float* W = s ? Wn : Wc;
    unsigned short tmp[8];
#pragma unroll
    for (int j = 0; j < 8; j++) {
      int k = quad * 8 + j;
      tmp[j] = (k < 4) ? f2b(W[h * 128 + k * 32 + o]) : (unsigned short)0;
    }
    *(short8*)(fragW + i * 8) = *(short8*)tmp;
  }
}

// ---------------------------------------------------------------------------
// Kernel 1: per-node GAT + fuse, all three GEMMs on MFMA 16x16x32 bf16.
// One 128-thread block (2 waves; wave w = stream s=w) per node.
// LDS ~35.6 KB -> 4 blocks/CU.
// ---------------------------------------------------------------------------
__global__ __launch_bounds__(128) void gat_fuse_kernel(
    const float* __restrict__ self_f,   // (B,48)
    const float* __restrict__ nbr_f,    // (B,4,48)
    const float* __restrict__ as_coop, const float* __restrict__ ad_coop,
    const float* __restrict__ as_conf, const float* __restrict__ ad_conf,
    const unsigned short* __restrict__ fragW,  // Wh-GEMM B frags
    const unsigned short* __restrict__ fragB,  // fuse-GEMM B frags
    const float* __restrict__ b_fuse,   // (128,)
    float* __restrict__ emb)            // (B,5,128)
{
  const int n = blockIdx.x;
  const int t = threadIdx.x;
  const int b = n / 5;
  const int slot = n - b * 5;
  const int w = t >> 6, lane = t & 63, c15 = lane & 15, quad = lane >> 4;

  __shared__ __align__(16) unsigned short sxb[16][40];      // bf16 x, A-frag layout
  __shared__ __align__(16) unsigned short WhT[2][256][16];  // bf16 Wh^T [n][l]
  __shared__ float sa[2][2][4][32];                         // a_src/a_dst staged
  __shared__ float ses[2][4][12], sed[2][4][12];
  __shared__ __align__(16) unsigned short sattb[2][4][16][16]; // bf16 att, A-frag
  __shared__ __align__(16) unsigned short scatb[16][264];   // bf16 fused-cat A
  __shared__ float sbias[128];
  __shared__ float red[2][4][64];

  // ---- phase 0: zero pads ----
  {
    unsigned int* z1 = (unsigned int*)sxb;
    for (int i = t; i < 320; i += 128) z1[i] = 0u;
    unsigned int* z2 = (unsigned int*)sattb;
    for (int i = t; i < 1024; i += 128) z2[i] = 0u;
    unsigned int* z3 = (unsigned int*)scatb;          // rows 12-15
    for (int i = t; i < 528; i += 128) z3[1584 + i] = 0u;
  }
  sbias[t] = b_fuse[t];
  for (int i = t; i < 512; i += 128) {
    int s = i >> 8, sd = (i >> 7) & 1, r = i & 127;
    const float* p = s ? (sd ? ad_conf : as_conf) : (sd ? ad_coop : as_coop);
    sa[s][sd][r >> 5][r & 31] = p[r];
  }
  __syncthreads();

  // ---- phase 1: stage x as bf16 into A-frag layout ----
  if (t < 48) {
    int l = t >> 2, f = t & 3;
    float v = (slot == 0) ? self_f[b * 48 + t]
                          : nbr_f[(b * 4 + slot - 1) * 48 + t];
    sxb[l][f] = f2b(v);
  }
  __syncthreads();

  // ---- phase 2: Wh GEMM via MFMA. Wave w: stream s=w, 16 N-tiles of 16. ----
  {
    const int s = w;
    short8 axf = *(const short8*)&sxb[c15][quad * 8];
#pragma unroll
    for (int tile = 0; tile < 16; tile++) {
      short8 bw = *(const short8*)(fragW + ((s * 16 + tile) * 64 + lane) * 8);
      f32x4 c = {0.f, 0.f, 0.f, 0.f};
      c = __builtin_amdgcn_mfma_f32_16x16x32_bf16(axf, bw, c, 0, 0, 0);
      // C: col n=tile*16+c15, rows l=quad*4+r. Rows 12-15 exact zero.
      u16x4 pk = { f2b(c[0]), f2b(c[1]), f2b(c[2]), f2b(c[3]) };
      *(u16x4*)&WhT[s][tile * 16 + c15][quad * 4] = pk;
    }
  }
  __syncthreads();

  // ---- phase 3: attention logits from WhT ----
  if (t < 96) {
    int s = t / 48;
    int r = t - s * 48;
    int h = r / 12;
    int l = r - h * 12;
    float es = 0.f, ed = 0.f;
#pragma unroll
    for (int o = 0; o < 32; o++) {
      float whv = b2f_u(WhT[s][h * 32 + o][l]);
      es += whv * sa[s][0][h][o];
      ed += whv * sa[s][1][h][o];
    }
    ses[s][h][l] = es;
    sed[s][h][l] = ed;
  }
  __syncthreads();

  // ---- phase 4: masked softmax -> bf16 A-frag layout ----
  if (t < 96) {
    int s = t / 48;
    int r = t - s * 48;
    int h = r / 12;
    int i = r - h * 12;
    int blk = i / 3;
    float esi = ses[s][h][i];
    float ev[12];
    float m = -1e30f;
#pragma unroll
    for (int j = 0; j < 12; j++) {
      bool allowed = (s == 0) ? ((j / 3) == blk) : ((j / 3) != blk);
      float e = esi + sed[s][h][j];
      e = e > 0.f ? e : 0.2f * e;
      if (!allowed) e = -1e30f;
      ev[j] = e;
      m = fmaxf(m, e);
    }
    float sum = 0.f;
#pragma unroll
    for (int j = 0; j < 12; j++) {
      float a = (ev[j] > -1e29f) ? __expf(ev[j] - m) : 0.f;
      ev[j] = a;
      sum += a;
    }
    float inv = 1.f / sum;
#pragma unroll
    for (int j = 0; j < 12; j++) sattb[s][h][i][j] = f2b(ev[j] * inv);
  }
  __syncthreads();

  // ---- phase 5: att @ Wh via MFMA; ELU -> scatb. Wave w: stream s=w. ----
  {
    const int s = w;
    const short8 z8 = {0,0,0,0,0,0,0,0};
#pragma unroll
    for (int h = 0; h < 4; h++) {
      short8 af = z8;
      if (quad < 2) af = *(const short8*)&sattb[s][h][c15][quad * 8];
#pragma unroll
      for (int tile = 0; tile < 2; tile++) {
        short8 bf = z8;
        if (quad < 2) bf = *(const short8*)&WhT[s][h * 32 + tile * 16 + c15][quad * 8];
        f32x4 c = {0.f, 0.f, 0.f, 0.f};
        c = __builtin_amdgcn_mfma_f32_16x16x32_bf16(af, bf, c, 0, 0, 0);
        // C: col o = h*32+tile*16+c15, rows i = quad*4+r (valid i<12)
        if (quad < 3) {
          int co = s * 128 + h * 32 + tile * 16 + c15;
#pragma unroll
          for (int r = 0; r < 4; r++) {
            float v = c[r];
            v = v > 0.f ? v : (__expf(v) - 1.f);
            scatb[quad * 4 + r][co] = f2b(v);
          }
        }
      }
    }
  }
  __syncthreads();

  // ---- phase 6: fuse GEMM via MFMA (as round 6) ----
  {
    f32x4 acc0 = {0.f,0.f,0.f,0.f}, acc1 = acc0, acc2 = acc0, acc3 = acc0;
    const int tbase = w * 4;
#pragma unroll
    for (int kb = 0; kb < 8; kb++) {
      short8 a = *(const short8*)&scatb[c15][kb * 32 + (quad << 3)];
      const short8* bf = (const short8*)(fragB) + (kb * 8 + tbase) * 64 + lane;
      acc0 = __builtin_amdgcn_mfma_f32_16x16x32_bf16(a, bf[0],   acc0, 0, 0, 0);
      acc1 = __builtin_amdgcn_mfma_f32_16x16x32_bf16(a, bf[64],  acc1, 0, 0, 0);
      acc2 = __builtin_amdgcn_mfma_f32_16x16x32_bf16(a, bf[128], acc2, 0, 0, 0);
      acc3 = __builtin_amdgcn_mfma_f32_16x16x32_bf16(a, bf[192], acc3, 0, 0, 0);
    }
#pragma unroll
    for (int tt = 0; tt < 4; tt++) {
      f32x4 a4 = (tt == 0) ? acc0 : (tt == 1) ? acc1 : (tt == 2) ? acc2 : acc3;
      float p = 0.f;
      if (quad < 3) {
        float bcol = sbias[w * 64 + tt * 16 + c15];
#pragma unroll
        for (int r = 0; r < 4; r++) {
          float v = a4[r] + bcol;
          v = v > 0.f ? v : (__expf(v) - 1.f);
          p += v;
        }
      }
      red[w][quad][tt * 16 + c15] = p;
    }
  }
  __syncthreads();
  {
    float s = red[w][0][lane] + red[w][1][lane] + red[w][2][lane];
    emb[n * 128 + w * 64 + lane] = s * (1.f / 12.f);
  }
}

// ---------------------------------------------------------------------------
// Kernel 2: per-sample head (unchanged from round 5/6).
// ---------------------------------------------------------------------------
__global__ __launch_bounds__(64) void head_kernel(
    const float* __restrict__ emb,
    const float* __restrict__ maskp,
    const float* __restrict__ dirsp,
    const float* __restrict__ W_proj,
    const float* __restrict__ b_proj,
    const float* __restrict__ Wih_f, const float* __restrict__ Whh_f,
    const float* __restrict__ bih_f, const float* __restrict__ bhh_f,
    const float* __restrict__ Wih_b, const float* __restrict__ Whh_b,
    const float* __restrict__ bih_b, const float* __restrict__ bhh_b,
    const float* __restrict__ W_out,
    const float* __restrict__ b_out,
    float* __restrict__ out)
{
  const int b = blockIdx.x;
  const int t = threadIdx.x;
  __shared__ float s_x[4][64];
  __shared__ float s_h[2][32];

  {
    float a0 = b_proj[t], a1 = a0, a2 = a0, a3 = a0;
    const float* e1 = emb + (b * 5 + 1) * 128;
    const float* e2 = e1 + 128;
    const float* e3 = e2 + 128;
    const float* e4 = e3 + 128;
    for (int i = 0; i < 128; i++) {
      float w = W_proj[i * 64 + t];
      a0 += e1[i] * w;
      a1 += e2[i] * w;
      a2 += e3[i] * w;
      a3 += e4[i] * w;
    }
    float wl = W_proj[128 * 64 + t];
    a0 = fmaxf(a0 + dirsp[b*4+0] * wl, 0.f) * maskp[b*4+0];
    a1 = fmaxf(a1 + dirsp[b*4+1] * wl, 0.f) * maskp[b*4+1];
    a2 = fmaxf(a2 + dirsp[b*4+2] * wl, 0.f) * maskp[b*4+2];
    a3 = fmaxf(a3 + dirsp[b*4+3] * wl, 0.f) * maskp[b*4+3];
    s_x[0][t] = a0; s_x[1][t] = a1; s_x[2][t] = a2; s_x[3][t] = a3;
  }
  s_h[t >> 5][t & 31] = 0.f;
  __syncthreads();

  const int dir = t >> 5;
  const int u   = t & 31;
  const float* Wih = dir ? Wih_b : Wih_f;
  const float* Whh = dir ? Whh_b : Whh_f;
  const float* bih = dir ? bih_b : bih_f;
  const float* bhh = dir ? bhh_b : bhh_f;

  for (int step = 0; step < 4; step++) {
    const int k = dir ? (3 - step) : step;
    float gir = bih[u],      ghr = bhh[u];
    float giz = bih[32 + u], ghz = bhh[32 + u];
    float gin = bih[64 + u], ghn = bhh[64 + u];
    for (int i = 0; i < 64; i++) {
      float xv = s_x[k][i];
      const float* wr = Wih + i * 96 + u;
      gir += xv * wr[0];
      giz += xv * wr[32];
      gin += xv * wr[64];
    }
    for (int i = 0; i < 32; i++) {
      float hv = s_h[dir][i];
      const float* wr = Whh + i * 96 + u;
      ghr += hv * wr[0];
      ghz += hv * wr[32];
      ghn += hv * wr[64];
    }
    float r  = 1.f / (1.f + __expf(-(gir + ghr)));
    float z  = 1.f / (1.f + __expf(-(giz + ghz)));
    float nn = tanhf(gin + r * ghn);
    float hnew = (1.f - z) * nn + z * s_h[dir][u];
    __syncthreads();
    s_h[dir][u] = hnew;
    __syncthreads();
  }

  {
    const float* e0 = emb + b * 5 * 128;
    float acc = b_out[t];
    for (int i = 0; i < 128; i++) acc += e0[i] * W_out[i * 64 + t];
#pragma unroll
    for (int i = 0; i < 32; i++)  acc += s_h[0][i] * W_out[(128 + i) * 64 + t];
#pragma unroll
    for (int i = 0; i < 32; i++)  acc += s_h[1][i] * W_out[(160 + i) * 64 + t];
    out[b * 192 + 128 + t] = fmaxf(acc, 0.f);
    out[b * 192 + t]       = e0[t];
    out[b * 192 + 64 + t]  = e0[64 + t];
  }
}

// ---------------------------------------------------------------------------
extern "C" void kernel_launch(void* const* d_in, const int* in_sizes, int n_in,
                              void* d_out, int out_size, void* d_ws, size_t ws_size,
                              hipStream_t stream) {
  const float* self_f  = (const float*)d_in[0];
  const float* nbr_f   = (const float*)d_in[1];
  const float* maskp   = (const float*)d_in[2];
  const float* dirsp   = (const float*)d_in[3];
  const float* W_coop  = (const float*)d_in[4];
  const float* as_coop = (const float*)d_in[5];
  const float* ad_coop = (const float*)d_in[6];
  const float* W_conf  = (const float*)d_in[7];
  const float* as_conf = (const float*)d_in[8];
  const float* ad_conf = (const float*)d_in[9];
  const float* W_fuse  = (const float*)d_in[10];
  const float* b_fuse  = (const float*)d_in[11];
  const float* W_proj  = (const float*)d_in[12];
  const float* b_proj  = (const float*)d_in[13];
  const float* Wih_f   = (const float*)d_in[14];
  const float* Whh_f   = (const float*)d_in[15];
  const float* bih_f   = (const float*)d_in[16];
  const float* bhh_f   = (const float*)d_in[17];
  const float* Wih_b   = (const float*)d_in[18];
  const float* Whh_b   = (const float*)d_in[19];
  const float* bih_b   = (const float*)d_in[20];
  const float* bhh_b   = (const float*)d_in[21];
  const float* W_out   = (const float*)d_in[22];
  const float* b_out   = (const float*)d_in[23];

  const int B = in_sizes[0] / 48;   // 8192
  unsigned short* fragB = (unsigned short*)d_ws;                   // 64 KB
  unsigned short* fragW = (unsigned short*)((char*)d_ws + 65536);  // 32 KB
  float* emb = (float*)((char*)d_ws + 65536 + 32768);              // (B,5,128)

  prepack_kernel<<<24, 256, 0, stream>>>(W_fuse, W_coop, W_conf, fragB, fragW);

  gat_fuse_kernel<<<B * 5, 128, 0, stream>>>(
      self_f, nbr_f, as_coop, ad_coop, as_conf, ad_conf,
      fragW, fragB, b_fuse, emb);

  head_kernel<<<B, 64, 0, stream>>>(
      emb, maskp, dirsp, W_proj, b_proj,
      Wih_f, Whh_f, bih_f, bhh_f,
      Wih_b, Whh_b, bih_b, bhh_b,
      W_out, b_out, (float*)d_out);
}

// Round 8
// 429.800 us; speedup vs baseline: 14.6567x; 1.2540x over previous
//
#include <hip/hip_runtime.h>
#include <math.h>

typedef short short8 __attribute__((ext_vector_type(8)));
typedef float f32x4  __attribute__((ext_vector_type(4)));

__device__ __forceinline__ unsigned short f2b(float f) {
  union { float f; unsigned int u; } x; x.f = f;
  return (unsigned short)((x.u + 0x7FFFu + ((x.u >> 16) & 1u)) >> 16);
}
__device__ __forceinline__ float b2f_u(unsigned short u) {
  union { unsigned int u; float f; } x; x.u = ((unsigned int)u) << 16;
  return x.f;
}
__device__ __forceinline__ unsigned int pk2(float a, float b) {
  return (unsigned int)f2b(a) | ((unsigned int)f2b(b) << 16);
}

// ---------------------------------------------------------------------------
// Prepack: fragB (W_fuse), fragW (W_coop/W_conf, 8 N-tiles/stream, K 4->32),
// Wa[s][d][h][f] = sum_o W_s[h][f][o] * a_{s,d}[h][o]  (64 floats).
// ---------------------------------------------------------------------------
__global__ __launch_bounds__(256) void prepack_kernel(
    const float* __restrict__ Wf,
    const float* __restrict__ Wc, const float* __restrict__ Wn,
    const float* __restrict__ as_c, const float* __restrict__ ad_c,
    const float* __restrict__ as_n, const float* __restrict__ ad_n,
    unsigned short* __restrict__ fragB,   // 4096*8 u16
    unsigned short* __restrict__ fragW,   // 1024*8 u16
    float* __restrict__ Wa) {             // 64 f32
  int e = blockIdx.x * 256 + threadIdx.x;
  if (e < 4096) {
    int kb = e >> 9, tile = (e >> 6) & 7, lane = e & 63;
    int n = tile * 16 + (lane & 15);
    int kbase = kb * 32 + (lane >> 4) * 8;
    unsigned short tmp[8];
#pragma unroll
    for (int j = 0; j < 8; j++) tmp[j] = f2b(Wf[(kbase + j) * 128 + n]);
    *(short8*)(fragB + e * 8) = *(short8*)tmp;
  } else if (e < 5120) {
    int i = e - 4096;
    int s = i >> 9, tile = (i >> 6) & 7, lane = i & 63;
    int c15 = lane & 15, quad = lane >> 4;
    int n = tile * 16 + c15;            // [0,128)
    int h = n >> 5, o = n & 31;
    const float* W = s ? Wn : Wc;
    unsigned short tmp[8];
#pragma unroll
    for (int j = 0; j < 8; j++) {
      int k = quad * 8 + j;
      tmp[j] = (k < 4) ? f2b(W[h * 128 + k * 32 + o]) : (unsigned short)0;
    }
    *(short8*)(fragW + i * 8) = *(short8*)tmp;
  } else if (e < 5184) {
    int i = e - 5120;
    int s = i >> 5, d = (i >> 4) & 1, h = (i >> 2) & 3, f = i & 3;
    const float* W = s ? Wn : Wc;
    const float* a = s ? (d ? ad_n : as_n) : (d ? ad_c : as_c);
    float acc = 0.f;
#pragma unroll
    for (int o = 0; o < 32; o++) acc += W[h * 128 + f * 32 + o] * a[h * 32 + o];
    Wa[i] = acc;
  }
}

// ---------------------------------------------------------------------------
// Kernel 1: per-node GAT + fuse; Wh kept in registers, logits via Wa trick.
// One 128-thread block (2 waves; wave w = stream) per node. LDS ~21 KB.
// ---------------------------------------------------------------------------
__global__ __launch_bounds__(128) void gat_fuse_kernel(
    const float* __restrict__ self_f,   // (B,48)
    const float* __restrict__ nbr_f,    // (B,4,48)
    const float* __restrict__ Wa,       // (64,)
    const unsigned short* __restrict__ fragW,
    const unsigned short* __restrict__ fragB,
    const float* __restrict__ b_fuse,   // (128,)
    float* __restrict__ emb)            // (B,5,128)
{
  const int n = blockIdx.x;
  const int t = threadIdx.x;
  const int b = n / 5;
  const int slot = n - b * 5;
  const int w = t >> 6, lane = t & 63, c15 = lane & 15, quad = lane >> 4;

  __shared__ __align__(16) unsigned short sxb[16][32];        // bf16 x, K-pad
  __shared__ float sWa[64];
  __shared__ float sed[2][4][12];
  __shared__ __align__(16) unsigned short sattb[2][4][16][32]; // att A-frag
  __shared__ __align__(16) unsigned short scatb[16][264];      // fused-cat A
  __shared__ float sbias[128];
  __shared__ float red[2][4][64];

  // ---- phase 0: zero pads + stage ----
  {
    unsigned int* zx = (unsigned int*)sxb;          // 256 dw; keep dw 0,1 of rows<12
    for (int i = t; i < 256; i += 128)
      if (((i & 15) >= 2) || ((i >> 4) >= 12)) zx[i] = 0u;
    unsigned int* za = (unsigned int*)sattb;        // rows 12-15 of each (s,h)
    for (int i = t; i < 512; i += 128) {
      int sh = i >> 6, r = i & 63;
      za[sh * 256 + 192 + r] = 0u;
    }
    unsigned int* zc = (unsigned int*)scatb;        // rows 12-15
    for (int i = t; i < 528; i += 128) zc[1584 + i] = 0u;
  }
  sbias[t] = b_fuse[t];
  if (t < 64) sWa[t] = Wa[t];
  if (t < 48) {
    int l = t >> 2, f = t & 3;
    float v = (slot == 0) ? self_f[b * 48 + t]
                          : nbr_f[(b * 4 + slot - 1) * 48 + t];
    sxb[l][f] = f2b(v);
  }
  __syncthreads();

  // ---- phase 1: Wh GEMM (regs) + logits ----
  unsigned int whpk[8][2];
  {
    short8 ax = *(const short8*)&sxb[c15][quad * 8];
#pragma unroll
    for (int tile = 0; tile < 8; tile++) {
      short8 bw = *(const short8*)(fragW + ((w * 8 + tile) * 64 + lane) * 8);
      f32x4 c = {0.f, 0.f, 0.f, 0.f};
      c = __builtin_amdgcn_mfma_f32_16x16x32_bf16(ax, bw, c, 0, 0, 0);
      whpk[tile][0] = pk2(c[0], c[1]);   // rows quad*4, quad*4+1 (col c15)
      whpk[tile][1] = pk2(c[2], c[3]);   // rows quad*4+2, quad*4+3
    }
  }
  float es_local = 0.f;
  {
    if (t < 96) {
      int s = t / 48;
      int r = t - s * 48;
      int h = r / 12;
      int l = r - h * 12;
      float ed = 0.f;
#pragma unroll
      for (int f = 0; f < 4; f++) {
        float xv = b2f_u(sxb[l][f]);
        es_local += xv * sWa[s * 32 + h * 4 + f];
        ed       += xv * sWa[s * 32 + 16 + h * 4 + f];
      }
      sed[s][h][l] = ed;
    }
  }
  __syncthreads();

  // ---- phase 2: masked softmax -> sattb (rows i<12, 32-wide, zero-padded) --
  if (t < 96) {
    int s = t / 48;
    int r = t - s * 48;
    int h = r / 12;
    int i = r - h * 12;
    int blk = i / 3;
    float ev[12];
    float m = -1e30f;
#pragma unroll
    for (int j = 0; j < 12; j++) {
      bool allowed = (s == 0) ? ((j / 3) == blk) : ((j / 3) != blk);
      float e = es_local + sed[s][h][j];
      e = e > 0.f ? e : 0.2f * e;
      if (!allowed) e = -1e30f;
      ev[j] = e;
      m = fmaxf(m, e);
    }
    float sum = 0.f;
#pragma unroll
    for (int j = 0; j < 12; j++) {
      float a = (ev[j] > -1e29f) ? __expf(ev[j] - m) : 0.f;
      ev[j] = a;
      sum += a;
    }
    float inv = 1.f / sum;
    unsigned short tmp[32];
#pragma unroll
    for (int j = 0; j < 12; j++) tmp[j] = f2b(ev[j] * inv);
#pragma unroll
    for (int j = 12; j < 32; j++) tmp[j] = 0;
    short8* dst = (short8*)&sattb[s][h][i][0];
    const short8* src = (const short8*)tmp;
    dst[0] = src[0]; dst[1] = src[1]; dst[2] = src[2]; dst[3] = src[3];
  }
  __syncthreads();

  // ---- phase 3: PV via MFMA, B-frags built from whpk via shfl ----
  {
    union U8 { unsigned int u[4]; short8 v; };
    const int sl0 = (32 * quad + c15) & 63;
    const int sl1 = (32 * quad + 16 + c15) & 63;
    const bool hiq = (quad >= 2);
#pragma unroll
    for (int h = 0; h < 4; h++) {
#pragma unroll
      for (int t2 = 0; t2 < 2; t2++) {
        short8 af = *(const short8*)&sattb[w][h][c15][quad * 8];
        unsigned int d0 = whpk[2 * h + t2][0], d1 = whpk[2 * h + t2][1];
        U8 bb;
        bb.u[0] = (unsigned int)__shfl((int)d0, sl0);
        bb.u[1] = (unsigned int)__shfl((int)d1, sl0);
        bb.u[2] = (unsigned int)__shfl((int)d0, sl1);
        bb.u[3] = (unsigned int)__shfl((int)d1, sl1);
        if (hiq) { bb.u[0] = 0; bb.u[1] = 0; bb.u[2] = 0; bb.u[3] = 0; }
        f32x4 c = {0.f, 0.f, 0.f, 0.f};
        c = __builtin_amdgcn_mfma_f32_16x16x32_bf16(af, bb.v, c, 0, 0, 0);
        if (quad < 3) {
          int co = w * 128 + h * 32 + t2 * 16 + c15;
#pragma unroll
          for (int r = 0; r < 4; r++) {
            float v = c[r];
            v = v > 0.f ? v : (__expf(v) - 1.f);
            scatb[quad * 4 + r][co] = f2b(v);
          }
        }
      }
    }
  }
  __syncthreads();

  // ---- phase 4: fuse GEMM via MFMA ----
  {
    f32x4 acc0 = {0.f,0.f,0.f,0.f}, acc1 = acc0, acc2 = acc0, acc3 = acc0;
    const int tbase = w * 4;
#pragma unroll
    for (int kb = 0; kb < 8; kb++) {
      short8 a = *(const short8*)&scatb[c15][kb * 32 + (quad << 3)];
      const short8* bf = (const short8*)(fragB) + (kb * 8 + tbase) * 64 + lane;
      acc0 = __builtin_amdgcn_mfma_f32_16x16x32_bf16(a, bf[0],   acc0, 0, 0, 0);
      acc1 = __builtin_amdgcn_mfma_f32_16x16x32_bf16(a, bf[64],  acc1, 0, 0, 0);
      acc2 = __builtin_amdgcn_mfma_f32_16x16x32_bf16(a, bf[128], acc2, 0, 0, 0);
      acc3 = __builtin_amdgcn_mfma_f32_16x16x32_bf16(a, bf[192], acc3, 0, 0, 0);
    }
#pragma unroll
    for (int tt = 0; tt < 4; tt++) {
      f32x4 a4 = (tt == 0) ? acc0 : (tt == 1) ? acc1 : (tt == 2) ? acc2 : acc3;
      float p = 0.f;
      if (quad < 3) {
        float bcol = sbias[w * 64 + tt * 16 + c15];
#pragma unroll
        for (int r = 0; r < 4; r++) {
          float v = a4[r] + bcol;
          v = v > 0.f ? v : (__expf(v) - 1.f);
          p += v;
        }
      }
      red[w][quad][tt * 16 + c15] = p;
    }
  }
  __syncthreads();
  {
    float s = red[w][0][lane] + red[w][1][lane] + red[w][2][lane];
    emb[n * 128 + w * 64 + lane] = s * (1.f / 12.f);
  }
}

// ---------------------------------------------------------------------------
// Kernel 2: head; 4 samples per 256-thread block (one wave each; barriers
// are block-uniform since all waves run the identical path).
// ---------------------------------------------------------------------------
__global__ __launch_bounds__(256) void head_kernel(
    const float* __restrict__ emb,
    const float* __restrict__ maskp,
    const float* __restrict__ dirsp,
    const float* __restrict__ W_proj,
    const float* __restrict__ b_proj,
    const float* __restrict__ Wih_f, const float* __restrict__ Whh_f,
    const float* __restrict__ bih_f, const float* __restrict__ bhh_f,
    const float* __restrict__ Wih_b, const float* __restrict__ Whh_b,
    const float* __restrict__ bih_b, const float* __restrict__ bhh_b,
    const float* __restrict__ W_out,
    const float* __restrict__ b_out,
    float* __restrict__ out)
{
  const int wv = threadIdx.x >> 6;
  const int t  = threadIdx.x & 63;
  const int b  = blockIdx.x * 4 + wv;
  __shared__ float s_x[4][4][64];
  __shared__ float s_h[4][2][32];

  {
    float a0 = b_proj[t], a1 = a0, a2 = a0, a3 = a0;
    const float* e1 = emb + (b * 5 + 1) * 128;
    const float* e2 = e1 + 128;
    const float* e3 = e2 + 128;
    const float* e4 = e3 + 128;
    for (int i = 0; i < 128; i++) {
      float w = W_proj[i * 64 + t];
      a0 += e1[i] * w;
      a1 += e2[i] * w;
      a2 += e3[i] * w;
      a3 += e4[i] * w;
    }
    float wl = W_proj[128 * 64 + t];
    a0 = fmaxf(a0 + dirsp[b*4+0] * wl, 0.f) * maskp[b*4+0];
    a1 = fmaxf(a1 + dirsp[b*4+1] * wl, 0.f) * maskp[b*4+1];
    a2 = fmaxf(a2 + dirsp[b*4+2] * wl, 0.f) * maskp[b*4+2];
    a3 = fmaxf(a3 + dirsp[b*4+3] * wl, 0.f) * maskp[b*4+3];
    s_x[wv][0][t] = a0; s_x[wv][1][t] = a1; s_x[wv][2][t] = a2; s_x[wv][3][t] = a3;
  }
  s_h[wv][t >> 5][t & 31] = 0.f;
  __syncthreads();

  const int dir = t >> 5;
  const int u   = t & 31;
  const float* Wih = dir ? Wih_b : Wih_f;
  const float* Whh = dir ? Whh_b : Whh_f;
  const float* bih = dir ? bih_b : bih_f;
  const float* bhh = dir ? bhh_b : bhh_f;

  for (int step = 0; step < 4; step++) {
    const int k = dir ? (3 - step) : step;
    float gir = bih[u],      ghr = bhh[u];
    float giz = bih[32 + u], ghz = bhh[32 + u];
    float gin = bih[64 + u], ghn = bhh[64 + u];
    for (int i = 0; i < 64; i++) {
      float xv = s_x[wv][k][i];
      const float* wr = Wih + i * 96 + u;
      gir += xv * wr[0];
      giz += xv * wr[32];
      gin += xv * wr[64];
    }
    for (int i = 0; i < 32; i++) {
      float hv = s_h[wv][dir][i];
      const float* wr = Whh + i * 96 + u;
      ghr += hv * wr[0];
      ghz += hv * wr[32];
      ghn += hv * wr[64];
    }
    float r  = 1.f / (1.f + __expf(-(gir + ghr)));
    float z  = 1.f / (1.f + __expf(-(giz + ghz)));
    float nn = tanhf(gin + r * ghn);
    float hnew = (1.f - z) * nn + z * s_h[wv][dir][u];
    __syncthreads();
    s_h[wv][dir][u] = hnew;
    __syncthreads();
  }

  {
    const float* e0 = emb + b * 5 * 128;
    float acc = b_out[t];
    for (int i = 0; i < 128; i++) acc += e0[i] * W_out[i * 64 + t];
#pragma unroll
    for (int i = 0; i < 32; i++)  acc += s_h[wv][0][i] * W_out[(128 + i) * 64 + t];
#pragma unroll
    for (int i = 0; i < 32; i++)  acc += s_h[wv][1][i] * W_out[(160 + i) * 64 + t];
    out[b * 192 + 128 + t] = fmaxf(acc, 0.f);
    out[b * 192 + t]       = e0[t];
    out[b * 192 + 64 + t]  = e0[64 + t];
  }
}

// ---------------------------------------------------------------------------
extern "C" void kernel_launch(void* const* d_in, const int* in_sizes, int n_in,
                              void* d_out, int out_size, void* d_ws, size_t ws_size,
                              hipStream_t stream) {
  const float* self_f  = (const float*)d_in[0];
  const float* nbr_f   = (const float*)d_in[1];
  const float* maskp   = (const float*)d_in[2];
  const float* dirsp   = (const float*)d_in[3];
  const float* W_coop  = (const float*)d_in[4];
  const float* as_coop = (const float*)d_in[5];
  const float* ad_coop = (const float*)d_in[6];
  const float* W_conf  = (const float*)d_in[7];
  const float* as_conf = (const float*)d_in[8];
  const float* ad_conf = (const float*)d_in[9];
  const float* W_fuse  = (const float*)d_in[10];
  const float* b_fuse  = (const float*)d_in[11];
  const float* W_proj  = (const float*)d_in[12];
  const float* b_proj  = (const float*)d_in[13];
  const float* Wih_f   = (const float*)d_in[14];
  const float* Whh_f   = (const float*)d_in[15];
  const float* bih_f   = (const float*)d_in[16];
  const float* bhh_f   = (const float*)d_in[17];
  const float* Wih_b   = (const float*)d_in[18];
  const float* Whh_b   = (const float*)d_in[19];
  const float* bih_b   = (const float*)d_in[20];
  const float* bhh_b   = (const float*)d_in[21];
  const float* W_out   = (const float*)d_in[22];
  const float* b_out   = (const float*)d_in[23];

  const int B = in_sizes[0] / 48;   // 8192
  unsigned short* fragB = (unsigned short*)d_ws;                   // 64 KB
  unsigned short* fragW = (unsigned short*)((char*)d_ws + 65536);  // 16 KB
  float* Wa  = (float*)((char*)d_ws + 65536 + 16384);              // 256 B
  float* emb = (float*)((char*)d_ws + 65536 + 16384 + 256);        // (B,5,128)

  prepack_kernel<<<21, 256, 0, stream>>>(
      W_fuse, W_coop, W_conf, as_coop, ad_coop, as_conf, ad_conf,
      fragB, fragW, Wa);

  gat_fuse_kernel<<<B * 5, 128, 0, stream>>>(
      self_f, nbr_f, Wa, fragW, fragB, b_fuse, emb);

  head_kernel<<<B / 4, 256, 0, stream>>>(
      emb, maskp, dirsp, W_proj, b_proj,
      Wih_f, Whh_f, bih_f, bhh_f,
      Wih_b, Whh_b, bih_b, bhh_b,
      W_out, b_out, (float*)d_out);
}

// Round 9
// 386.377 us; speedup vs baseline: 16.3039x; 1.1124x over previous
//
#include <hip/hip_runtime.h>
#include <math.h>

typedef short short8 __attribute__((ext_vector_type(8)));
typedef float f32x4  __attribute__((ext_vector_type(4)));

__device__ __forceinline__ unsigned short f2b(float f) {
  union { float f; unsigned int u; } x; x.f = f;
  return (unsigned short)((x.u + 0x7FFFu + ((x.u >> 16) & 1u)) >> 16);
}
__device__ __forceinline__ float b2f_u(unsigned short u) {
  union { unsigned int u; float f; } x; x.u = ((unsigned int)u) << 16;
  return x.f;
}
__device__ __forceinline__ unsigned int pk2(float a, float b) {
  return (unsigned int)f2b(a) | ((unsigned int)f2b(b) << 16);
}
__device__ __forceinline__ float sigm(float x) { return 1.f / (1.f + __expf(-x)); }

// ---------------------------------------------------------------------------
// Prepack all weights into MFMA B-fragment layouts (16x16x32 bf16):
//  frag[( kb*NT + nt )*64 + lane][j] = bf16( W[(kb*32 + (lane>>4)*8 + j)*N + nt*16 + (lane&15)] )
// ---------------------------------------------------------------------------
__global__ __launch_bounds__(256) void prepack_kernel(
    const float* __restrict__ Wf,                       // W_fuse (256,128)
    const float* __restrict__ Wc, const float* __restrict__ Wn,
    const float* __restrict__ as_c, const float* __restrict__ ad_c,
    const float* __restrict__ as_n, const float* __restrict__ ad_n,
    const float* __restrict__ Wproj,                    // (129,64)
    const float* __restrict__ Wih_f, const float* __restrict__ Wih_b, // (64,96)
    const float* __restrict__ Wout,                     // (192,64)
    unsigned short* __restrict__ fragB,   // 4096*8
    unsigned short* __restrict__ fragW,   // 1024*8
    float* __restrict__ Wa,               // 64
    unsigned short* __restrict__ fragP,   // 1024*8
    unsigned short* __restrict__ fragIH,  // 1536*8
    unsigned short* __restrict__ fragO)   // 1536*8
{
  int e = blockIdx.x * 256 + threadIdx.x;
  unsigned short tmp[8];
  if (e < 4096) {                                   // fuse GEMM B (K=256,N=128)
    int kb = e >> 9, tile = (e >> 6) & 7, lane = e & 63;
    int n = tile * 16 + (lane & 15);
    int kbase = kb * 32 + (lane >> 4) * 8;
#pragma unroll
    for (int j = 0; j < 8; j++) tmp[j] = f2b(Wf[(kbase + j) * 128 + n]);
    *(short8*)(fragB + e * 8) = *(short8*)tmp;
  } else if (e < 5120) {                            // Wh GEMM B (K pad 4->32, N=128) x2 streams
    int i = e - 4096;
    int s = i >> 9, tile = (i >> 6) & 7, lane = i & 63;
    int c15 = lane & 15, quad = lane >> 4;
    int n = tile * 16 + c15;
    int h = n >> 5, o = n & 31;
    const float* W = s ? Wn : Wc;
#pragma unroll
    for (int j = 0; j < 8; j++) {
      int k = quad * 8 + j;
      tmp[j] = (k < 4) ? f2b(W[h * 128 + k * 32 + o]) : (unsigned short)0;
    }
    *(short8*)(fragW + i * 8) = *(short8*)tmp;
  } else if (e < 5184) {                            // Wa[s][d][h][f]
    int i = e - 5120;
    int s = i >> 5, d = (i >> 4) & 1, h = (i >> 2) & 3, f = i & 3;
    const float* W = s ? Wn : Wc;
    const float* a = s ? (d ? ad_n : as_n) : (d ? ad_c : as_c);
    float acc = 0.f;
#pragma unroll
    for (int o = 0; o < 32; o++) acc += W[h * 128 + f * 32 + o] * a[h * 32 + o];
    Wa[i] = acc;
  } else if (e < 6208) {                            // proj B (K=128, N=64)
    int i = e - 5184;
    int kb = i >> 8, nt = (i >> 6) & 3, lane = i & 63;
    int c15 = lane & 15, quad = lane >> 4;
#pragma unroll
    for (int j = 0; j < 8; j++)
      tmp[j] = f2b(Wproj[(kb * 32 + quad * 8 + j) * 64 + nt * 16 + c15]);
    *(short8*)(fragP + i * 8) = *(short8*)tmp;
  } else if (e < 7744) {                            // Wih B (K=64, N=96) x2 dirs
    int i = e - 6208;
    int d = (i >= 768), r = i - d * 768;
    int kb = r / 384, nt = (r >> 6) % 6, lane = r & 63;
    int c15 = lane & 15, quad = lane >> 4;
    const float* W = d ? Wih_b : Wih_f;
#pragma unroll
    for (int j = 0; j < 8; j++)
      tmp[j] = f2b(W[(kb * 32 + quad * 8 + j) * 96 + nt * 16 + c15]);
    *(short8*)(fragIH + i * 8) = *(short8*)tmp;
  } else if (e < 9280) {                            // out B (K=192, N=64)
    int r = e - 7744;
    int kb = r >> 8, nt = (r >> 6) & 3, lane = r & 63;
    int c15 = lane & 15, quad = lane >> 4;
#pragma unroll
    for (int j = 0; j < 8; j++)
      tmp[j] = f2b(Wout[(kb * 32 + quad * 8 + j) * 64 + nt * 16 + c15]);
    *(short8*)(fragO + r * 8) = *(short8*)tmp;
  }
}

// ---------------------------------------------------------------------------
// Kernel 1: GAT + fuse, 2 NODES per 128-thread block (B-frags shared across
// both nodes' M-tiles). Wave w = stream. LDS ~45.6 KB -> 3 blocks/CU.
// ---------------------------------------------------------------------------
__global__ __launch_bounds__(128) void gat_fuse_kernel(
    const float* __restrict__ self_f, const float* __restrict__ nbr_f,
    const float* __restrict__ Wa,
    const unsigned short* __restrict__ fragW,
    const unsigned short* __restrict__ fragB,
    const float* __restrict__ b_fuse,
    float* __restrict__ emb)
{
  const int t = threadIdx.x;
  const int w = t >> 6, lane = t & 63, c15 = lane & 15, quad = lane >> 4;
  const int n0 = blockIdx.x * 2;

  __shared__ __align__(16) unsigned short sxb[2][16][40];
  __shared__ float sWa[64];
  __shared__ float sed[2][2][4][12];
  __shared__ __align__(16) unsigned short sattb[2][2][4][16][40];
  __shared__ __align__(16) unsigned short scatb[2][16][264];
  __shared__ float sbias[128];
  __shared__ float red[2][2][4][64];

  // phase 0: zero x staging (rows>=12 and cols>=4 must be exact zero), stage
  {
    unsigned int* zx = (unsigned int*)sxb;          // 2*16*40/2 = 640 dwords
    for (int i = t; i < 640; i += 128) zx[i] = 0u;
  }
  sbias[t] = b_fuse[t];
  if (t < 64) sWa[t] = Wa[t];
  __syncthreads();
  if (t < 96) {
    int nd = t / 48, f = t - nd * 48;
    int nn = n0 + nd, b = nn / 5, slot = nn - b * 5;
    float v = (slot == 0) ? self_f[b * 48 + f]
                          : nbr_f[(b * 4 + slot - 1) * 48 + f];
    sxb[nd][f >> 2][f & 3] = f2b(v);
  }
  __syncthreads();

  // phase 1: Wh GEMM (both nodes share B-frags) + logits
  unsigned int whpk[2][8][2];
  {
    short8 ax0 = *(const short8*)&sxb[0][c15][quad * 8];
    short8 ax1 = *(const short8*)&sxb[1][c15][quad * 8];
#pragma unroll
    for (int tile = 0; tile < 8; tile++) {
      short8 bw = *(const short8*)(fragW + ((w * 8 + tile) * 64 + lane) * 8);
      f32x4 c0 = {0.f,0.f,0.f,0.f}, c1 = c0;
      c0 = __builtin_amdgcn_mfma_f32_16x16x32_bf16(ax0, bw, c0, 0, 0, 0);
      c1 = __builtin_amdgcn_mfma_f32_16x16x32_bf16(ax1, bw, c1, 0, 0, 0);
      whpk[0][tile][0] = pk2(c0[0], c0[1]); whpk[0][tile][1] = pk2(c0[2], c0[3]);
      whpk[1][tile][0] = pk2(c1[0], c1[1]); whpk[1][tile][1] = pk2(c1[2], c1[3]);
    }
  }
  float es_local[2] = {0.f, 0.f};
  if (t < 96) {
    int s = t / 48;
    int r = t - s * 48;
    int h = r / 12;
    int l = r - h * 12;
#pragma unroll
    for (int nd = 0; nd < 2; nd++) {
      float es = 0.f, ed = 0.f;
#pragma unroll
      for (int f = 0; f < 4; f++) {
        float xv = b2f_u(sxb[nd][l][f]);
        es += xv * sWa[s * 32 + h * 4 + f];
        ed += xv * sWa[s * 32 + 16 + h * 4 + f];
      }
      es_local[nd] = es;
      sed[nd][s][h][l] = ed;
    }
  }
  __syncthreads();

  // phase 2: masked softmax -> sattb (rows <12 written, k>=12 zeroed in-reg)
  if (t < 96) {
    int s = t / 48;
    int r = t - s * 48;
    int h = r / 12;
    int i = r - h * 12;
    int blk = i / 3;
#pragma unroll
    for (int nd = 0; nd < 2; nd++) {
      float ev[12];
      float m = -1e30f;
#pragma unroll
      for (int j = 0; j < 12; j++) {
        bool allowed = (s == 0) ? ((j / 3) == blk) : ((j / 3) != blk);
        float e = es_local[nd] + sed[nd][s][h][j];
        e = e > 0.f ? e : 0.2f * e;
        if (!allowed) e = -1e30f;
        ev[j] = e;
        m = fmaxf(m, e);
      }
      float sum = 0.f;
#pragma unroll
      for (int j = 0; j < 12; j++) {
        float a = (ev[j] > -1e29f) ? __expf(ev[j] - m) : 0.f;
        ev[j] = a;
        sum += a;
      }
      float inv = 1.f / sum;
      unsigned short tmp[32];
#pragma unroll
      for (int j = 0; j < 12; j++) tmp[j] = f2b(ev[j] * inv);
#pragma unroll
      for (int j = 12; j < 32; j++) tmp[j] = 0;
      short8* dst = (short8*)&sattb[nd][s][h][i][0];
      const short8* src = (const short8*)tmp;
      dst[0] = src[0]; dst[1] = src[1]; dst[2] = src[2]; dst[3] = src[3];
    }
  }
  __syncthreads();

  // phase 3: PV via MFMA, B-frags from whpk via shfl (both nodes)
  {
    union U8 { unsigned int u[4]; short8 v; };
    const int sl0 = (32 * quad + c15) & 63;
    const int sl1 = (32 * quad + 16 + c15) & 63;
    const bool hiq = (quad >= 2);
#pragma unroll
    for (int h = 0; h < 4; h++) {
#pragma unroll
      for (int t2 = 0; t2 < 2; t2++) {
#pragma unroll
        for (int nd = 0; nd < 2; nd++) {
          short8 af = *(const short8*)&sattb[nd][w][h][c15][quad * 8];
          unsigned int d0 = whpk[nd][2 * h + t2][0], d1 = whpk[nd][2 * h + t2][1];
          U8 bb;
          bb.u[0] = (unsigned int)__shfl((int)d0, sl0);
          bb.u[1] = (unsigned int)__shfl((int)d1, sl0);
          bb.u[2] = (unsigned int)__shfl((int)d0, sl1);
          bb.u[3] = (unsigned int)__shfl((int)d1, sl1);
          if (hiq) { bb.u[0] = 0; bb.u[1] = 0; bb.u[2] = 0; bb.u[3] = 0; }
          f32x4 c = {0.f, 0.f, 0.f, 0.f};
          c = __builtin_amdgcn_mfma_f32_16x16x32_bf16(af, bb.v, c, 0, 0, 0);
          if (quad < 3) {
            int co = w * 128 + h * 32 + t2 * 16 + c15;
#pragma unroll
            for (int r = 0; r < 4; r++) {
              float v = c[r];
              v = v > 0.f ? v : (__expf(v) - 1.f);
              scatb[nd][quad * 4 + r][co] = f2b(v);
            }
          }
        }
      }
    }
  }
  __syncthreads();

  // phase 4: fuse GEMM, B-frags shared across both nodes
  {
    f32x4 accA[4], accB[4];
#pragma unroll
    for (int i = 0; i < 4; i++) { accA[i] = (f32x4){0.f,0.f,0.f,0.f}; accB[i] = accA[i]; }
    const int tbase = w * 4;
#pragma unroll
    for (int kb = 0; kb < 8; kb++) {
      short8 a0 = *(const short8*)&scatb[0][c15][kb * 32 + (quad << 3)];
      short8 a1 = *(const short8*)&scatb[1][c15][kb * 32 + (quad << 3)];
      const short8* bf = (const short8*)(fragB) + (kb * 8 + tbase) * 64 + lane;
#pragma unroll
      for (int tt = 0; tt < 4; tt++) {
        short8 bw = bf[tt * 64];
        accA[tt] = __builtin_amdgcn_mfma_f32_16x16x32_bf16(a0, bw, accA[tt], 0, 0, 0);
        accB[tt] = __builtin_amdgcn_mfma_f32_16x16x32_bf16(a1, bw, accB[tt], 0, 0, 0);
      }
    }
#pragma unroll
    for (int nd = 0; nd < 2; nd++) {
#pragma unroll
      for (int tt = 0; tt < 4; tt++) {
        f32x4 a4 = nd ? accB[tt] : accA[tt];
        float p = 0.f;
        if (quad < 3) {
          float bcol = sbias[w * 64 + tt * 16 + c15];
#pragma unroll
          for (int r = 0; r < 4; r++) {
            float v = a4[r] + bcol;
            v = v > 0.f ? v : (__expf(v) - 1.f);
            p += v;
          }
        }
        red[nd][w][quad][tt * 16 + c15] = p;
      }
    }
  }
  __syncthreads();
#pragma unroll
  for (int nd = 0; nd < 2; nd++) {
    float s = red[nd][w][0][lane] + red[nd][w][1][lane] + red[nd][w][2][lane];
    emb[(n0 + nd) * 128 + w * 64 + lane] = s * (1.f / 12.f);
  }
}

// ---------------------------------------------------------------------------
// Kernel 2: head, 8 samples per 256-thread block; proj/gi/out on MFMA,
// only the 4-step gh recurrence scalar.
// ---------------------------------------------------------------------------
__global__ __launch_bounds__(256) void head_kernel(
    const float* __restrict__ emb,
    const float* __restrict__ maskp, const float* __restrict__ dirsp,
    const float* __restrict__ W_proj, const float* __restrict__ b_proj,
    const unsigned short* __restrict__ fragP,
    const unsigned short* __restrict__ fragIH,
    const float* __restrict__ bih_f, const float* __restrict__ bhh_f,
    const float* __restrict__ bih_b, const float* __restrict__ bhh_b,
    const float* __restrict__ Whh_f, const float* __restrict__ Whh_b,
    const unsigned short* __restrict__ fragO,
    const float* __restrict__ b_out,
    float* __restrict__ out)
{
  const int b8 = blockIdx.x * 8;
  const int tid = threadIdx.x;
  const int w = tid >> 6, lane = tid & 63, c15 = lane & 15, quad = lane >> 4;

  __shared__ __align__(16) unsigned short sX[32][72];      // proj out (bf16)
  __shared__ __align__(16) unsigned short sgi[2][32][104]; // gi+bih (bf16)
  __shared__ float sH[2][8][32];
  __shared__ __align__(16) unsigned short sCat[16][200];
  __shared__ float sPB[128];    // [0..63]=b_proj, [64..127]=W_proj dir row
  __shared__ float sBI[2][96], sBH[2][96], sBO[64];

  if (tid < 64) { sPB[tid] = b_proj[tid]; sPB[64 + tid] = W_proj[128 * 64 + tid]; sBO[tid] = b_out[tid]; }
  if (tid < 96) { sBI[0][tid] = bih_f[tid]; sBI[1][tid] = bih_b[tid];
                  sBH[0][tid] = bhh_f[tid]; sBH[1][tid] = bhh_b[tid]; }
  __syncthreads();

  // ---- proj via MFMA: X(32x64) = nbr_emb(32x128) @ W_proj ----
  {
    const int mt = w >> 1;          // M-tile (4 samples)
    const int nt0 = (w & 1) * 2;    // 2 N-tiles per wave
    const int sloc = mt * 4 + (c15 >> 2);
    const int nbr  = c15 & 3;
    const float* arow = emb + (((b8 + sloc) * 5) + 1 + nbr) * 128;
    short8 a[4];
#pragma unroll
    for (int kb = 0; kb < 4; kb++) {
      const float* p = arow + kb * 32 + quad * 8;
      f32x4 v0 = *(const f32x4*)p;
      f32x4 v1 = *(const f32x4*)(p + 4);
      unsigned short tmp[8];
      tmp[0]=f2b(v0[0]); tmp[1]=f2b(v0[1]); tmp[2]=f2b(v0[2]); tmp[3]=f2b(v0[3]);
      tmp[4]=f2b(v1[0]); tmp[5]=f2b(v1[1]); tmp[6]=f2b(v1[2]); tmp[7]=f2b(v1[3]);
      a[kb] = *(short8*)tmp;
    }
    f32x4 acc0 = {0.f,0.f,0.f,0.f}, acc1 = acc0;
#pragma unroll
    for (int kb = 0; kb < 4; kb++) {
      short8 b0 = *(const short8*)(fragP + ((kb * 4 + nt0    ) * 64 + lane) * 8);
      short8 b1 = *(const short8*)(fragP + ((kb * 4 + nt0 + 1) * 64 + lane) * 8);
      acc0 = __builtin_amdgcn_mfma_f32_16x16x32_bf16(a[kb], b0, acc0, 0, 0, 0);
      acc1 = __builtin_amdgcn_mfma_f32_16x16x32_bf16(a[kb], b1, acc1, 0, 0, 0);
    }
    const int sE = mt * 4 + quad;   // C rows quad*4+r -> sample sE, step r
    float dirv[4], maskv[4];
#pragma unroll
    for (int r = 0; r < 4; r++) {
      dirv[r]  = dirsp[(b8 + sE) * 4 + r];
      maskv[r] = maskp[(b8 + sE) * 4 + r];
    }
#pragma unroll
    for (int tt = 0; tt < 2; tt++) {
      f32x4 c = tt ? acc1 : acc0;
      int col = (nt0 + tt) * 16 + c15;
#pragma unroll
      for (int r = 0; r < 4; r++) {
        float v = c[r] + dirv[r] * sPB[64 + col] + sPB[col];
        v = fmaxf(v, 0.f) * maskv[r];
        sX[mt * 16 + quad * 4 + r][col] = f2b(v);
      }
    }
  }
  __syncthreads();

  // ---- gi via MFMA: gi[d] = X(32x64) @ Wih_d(64x96), + bih ----
  {
    const int mt = w >> 1;
    const int ntb = (w & 1) * 3;
    short8 a[2];
#pragma unroll
    for (int kb = 0; kb < 2; kb++)
      a[kb] = *(const short8*)&sX[mt * 16 + c15][kb * 32 + quad * 8];
#pragma unroll
    for (int d = 0; d < 2; d++) {
#pragma unroll
      for (int t2 = 0; t2 < 3; t2++) {
        int nt = ntb + t2;
        f32x4 acc = {0.f,0.f,0.f,0.f};
#pragma unroll
        for (int kb = 0; kb < 2; kb++) {
          short8 bb = *(const short8*)(fragIH + ((d * 12 + kb * 6 + nt) * 64 + lane) * 8);
          acc = __builtin_amdgcn_mfma_f32_16x16x32_bf16(a[kb], bb, acc, 0, 0, 0);
        }
        int col = nt * 16 + c15;
        float bi = sBI[d][col];
#pragma unroll
        for (int r = 0; r < 4; r++)
          sgi[d][mt * 16 + quad * 4 + r][col] = f2b(acc[r] + bi);
      }
    }
  }

  // ---- sequential GRU (gh only): thread = (slg, d, u); 2 samples/thread ----
  {
    const int u = tid & 31;
    const int d = (tid >> 5) & 1;
    const int slg = tid >> 6;          // samples slg, slg+4
    const float* Whh = d ? Whh_b : Whh_f;
    sH[d][slg][u] = 0.f; sH[d][slg + 4][u] = 0.f;
    __syncthreads();                   // also covers sgi writes above
    for (int step = 0; step < 4; step++) {
      const int k = d ? (3 - step) : step;
      float ghr0 = sBH[d][u],      ghr1 = ghr0;
      float ghz0 = sBH[d][32 + u], ghz1 = ghz0;
      float ghn0 = sBH[d][64 + u], ghn1 = ghn0;
      for (int i = 0; i < 32; i++) {
        const float* wr = Whh + i * 96 + u;
        float w0 = wr[0], w1 = wr[32], w2 = wr[64];
        float ha = sH[d][slg][i], hb = sH[d][slg + 4][i];
        ghr0 += ha * w0; ghz0 += ha * w1; ghn0 += ha * w2;
        ghr1 += hb * w0; ghz1 += hb * w1; ghn1 += hb * w2;
      }
      float r0 = sigm(b2f_u(sgi[d][slg * 4 + k][u]) + ghr0);
      float z0 = sigm(b2f_u(sgi[d][slg * 4 + k][32 + u]) + ghz0);
      float n0 = tanhf(b2f_u(sgi[d][slg * 4 + k][64 + u]) + r0 * ghn0);
      float hn0 = (1.f - z0) * n0 + z0 * sH[d][slg][u];
      float r1 = sigm(b2f_u(sgi[d][(slg + 4) * 4 + k][u]) + ghr1);
      float z1 = sigm(b2f_u(sgi[d][(slg + 4) * 4 + k][32 + u]) + ghz1);
      float n1 = tanhf(b2f_u(sgi[d][(slg + 4) * 4 + k][64 + u]) + r1 * ghn1);
      float hn1 = (1.f - z1) * n1 + z1 * sH[d][slg + 4][u];
      __syncthreads();
      sH[d][slg][u] = hn0; sH[d][slg + 4][u] = hn1;
      __syncthreads();
    }
  }

  // ---- build sCat rows 0..7 = [self_emb | h_f | h_b] ----
  for (int i = tid; i < 8 * 128; i += 256) {
    int s = i >> 7, cc = i & 127;
    sCat[s][cc] = f2b(emb[(b8 + s) * 5 * 128 + cc]);
  }
  for (int i = tid; i < 512; i += 256) {
    int s = i >> 6, j = i & 63;
    float hv = (j < 32) ? sH[0][s][j] : sH[1][s][j - 32];
    sCat[s][128 + j] = f2b(hv);
  }
  __syncthreads();

  // ---- out head via MFMA: net(8x64) = cat(8x192) @ W_out ----
  {
    const int nt = w;
    f32x4 acc = {0.f,0.f,0.f,0.f};
#pragma unroll
    for (int kb = 0; kb < 6; kb++) {
      short8 a = *(const short8*)&sCat[c15][kb * 32 + quad * 8];
      short8 bb = *(const short8*)(fragO + ((kb * 4 + nt) * 64 + lane) * 8);
      acc = __builtin_amdgcn_mfma_f32_16x16x32_bf16(a, bb, acc, 0, 0, 0);
    }
    if (quad < 2) {
      int col = nt * 16 + c15;
#pragma unroll
      for (int r = 0; r < 4; r++) {
        int m = quad * 4 + r;      // sample index < 8
        out[(b8 + m) * 192 + 128 + col] = fmaxf(acc[r] + sBO[col], 0.f);
      }
    }
  }
  // ---- self_emb passthrough (f32 exact) ----
  for (int i = tid; i < 8 * 128; i += 256) {
    int s = i >> 7, cc = i & 127;
    out[(b8 + s) * 192 + cc] = emb[(b8 + s) * 5 * 128 + cc];
  }
}

// ---------------------------------------------------------------------------
extern "C" void kernel_launch(void* const* d_in, const int* in_sizes, int n_in,
                              void* d_out, int out_size, void* d_ws, size_t ws_size,
                              hipStream_t stream) {
  const float* self_f  = (const float*)d_in[0];
  const float* nbr_f   = (const float*)d_in[1];
  const float* maskp   = (const float*)d_in[2];
  const float* dirsp   = (const float*)d_in[3];
  const float* W_coop  = (const float*)d_in[4];
  const float* as_coop = (const float*)d_in[5];
  const float* ad_coop = (const float*)d_in[6];
  const float* W_conf  = (const float*)d_in[7];
  const float* as_conf = (const float*)d_in[8];
  const float* ad_conf = (const float*)d_in[9];
  const float* W_fuse  = (const float*)d_in[10];
  const float* b_fuse  = (const float*)d_in[11];
  const float* W_proj  = (const float*)d_in[12];
  const float* b_proj  = (const float*)d_in[13];
  const float* Wih_f   = (const float*)d_in[14];
  const float* Whh_f   = (const float*)d_in[15];
  const float* bih_f   = (const float*)d_in[16];
  const float* bhh_f   = (const float*)d_in[17];
  const float* Wih_b   = (const float*)d_in[18];
  const float* Whh_b   = (const float*)d_in[19];
  const float* bih_b   = (const float*)d_in[20];
  const float* bhh_b   = (const float*)d_in[21];
  const float* W_out   = (const float*)d_in[22];
  const float* b_out   = (const float*)d_in[23];

  const int B = in_sizes[0] / 48;   // 8192
  char* ws = (char*)d_ws;
  unsigned short* fragB  = (unsigned short*)(ws);            // 65536 B
  unsigned short* fragW  = (unsigned short*)(ws + 65536);    // 16384 B
  float*          Wa     = (float*)(ws + 81920);             // 256 B
  unsigned short* fragP  = (unsigned short*)(ws + 82176);    // 16384 B
  unsigned short* fragIH = (unsigned short*)(ws + 98560);    // 24576 B
  unsigned short* fragO  = (unsigned short*)(ws + 123136);   // 24576 B
  float*          emb    = (float*)(ws + 147712);            // B*5*128*4

  prepack_kernel<<<37, 256, 0, stream>>>(
      W_fuse, W_coop, W_conf, as_coop, ad_coop, as_conf, ad_conf,
      W_proj, Wih_f, Wih_b, W_out,
      fragB, fragW, Wa, fragP, fragIH, fragO);

  gat_fuse_kernel<<<B * 5 / 2, 128, 0, stream>>>(
      self_f, nbr_f, Wa, fragW, fragB, b_fuse, emb);

  head_kernel<<<B / 8, 256, 0, stream>>>(
      emb, maskp, dirsp, W_proj, b_proj, fragP, fragIH,
      bih_f, bhh_f, bih_b, bhh_b, Whh_f, Whh_b,
      fragO, b_out, (float*)d_out);
}

// Round 10
// 297.130 us; speedup vs baseline: 21.2010x; 1.3004x over previous
//
#include <hip/hip_runtime.h>
#include <math.h>

typedef short short8 __attribute__((ext_vector_type(8)));
typedef float f32x4  __attribute__((ext_vector_type(4)));

__device__ __forceinline__ unsigned short f2b(float f) {
  union { float f; unsigned int u; } x; x.f = f;
  return (unsigned short)((x.u + 0x7FFFu + ((x.u >> 16) & 1u)) >> 16);
}
__device__ __forceinline__ float b2f_u(unsigned short u) {
  union { unsigned int u; float f; } x; x.u = ((unsigned int)u) << 16;
  return x.f;
}
__device__ __forceinline__ unsigned int pk2(float a, float b) {
  return (unsigned int)f2b(a) | ((unsigned int)f2b(b) << 16);
}
__device__ __forceinline__ float sigm(float x) { return 1.f / (1.f + __expf(-x)); }

// ---------------------------------------------------------------------------
// Prepack (unchanged from round 9).
// ---------------------------------------------------------------------------
__global__ __launch_bounds__(256) void prepack_kernel(
    const float* __restrict__ Wf,
    const float* __restrict__ Wc, const float* __restrict__ Wn,
    const float* __restrict__ as_c, const float* __restrict__ ad_c,
    const float* __restrict__ as_n, const float* __restrict__ ad_n,
    const float* __restrict__ Wproj,
    const float* __restrict__ Wih_f, const float* __restrict__ Wih_b,
    const float* __restrict__ Wout,
    unsigned short* __restrict__ fragB,   // 4096*8
    unsigned short* __restrict__ fragW,   // 1024*8
    float* __restrict__ Wa,               // 64
    unsigned short* __restrict__ fragP,   // 1024*8
    unsigned short* __restrict__ fragIH,  // 1536*8
    unsigned short* __restrict__ fragO)   // 1536*8
{
  int e = blockIdx.x * 256 + threadIdx.x;
  unsigned short tmp[8];
  if (e < 4096) {
    int kb = e >> 9, tile = (e >> 6) & 7, lane = e & 63;
    int n = tile * 16 + (lane & 15);
    int kbase = kb * 32 + (lane >> 4) * 8;
#pragma unroll
    for (int j = 0; j < 8; j++) tmp[j] = f2b(Wf[(kbase + j) * 128 + n]);
    *(short8*)(fragB + e * 8) = *(short8*)tmp;
  } else if (e < 5120) {
    int i = e - 4096;
    int s = i >> 9, tile = (i >> 6) & 7, lane = i & 63;
    int c15 = lane & 15, quad = lane >> 4;
    int n = tile * 16 + c15;
    int h = n >> 5, o = n & 31;
    const float* W = s ? Wn : Wc;
#pragma unroll
    for (int j = 0; j < 8; j++) {
      int k = quad * 8 + j;
      tmp[j] = (k < 4) ? f2b(W[h * 128 + k * 32 + o]) : (unsigned short)0;
    }
    *(short8*)(fragW + i * 8) = *(short8*)tmp;
  } else if (e < 5184) {
    int i = e - 5120;
    int s = i >> 5, d = (i >> 4) & 1, h = (i >> 2) & 3, f = i & 3;
    const float* W = s ? Wn : Wc;
    const float* a = s ? (d ? ad_n : as_n) : (d ? ad_c : as_c);
    float acc = 0.f;
#pragma unroll
    for (int o = 0; o < 32; o++) acc += W[h * 128 + f * 32 + o] * a[h * 32 + o];
    Wa[i] = acc;
  } else if (e < 6208) {
    int i = e - 5184;
    int kb = i >> 8, nt = (i >> 6) & 3, lane = i & 63;
    int c15 = lane & 15, quad = lane >> 4;
#pragma unroll
    for (int j = 0; j < 8; j++)
      tmp[j] = f2b(Wproj[(kb * 32 + quad * 8 + j) * 64 + nt * 16 + c15]);
    *(short8*)(fragP + i * 8) = *(short8*)tmp;
  } else if (e < 7744) {
    int i = e - 6208;
    int d = (i >= 768), r = i - d * 768;
    int kb = r / 384, nt = (r >> 6) % 6, lane = r & 63;
    int c15 = lane & 15, quad = lane >> 4;
    const float* W = d ? Wih_b : Wih_f;
#pragma unroll
    for (int j = 0; j < 8; j++)
      tmp[j] = f2b(W[(kb * 32 + quad * 8 + j) * 96 + nt * 16 + c15]);
    *(short8*)(fragIH + i * 8) = *(short8*)tmp;
  } else if (e < 9280) {
    int r = e - 7744;
    int kb = r >> 8, nt = (r >> 6) & 3, lane = r & 63;
    int c15 = lane & 15, quad = lane >> 4;
#pragma unroll
    for (int j = 0; j < 8; j++)
      tmp[j] = f2b(Wout[(kb * 32 + quad * 8 + j) * 64 + nt * 16 + c15]);
    *(short8*)(fragO + r * 8) = *(short8*)tmp;
  }
}

// ---------------------------------------------------------------------------
// Kernel 1: GAT + fuse. 2 nodes per 256-thread block (4 waves).
// Waves = (stream, node) for Wh/PV; phase-4 fuse splits N-tiles across waves.
// LDS ~38.6 KB -> 4 blocks/CU = 16 waves/CU.
// ---------------------------------------------------------------------------
__global__ __launch_bounds__(256) void gat_fuse_kernel(
    const float* __restrict__ self_f, const float* __restrict__ nbr_f,
    const float* __restrict__ Wa,
    const unsigned short* __restrict__ fragW,
    const unsigned short* __restrict__ fragB,
    const float* __restrict__ b_fuse,
    float* __restrict__ emb)
{
  const int tid = threadIdx.x;
  const int w = tid >> 6, lane = tid & 63, c15 = lane & 15, quad = lane >> 4;
  const int n0 = blockIdx.x * 2;
  const int ws = w & 1;        // stream for phases 1/3
  const int wn = w >> 1;       // node for phases 1/3

  __shared__ __align__(16) unsigned short sxb[2][16][40];       // 2560 B
  __shared__ float sWa[64];                                     // 256 B
  __shared__ float sed[2][2][4][12];                            // 768 B
  __shared__ __align__(16) unsigned short sattb[2][2][4][16][34]; // 17408 B
  __shared__ __align__(16) unsigned short scatb[2][16][268];    // 17152 B
  __shared__ float sbias[128];                                  // 512 B

  // ---- phase 0: zero sxb (must be exact-zero outside the 48 values), stage
  {
    unsigned int* zx = (unsigned int*)sxb;   // 1280 u16 = 640 dwords
    for (int i = tid; i < 640; i += 256) zx[i] = 0u;
  }
  if (tid < 128) sbias[tid] = b_fuse[tid];
  if (tid < 64) sWa[tid] = Wa[tid];
  __syncthreads();
  if (tid < 96) {
    int nd = tid / 48, f = tid - nd * 48;
    int nn = n0 + nd, b = nn / 5, slot = nn - b * 5;
    float v = (slot == 0) ? self_f[b * 48 + f]
                          : nbr_f[(b * 4 + slot - 1) * 48 + f];
    sxb[nd][f >> 2][f & 3] = f2b(v);
  }
  __syncthreads();

  // ---- phase 1: Wh GEMM (wave = (ws,wn)) + logits (tid<192: g=node) ----
  unsigned int whpk[8][2];
  {
    short8 ax = *(const short8*)&sxb[wn][c15][quad * 8];
#pragma unroll
    for (int tile = 0; tile < 8; tile++) {
      short8 bw = *(const short8*)(fragW + ((ws * 8 + tile) * 64 + lane) * 8);
      f32x4 c = {0.f, 0.f, 0.f, 0.f};
      c = __builtin_amdgcn_mfma_f32_16x16x32_bf16(ax, bw, c, 0, 0, 0);
      whpk[tile][0] = pk2(c[0], c[1]);
      whpk[tile][1] = pk2(c[2], c[3]);
    }
  }
  float es_local = 0.f;
  if (tid < 192) {
    int g = tid / 96, r = tid - g * 96;
    int s = r / 48, r2 = r - s * 48;
    int h = r2 / 12, l = r2 - h * 12;
    float ed = 0.f;
#pragma unroll
    for (int f = 0; f < 4; f++) {
      float xv = b2f_u(sxb[g][l][f]);
      es_local += xv * sWa[s * 32 + h * 4 + f];
      ed       += xv * sWa[s * 32 + 16 + h * 4 + f];
    }
    sed[g][s][h][l] = ed;
  }
  __syncthreads();

  // ---- phase 2: masked softmax -> sattb (rows <12; 32 k-cols written) ----
  if (tid < 192) {
    int g = tid / 96, r = tid - g * 96;
    int s = r / 48, r2 = r - s * 48;
    int h = r2 / 12, i = r2 - h * 12;
    int blk = i / 3;
    float ev[12];
    float m = -1e30f;
#pragma unroll
    for (int j = 0; j < 12; j++) {
      bool allowed = (s == 0) ? ((j / 3) == blk) : ((j / 3) != blk);
      float e = es_local + sed[g][s][h][j];
      e = e > 0.f ? e : 0.2f * e;
      if (!allowed) e = -1e30f;
      ev[j] = e;
      m = fmaxf(m, e);
    }
    float sum = 0.f;
#pragma unroll
    for (int j = 0; j < 12; j++) {
      float a = (ev[j] > -1e29f) ? __expf(ev[j] - m) : 0.f;
      ev[j] = a;
      sum += a;
    }
    float inv = 1.f / sum;
    unsigned short tmp[32];
#pragma unroll
    for (int j = 0; j < 12; j++) tmp[j] = f2b(ev[j] * inv);
#pragma unroll
    for (int j = 12; j < 32; j++) tmp[j] = 0;
    const short8* src = (const short8*)tmp;
    unsigned short* dp = &sattb[g][s][h][i][0];
    *(short8*)(dp)      = src[0];
    *(short8*)(dp + 8)  = src[1];
    *(short8*)(dp + 16) = src[2];
    *(short8*)(dp + 24) = src[3];
  }
  __syncthreads();

  // ---- phase 3: PV via MFMA (wave = (ws,wn)); B-frags from whpk via shfl --
  {
    union U8 { unsigned int u[4]; short8 v; };
    const int sl0 = (32 * quad + c15) & 63;
    const int sl1 = (32 * quad + 16 + c15) & 63;
    const bool hiq = (quad >= 2);
#pragma unroll
    for (int h = 0; h < 4; h++) {
#pragma unroll
      for (int t2 = 0; t2 < 2; t2++) {
        short8 af = *(const short8*)&sattb[wn][ws][h][c15][quad * 8];
        unsigned int d0 = whpk[2 * h + t2][0], d1 = whpk[2 * h + t2][1];
        U8 bb;
        bb.u[0] = (unsigned int)__shfl((int)d0, sl0);
        bb.u[1] = (unsigned int)__shfl((int)d1, sl0);
        bb.u[2] = (unsigned int)__shfl((int)d0, sl1);
        bb.u[3] = (unsigned int)__shfl((int)d1, sl1);
        if (hiq) { bb.u[0] = 0; bb.u[1] = 0; bb.u[2] = 0; bb.u[3] = 0; }
        f32x4 c = {0.f, 0.f, 0.f, 0.f};
        c = __builtin_amdgcn_mfma_f32_16x16x32_bf16(af, bb.v, c, 0, 0, 0);
        if (quad < 3) {
          int co = ws * 128 + h * 32 + t2 * 16 + c15;
#pragma unroll
          for (int r = 0; r < 4; r++) {
            float v = c[r];
            v = v > 0.f ? v : (__expf(v) - 1.f);
            scatb[wn][quad * 4 + r][co] = f2b(v);
          }
        }
      }
    }
  }
  __syncthreads();

  // ---- phase 4: fuse GEMM; wave w covers N-tiles {2w,2w+1}, both nodes ----
  {
    f32x4 acc[2][2];
#pragma unroll
    for (int nd = 0; nd < 2; nd++)
#pragma unroll
      for (int tt = 0; tt < 2; tt++) acc[nd][tt] = (f32x4){0.f,0.f,0.f,0.f};
#pragma unroll
    for (int kb = 0; kb < 8; kb++) {
      short8 a0 = *(const short8*)&scatb[0][c15][kb * 32 + (quad << 3)];
      short8 a1 = *(const short8*)&scatb[1][c15][kb * 32 + (quad << 3)];
#pragma unroll
      for (int tt = 0; tt < 2; tt++) {
        short8 bw = *(const short8*)(fragB + ((kb * 8 + 2 * w + tt) * 64 + lane) * 8);
        acc[0][tt] = __builtin_amdgcn_mfma_f32_16x16x32_bf16(a0, bw, acc[0][tt], 0, 0, 0);
        acc[1][tt] = __builtin_amdgcn_mfma_f32_16x16x32_bf16(a1, bw, acc[1][tt], 0, 0, 0);
      }
    }
    // epilogue: bias+ELU, partial row-sum (quad<3), butterfly over quads
    float tot[2][2];
#pragma unroll
    for (int nd = 0; nd < 2; nd++) {
#pragma unroll
      for (int tt = 0; tt < 2; tt++) {
        float p = 0.f;
        if (quad < 3) {
          float bcol = sbias[w * 32 + tt * 16 + c15];
#pragma unroll
          for (int r = 0; r < 4; r++) {
            float v = acc[nd][tt][r] + bcol;
            v = v > 0.f ? v : (__expf(v) - 1.f);
            p += v;
          }
        }
        p += __shfl_xor(p, 16);
        p += __shfl_xor(p, 32);
        tot[nd][tt] = p;
      }
    }
    // lane (quad,c15): nd = quad>>1, tt = quad&1, col = w*32 + tt*16 + c15
    int ndw = quad >> 1, ttw = quad & 1;
    float val = ndw ? (ttw ? tot[1][1] : tot[1][0])
                    : (ttw ? tot[0][1] : tot[0][0]);
    emb[(n0 + ndw) * 128 + w * 32 + ttw * 16 + c15] = val * (1.f / 12.f);
  }
}

// ---------------------------------------------------------------------------
// Kernel 2: head (unchanged from round 9).
// ---------------------------------------------------------------------------
__global__ __launch_bounds__(256) void head_kernel(
    const float* __restrict__ emb,
    const float* __restrict__ maskp, const float* __restrict__ dirsp,
    const float* __restrict__ W_proj, const float* __restrict__ b_proj,
    const unsigned short* __restrict__ fragP,
    const unsigned short* __restrict__ fragIH,
    const float* __restrict__ bih_f, const float* __restrict__ bhh_f,
    const float* __restrict__ bih_b, const float* __restrict__ bhh_b,
    const float* __restrict__ Whh_f, const float* __restrict__ Whh_b,
    const unsigned short* __restrict__ fragO,
    const float* __restrict__ b_out,
    float* __restrict__ out)
{
  const int b8 = blockIdx.x * 8;
  const int tid = threadIdx.x;
  const int w = tid >> 6, lane = tid & 63, c15 = lane & 15, quad = lane >> 4;

  __shared__ __align__(16) unsigned short sX[32][72];
  __shared__ __align__(16) unsigned short sgi[2][32][104];
  __shared__ float sH[2][8][32];
  __shared__ __align__(16) unsigned short sCat[16][200];
  __shared__ float sPB[128];
  __shared__ float sBI[2][96], sBH[2][96], sBO[64];

  if (tid < 64) { sPB[tid] = b_proj[tid]; sPB[64 + tid] = W_proj[128 * 64 + tid]; sBO[tid] = b_out[tid]; }
  if (tid < 96) { sBI[0][tid] = bih_f[tid]; sBI[1][tid] = bih_b[tid];
                  sBH[0][tid] = bhh_f[tid]; sBH[1][tid] = bhh_b[tid]; }
  __syncthreads();

  {
    const int mt = w >> 1;
    const int nt0 = (w & 1) * 2;
    const int sloc = mt * 4 + (c15 >> 2);
    const int nbr  = c15 & 3;
    const float* arow = emb + (((b8 + sloc) * 5) + 1 + nbr) * 128;
    short8 a[4];
#pragma unroll
    for (int kb = 0; kb < 4; kb++) {
      const float* p = arow + kb * 32 + quad * 8;
      f32x4 v0 = *(const f32x4*)p;
      f32x4 v1 = *(const f32x4*)(p + 4);
      unsigned short tmp[8];
      tmp[0]=f2b(v0[0]); tmp[1]=f2b(v0[1]); tmp[2]=f2b(v0[2]); tmp[3]=f2b(v0[3]);
      tmp[4]=f2b(v1[0]); tmp[5]=f2b(v1[1]); tmp[6]=f2b(v1[2]); tmp[7]=f2b(v1[3]);
      a[kb] = *(short8*)tmp;
    }
    f32x4 acc0 = {0.f,0.f,0.f,0.f}, acc1 = acc0;
#pragma unroll
    for (int kb = 0; kb < 4; kb++) {
      short8 b0 = *(const short8*)(fragP + ((kb * 4 + nt0    ) * 64 + lane) * 8);
      short8 b1 = *(const short8*)(fragP + ((kb * 4 + nt0 + 1) * 64 + lane) * 8);
      acc0 = __builtin_amdgcn_mfma_f32_16x16x32_bf16(a[kb], b0, acc0, 0, 0, 0);
      acc1 = __builtin_amdgcn_mfma_f32_16x16x32_bf16(a[kb], b1, acc1, 0, 0, 0);
    }
    const int sE = mt * 4 + quad;
    float dirv[4], maskv[4];
#pragma unroll
    for (int r = 0; r < 4; r++) {
      dirv[r]  = dirsp[(b8 + sE) * 4 + r];
      maskv[r] = maskp[(b8 + sE) * 4 + r];
    }
#pragma unroll
    for (int tt = 0; tt < 2; tt++) {
      f32x4 c = tt ? acc1 : acc0;
      int col = (nt0 + tt) * 16 + c15;
#pragma unroll
      for (int r = 0; r < 4; r++) {
        float v = c[r] + dirv[r] * sPB[64 + col] + sPB[col];
        v = fmaxf(v, 0.f) * maskv[r];
        sX[mt * 16 + quad * 4 + r][col] = f2b(v);
      }
    }
  }
  __syncthreads();

  {
    const int mt = w >> 1;
    const int ntb = (w & 1) * 3;
    short8 a[2];
#pragma unroll
    for (int kb = 0; kb < 2; kb++)
      a[kb] = *(const short8*)&sX[mt * 16 + c15][kb * 32 + quad * 8];
#pragma unroll
    for (int d = 0; d < 2; d++) {
#pragma unroll
      for (int t2 = 0; t2 < 3; t2++) {
        int nt = ntb + t2;
        f32x4 acc = {0.f,0.f,0.f,0.f};
#pragma unroll
        for (int kb = 0; kb < 2; kb++) {
          short8 bb = *(const short8*)(fragIH + ((d * 12 + kb * 6 + nt) * 64 + lane) * 8);
          acc = __builtin_amdgcn_mfma_f32_16x16x32_bf16(a[kb], bb, acc, 0, 0, 0);
        }
        int col = nt * 16 + c15;
        float bi = sBI[d][col];
#pragma unroll
        for (int r = 0; r < 4; r++)
          sgi[d][mt * 16 + quad * 4 + r][col] = f2b(acc[r] + bi);
      }
    }
  }

  {
    const int u = tid & 31;
    const int d = (tid >> 5) & 1;
    const int slg = tid >> 6;
    const float* Whh = d ? Whh_b : Whh_f;
    sH[d][slg][u] = 0.f; sH[d][slg + 4][u] = 0.f;
    __syncthreads();
    for (int step = 0; step < 4; step++) {
      const int k = d ? (3 - step) : step;
      float ghr0 = sBH[d][u],      ghr1 = ghr0;
      float ghz0 = sBH[d][32 + u], ghz1 = ghz0;
      float ghn0 = sBH[d][64 + u], ghn1 = ghn0;
      for (int i = 0; i < 32; i++) {
        const float* wr = Whh + i * 96 + u;
        float w0 = wr[0], w1 = wr[32], w2 = wr[64];
        float ha = sH[d][slg][i], hb = sH[d][slg + 4][i];
        ghr0 += ha * w0; ghz0 += ha * w1; ghn0 += ha * w2;
        ghr1 += hb * w0; ghz1 += hb * w1; ghn1 += hb * w2;
      }
      float r0 = sigm(b2f_u(sgi[d][slg * 4 + k][u]) + ghr0);
      float z0 = sigm(b2f_u(sgi[d][slg * 4 + k][32 + u]) + ghz0);
      float n0 = tanhf(b2f_u(sgi[d][slg * 4 + k][64 + u]) + r0 * ghn0);
      float hn0 = (1.f - z0) * n0 + z0 * sH[d][slg][u];
      float r1 = sigm(b2f_u(sgi[d][(slg + 4) * 4 + k][u]) + ghr1);
      float z1 = sigm(b2f_u(sgi[d][(slg + 4) * 4 + k][32 + u]) + ghz1);
      float n1 = tanhf(b2f_u(sgi[d][(slg + 4) * 4 + k][64 + u]) + r1 * ghn1);
      float hn1 = (1.f - z1) * n1 + z1 * sH[d][slg + 4][u];
      __syncthreads();
      sH[d][slg][u] = hn0; sH[d][slg + 4][u] = hn1;
      __syncthreads();
    }
  }

  for (int i = tid; i < 8 * 128; i += 256) {
    int s = i >> 7, cc = i & 127;
    sCat[s][cc] = f2b(emb[(b8 + s) * 5 * 128 + cc]);
  }
  for (int i = tid; i < 512; i += 256) {
    int s = i >> 6, j = i & 63;
    float hv = (j < 32) ? sH[0][s][j] : sH[1][s][j - 32];
    sCat[s][128 + j] = f2b(hv);
  }
  __syncthreads();

  {
    const int nt = w;
    f32x4 acc = {0.f,0.f,0.f,0.f};
#pragma unroll
    for (int kb = 0; kb < 6; kb++) {
      short8 a = *(const short8*)&sCat[c15][kb * 32 + quad * 8];
      short8 bb = *(const short8*)(fragO + ((kb * 4 + nt) * 64 + lane) * 8);
      acc = __builtin_amdgcn_mfma_f32_16x16x32_bf16(a, bb, acc, 0, 0, 0);
    }
    if (quad < 2) {
      int col = nt * 16 + c15;
#pragma unroll
      for (int r = 0; r < 4; r++) {
        int m = quad * 4 + r;
        out[(b8 + m) * 192 + 128 + col] = fmaxf(acc[r] + sBO[col], 0.f);
      }
    }
  }
  for (int i = tid; i < 8 * 128; i += 256) {
    int s = i >> 7, cc = i & 127;
    out[(b8 + s) * 192 + cc] = emb[(b8 + s) * 5 * 128 + cc];
  }
}

// ---------------------------------------------------------------------------
extern "C" void kernel_launch(void* const* d_in, const int* in_sizes, int n_in,
                              void* d_out, int out_size, void* d_ws, size_t ws_size,
                              hipStream_t stream) {
  const float* self_f  = (const float*)d_in[0];
  const float* nbr_f   = (const float*)d_in[1];
  const float* maskp   = (const float*)d_in[2];
  const float* dirsp   = (const float*)d_in[3];
  const float* W_coop  = (const float*)d_in[4];
  const float* as_coop = (const float*)d_in[5];
  const float* ad_coop = (const float*)d_in[6];
  const float* W_conf  = (const float*)d_in[7];
  const float* as_conf = (const float*)d_in[8];
  const float* ad_conf = (const float*)d_in[9];
  const float* W_fuse  = (const float*)d_in[10];
  const float* b_fuse  = (const float*)d_in[11];
  const float* W_proj  = (const float*)d_in[12];
  const float* b_proj  = (const float*)d_in[13];
  const float* Wih_f   = (const float*)d_in[14];
  const float* Whh_f   = (const float*)d_in[15];
  const float* bih_f   = (const float*)d_in[16];
  const float* bhh_f   = (const float*)d_in[17];
  const float* Wih_b   = (const float*)d_in[18];
  const float* Whh_b   = (const float*)d_in[19];
  const float* bih_b   = (const float*)d_in[20];
  const float* bhh_b   = (const float*)d_in[21];
  const float* W_out   = (const float*)d_in[22];
  const float* b_out   = (const float*)d_in[23];

  const int B = in_sizes[0] / 48;   // 8192
  char* ws = (char*)d_ws;
  unsigned short* fragB  = (unsigned short*)(ws);            // 65536 B
  unsigned short* fragW  = (unsigned short*)(ws + 65536);    // 16384 B
  float*          Wa     = (float*)(ws + 81920);             // 256 B
  unsigned short* fragP  = (unsigned short*)(ws + 82176);    // 16384 B
  unsigned short* fragIH = (unsigned short*)(ws + 98560);    // 24576 B
  unsigned short* fragO  = (unsigned short*)(ws + 123136);   // 24576 B
  float*          emb    = (float*)(ws + 147712);            // B*5*128*4

  prepack_kernel<<<37, 256, 0, stream>>>(
      W_fuse, W_coop, W_conf, as_coop, ad_coop, as_conf, ad_conf,
      W_proj, Wih_f, Wih_b, W_out,
      fragB, fragW, Wa, fragP, fragIH, fragO);

  gat_fuse_kernel<<<B * 5 / 2, 256, 0, stream>>>(
      self_f, nbr_f, Wa, fragW, fragB, b_fuse, emb);

  head_kernel<<<B / 8, 256, 0, stream>>>(
      emb, maskp, dirsp, W_proj, b_proj, fragP, fragIH,
      bih_f, bhh_f, bih_b, bhh_b, Whh_f, Whh_b,
      fragO, b_out, (float*)d_out);
}

// Round 11
// 281.541 us; speedup vs baseline: 22.3750x; 1.0554x over previous
//
#include <hip/hip_runtime.h>
#include <math.h>

typedef short short8 __attribute__((ext_vector_type(8)));
typedef float f32x4  __attribute__((ext_vector_type(4)));

__device__ __forceinline__ unsigned short f2b(float f) {
  union { float f; unsigned int u; } x; x.f = f;
  return (unsigned short)((x.u + 0x7FFFu + ((x.u >> 16) & 1u)) >> 16);
}
__device__ __forceinline__ float b2f_u(unsigned short u) {
  union { unsigned int u; float f; } x; x.u = ((unsigned int)u) << 16;
  return x.f;
}
__device__ __forceinline__ unsigned int pk2(float a, float b) {
  return (unsigned int)f2b(a) | ((unsigned int)f2b(b) << 16);
}
__device__ __forceinline__ float sigm(float x) { return 1.f / (1.f + __expf(-x)); }

// ---------------------------------------------------------------------------
// Prepack (unchanged from round 9/10).
// ---------------------------------------------------------------------------
__global__ __launch_bounds__(256) void prepack_kernel(
    const float* __restrict__ Wf,
    const float* __restrict__ Wc, const float* __restrict__ Wn,
    const float* __restrict__ as_c, const float* __restrict__ ad_c,
    const float* __restrict__ as_n, const float* __restrict__ ad_n,
    const float* __restrict__ Wproj,
    const float* __restrict__ Wih_f, const float* __restrict__ Wih_b,
    const float* __restrict__ Wout,
    unsigned short* __restrict__ fragB,
    unsigned short* __restrict__ fragW,
    float* __restrict__ Wa,
    unsigned short* __restrict__ fragP,
    unsigned short* __restrict__ fragIH,
    unsigned short* __restrict__ fragO)
{
  int e = blockIdx.x * 256 + threadIdx.x;
  unsigned short tmp[8];
  if (e < 4096) {
    int kb = e >> 9, tile = (e >> 6) & 7, lane = e & 63;
    int n = tile * 16 + (lane & 15);
    int kbase = kb * 32 + (lane >> 4) * 8;
#pragma unroll
    for (int j = 0; j < 8; j++) tmp[j] = f2b(Wf[(kbase + j) * 128 + n]);
    *(short8*)(fragB + e * 8) = *(short8*)tmp;
  } else if (e < 5120) {
    int i = e - 4096;
    int s = i >> 9, tile = (i >> 6) & 7, lane = i & 63;
    int c15 = lane & 15, quad = lane >> 4;
    int n = tile * 16 + c15;
    int h = n >> 5, o = n & 31;
    const float* W = s ? Wn : Wc;
#pragma unroll
    for (int j = 0; j < 8; j++) {
      int k = quad * 8 + j;
      tmp[j] = (k < 4) ? f2b(W[h * 128 + k * 32 + o]) : (unsigned short)0;
    }
    *(short8*)(fragW + i * 8) = *(short8*)tmp;
  } else if (e < 5184) {
    int i = e - 5120;
    int s = i >> 5, d = (i >> 4) & 1, h = (i >> 2) & 3, f = i & 3;
    const float* W = s ? Wn : Wc;
    const float* a = s ? (d ? ad_n : as_n) : (d ? ad_c : as_c);
    float acc = 0.f;
#pragma unroll
    for (int o = 0; o < 32; o++) acc += W[h * 128 + f * 32 + o] * a[h * 32 + o];
    Wa[i] = acc;
  } else if (e < 6208) {
    int i = e - 5184;
    int kb = i >> 8, nt = (i >> 6) & 3, lane = i & 63;
    int c15 = lane & 15, quad = lane >> 4;
#pragma unroll
    for (int j = 0; j < 8; j++)
      tmp[j] = f2b(Wproj[(kb * 32 + quad * 8 + j) * 64 + nt * 16 + c15]);
    *(short8*)(fragP + i * 8) = *(short8*)tmp;
  } else if (e < 7744) {
    int i = e - 6208;
    int d = (i >= 768), r = i - d * 768;
    int kb = r / 384, nt = (r >> 6) % 6, lane = r & 63;
    int c15 = lane & 15, quad = lane >> 4;
    const float* W = d ? Wih_b : Wih_f;
#pragma unroll
    for (int j = 0; j < 8; j++)
      tmp[j] = f2b(W[(kb * 32 + quad * 8 + j) * 96 + nt * 16 + c15]);
    *(short8*)(fragIH + i * 8) = *(short8*)tmp;
  } else if (e < 9280) {
    int r = e - 7744;
    int kb = r >> 8, nt = (r >> 6) & 3, lane = r & 63;
    int c15 = lane & 15, quad = lane >> 4;
#pragma unroll
    for (int j = 0; j < 8; j++)
      tmp[j] = f2b(Wout[(kb * 32 + quad * 8 + j) * 64 + nt * 16 + c15]);
    *(short8*)(fragO + r * 8) = *(short8*)tmp;
  }
}

// ---------------------------------------------------------------------------
// Kernel 1: GAT + fuse. 2 nodes per 256-thread block (4 waves).
// LDS ~31.9 KB -> 5 blocks/CU = 20 waves/CU. Zero-quads use constant regs
// instead of LDS zeros (quad>=1 of x-frag, quad>=2 of att-frag).
// ---------------------------------------------------------------------------
__global__ __launch_bounds__(256) void gat_fuse_kernel(
    const float* __restrict__ self_f, const float* __restrict__ nbr_f,
    const float* __restrict__ Wa,
    const unsigned short* __restrict__ fragW,
    const unsigned short* __restrict__ fragB,
    const float* __restrict__ b_fuse,
    float* __restrict__ emb)
{
  const int tid = threadIdx.x;
  const int w = tid >> 6, lane = tid & 63, c15 = lane & 15, quad = lane >> 4;
  const int n0 = blockIdx.x * 2;
  const int ws = w & 1;        // stream for phases 1/3
  const int wn = w >> 1;       // node for phases 1/3

  __shared__ __align__(16) unsigned short sxb[2][16][16];         // 1024 B
  __shared__ float sWa[64];                                       // 256 B
  __shared__ float sed[2][2][4][12];                              // 768 B
  __shared__ __align__(16) unsigned short sattb[2][2][4][16][24]; // 12288 B
  __shared__ __align__(16) unsigned short scatb[2][16][268];      // 17152 B
  __shared__ float sbias[128];                                    // 512 B

  // ---- phase 0: zero sxb (rows>=12 and k>=4 must be exact zero), stage ----
  {
    unsigned int* zx = (unsigned int*)sxb;   // 512 u16 = 256 dwords
    if (tid < 256) zx[tid] = 0u;
  }
  if (tid < 128) sbias[tid] = b_fuse[tid];
  if (tid < 64) sWa[tid] = Wa[tid];
  __syncthreads();
  if (tid < 96) {
    int nd = tid / 48, f = tid - nd * 48;
    int nn = n0 + nd, b = nn / 5, slot = nn - b * 5;
    float v = (slot == 0) ? self_f[b * 48 + f]
                          : nbr_f[(b * 4 + slot - 1) * 48 + f];
    sxb[nd][f >> 2][f & 3] = f2b(v);
  }
  __syncthreads();

  const short8 z8 = {0,0,0,0,0,0,0,0};

  // ---- phase 1: Wh GEMM (wave = (ws,wn)) + logits ----
  unsigned int whpk[8][2];
  {
    short8 ax = z8;
    if (quad == 0) ax = *(const short8*)&sxb[wn][c15][0];
#pragma unroll
    for (int tile = 0; tile < 8; tile++) {
      short8 bw = *(const short8*)(fragW + ((ws * 8 + tile) * 64 + lane) * 8);
      f32x4 c = {0.f, 0.f, 0.f, 0.f};
      c = __builtin_amdgcn_mfma_f32_16x16x32_bf16(ax, bw, c, 0, 0, 0);
      whpk[tile][0] = pk2(c[0], c[1]);
      whpk[tile][1] = pk2(c[2], c[3]);
    }
  }
  float es_local = 0.f;
  if (tid < 192) {
    int g = tid / 96, r = tid - g * 96;
    int s = r / 48, r2 = r - s * 48;
    int h = r2 / 12, l = r2 - h * 12;
    float ed = 0.f;
#pragma unroll
    for (int f = 0; f < 4; f++) {
      float xv = b2f_u(sxb[g][l][f]);
      es_local += xv * sWa[s * 32 + h * 4 + f];
      ed       += xv * sWa[s * 32 + 16 + h * 4 + f];
    }
    sed[g][s][h][l] = ed;
  }
  __syncthreads();

  // ---- phase 2: masked softmax -> sattb rows i<12, 16 k-entries (4 zero) --
  if (tid < 192) {
    int g = tid / 96, r = tid - g * 96;
    int s = r / 48, r2 = r - s * 48;
    int h = r2 / 12, i = r2 - h * 12;
    int blk = i / 3;
    float ev[12];
    float m = -1e30f;
#pragma unroll
    for (int j = 0; j < 12; j++) {
      bool allowed = (s == 0) ? ((j / 3) == blk) : ((j / 3) != blk);
      float e = es_local + sed[g][s][h][j];
      e = e > 0.f ? e : 0.2f * e;
      if (!allowed) e = -1e30f;
      ev[j] = e;
      m = fmaxf(m, e);
    }
    float sum = 0.f;
#pragma unroll
    for (int j = 0; j < 12; j++) {
      float a = (ev[j] > -1e29f) ? __expf(ev[j] - m) : 0.f;
      ev[j] = a;
      sum += a;
    }
    float inv = 1.f / sum;
    unsigned short tmp[16];
#pragma unroll
    for (int j = 0; j < 12; j++) tmp[j] = f2b(ev[j] * inv);
#pragma unroll
    for (int j = 12; j < 16; j++) tmp[j] = 0;
    const short8* src = (const short8*)tmp;
    unsigned short* dp = &sattb[g][s][h][i][0];
    *(short8*)(dp)     = src[0];
    *(short8*)(dp + 8) = src[1];
  }
  __syncthreads();

  // ---- phase 3: PV via MFMA (wave = (ws,wn)); B-frags from whpk via shfl --
  {
    union U8 { unsigned int u[4]; short8 v; };
    const int sl0 = (32 * quad + c15) & 63;
    const int sl1 = (32 * quad + 16 + c15) & 63;
    const bool hiq = (quad >= 2);
#pragma unroll
    for (int h = 0; h < 4; h++) {
#pragma unroll
      for (int t2 = 0; t2 < 2; t2++) {
        short8 af = z8;
        if (!hiq) af = *(const short8*)&sattb[wn][ws][h][c15][quad * 8];
        unsigned int d0 = whpk[2 * h + t2][0], d1 = whpk[2 * h + t2][1];
        U8 bb;
        bb.u[0] = (unsigned int)__shfl((int)d0, sl0);
        bb.u[1] = (unsigned int)__shfl((int)d1, sl0);
        bb.u[2] = (unsigned int)__shfl((int)d0, sl1);
        bb.u[3] = (unsigned int)__shfl((int)d1, sl1);
        if (hiq) { bb.u[0] = 0; bb.u[1] = 0; bb.u[2] = 0; bb.u[3] = 0; }
        f32x4 c = {0.f, 0.f, 0.f, 0.f};
        c = __builtin_amdgcn_mfma_f32_16x16x32_bf16(af, bb.v, c, 0, 0, 0);
        if (quad < 3) {
          int co = ws * 128 + h * 32 + t2 * 16 + c15;
#pragma unroll
          for (int r = 0; r < 4; r++) {
            float v = c[r];
            v = v > 0.f ? v : (__expf(v) - 1.f);
            scatb[wn][quad * 4 + r][co] = f2b(v);
          }
        }
      }
    }
  }
  __syncthreads();

  // ---- phase 4: fuse GEMM; wave w covers N-tiles {2w,2w+1}, both nodes ----
  {
    f32x4 acc[2][2];
#pragma unroll
    for (int nd = 0; nd < 2; nd++)
#pragma unroll
      for (int tt = 0; tt < 2; tt++) acc[nd][tt] = (f32x4){0.f,0.f,0.f,0.f};
#pragma unroll
    for (int kb = 0; kb < 8; kb++) {
      short8 a0 = *(const short8*)&scatb[0][c15][kb * 32 + (quad << 3)];
      short8 a1 = *(const short8*)&scatb[1][c15][kb * 32 + (quad << 3)];
#pragma unroll
      for (int tt = 0; tt < 2; tt++) {
        short8 bw = *(const short8*)(fragB + ((kb * 8 + 2 * w + tt) * 64 + lane) * 8);
        acc[0][tt] = __builtin_amdgcn_mfma_f32_16x16x32_bf16(a0, bw, acc[0][tt], 0, 0, 0);
        acc[1][tt] = __builtin_amdgcn_mfma_f32_16x16x32_bf16(a1, bw, acc[1][tt], 0, 0, 0);
      }
    }
    float tot[2][2];
#pragma unroll
    for (int nd = 0; nd < 2; nd++) {
#pragma unroll
      for (int tt = 0; tt < 2; tt++) {
        float p = 0.f;
        if (quad < 3) {
          float bcol = sbias[w * 32 + tt * 16 + c15];
#pragma unroll
          for (int r = 0; r < 4; r++) {
            float v = acc[nd][tt][r] + bcol;
            v = v > 0.f ? v : (__expf(v) - 1.f);
            p += v;
          }
        }
        p += __shfl_xor(p, 16);
        p += __shfl_xor(p, 32);
        tot[nd][tt] = p;
      }
    }
    int ndw = quad >> 1, ttw = quad & 1;
    float val = ndw ? (ttw ? tot[1][1] : tot[1][0])
                    : (ttw ? tot[0][1] : tot[0][0]);
    emb[(n0 + ndw) * 128 + w * 32 + ttw * 16 + c15] = val * (1.f / 12.f);
  }
}

// ---------------------------------------------------------------------------
// Kernel 2: head; Whh staged in LDS as bf16 (exact — values bf16-clean).
// LDS ~39.9 KB -> 4 blocks/CU (grid = exactly 4/CU, single shot).
// ---------------------------------------------------------------------------
__global__ __launch_bounds__(256) void head_kernel(
    const float* __restrict__ emb,
    const float* __restrict__ maskp, const float* __restrict__ dirsp,
    const float* __restrict__ W_proj, const float* __restrict__ b_proj,
    const unsigned short* __restrict__ fragP,
    const unsigned short* __restrict__ fragIH,
    const float* __restrict__ bih_f, const float* __restrict__ bhh_f,
    const float* __restrict__ bih_b, const float* __restrict__ bhh_b,
    const float* __restrict__ Whh_f, const float* __restrict__ Whh_b,
    const unsigned short* __restrict__ fragO,
    const float* __restrict__ b_out,
    float* __restrict__ out)
{
  const int b8 = blockIdx.x * 8;
  const int tid = threadIdx.x;
  const int w = tid >> 6, lane = tid & 63, c15 = lane & 15, quad = lane >> 4;

  __shared__ __align__(16) unsigned short sX[32][72];        // 4608 B
  __shared__ __align__(16) unsigned short sgi[2][32][96];    // 12288 B
  __shared__ float sH[2][8][32];                             // 2048 B
  __shared__ __align__(16) unsigned short sCat[16][200];     // 6400 B
  __shared__ unsigned short sWhh[2][32][96];                 // 12288 B
  __shared__ float sPB[128];
  __shared__ float sBI[2][96], sBH[2][96], sBO[64];

  if (tid < 64) { sPB[tid] = b_proj[tid]; sPB[64 + tid] = W_proj[128 * 64 + tid]; sBO[tid] = b_out[tid]; }
  if (tid < 96) { sBI[0][tid] = bih_f[tid]; sBI[1][tid] = bih_b[tid];
                  sBH[0][tid] = bhh_f[tid]; sBH[1][tid] = bhh_b[tid]; }
  for (int i = tid; i < 3072; i += 256) {
    sWhh[0][0][i] = f2b(Whh_f[i]);
    sWhh[1][0][i] = f2b(Whh_b[i]);
  }
  __syncthreads();

  // ---- proj via MFMA ----
  {
    const int mt = w >> 1;
    const int nt0 = (w & 1) * 2;
    const int sloc = mt * 4 + (c15 >> 2);
    const int nbr  = c15 & 3;
    const float* arow = emb + (((b8 + sloc) * 5) + 1 + nbr) * 128;
    short8 a[4];
#pragma unroll
    for (int kb = 0; kb < 4; kb++) {
      const float* p = arow + kb * 32 + quad * 8;
      f32x4 v0 = *(const f32x4*)p;
      f32x4 v1 = *(const f32x4*)(p + 4);
      unsigned short tmp[8];
      tmp[0]=f2b(v0[0]); tmp[1]=f2b(v0[1]); tmp[2]=f2b(v0[2]); tmp[3]=f2b(v0[3]);
      tmp[4]=f2b(v1[0]); tmp[5]=f2b(v1[1]); tmp[6]=f2b(v1[2]); tmp[7]=f2b(v1[3]);
      a[kb] = *(short8*)tmp;
    }
    f32x4 acc0 = {0.f,0.f,0.f,0.f}, acc1 = acc0;
#pragma unroll
    for (int kb = 0; kb < 4; kb++) {
      short8 b0 = *(const short8*)(fragP + ((kb * 4 + nt0    ) * 64 + lane) * 8);
      short8 b1 = *(const short8*)(fragP + ((kb * 4 + nt0 + 1) * 64 + lane) * 8);
      acc0 = __builtin_amdgcn_mfma_f32_16x16x32_bf16(a[kb], b0, acc0, 0, 0, 0);
      acc1 = __builtin_amdgcn_mfma_f32_16x16x32_bf16(a[kb], b1, acc1, 0, 0, 0);
    }
    const int sE = mt * 4 + quad;
    float dirv[4], maskv[4];
#pragma unroll
    for (int r = 0; r < 4; r++) {
      dirv[r]  = dirsp[(b8 + sE) * 4 + r];
      maskv[r] = maskp[(b8 + sE) * 4 + r];
    }
#pragma unroll
    for (int tt = 0; tt < 2; tt++) {
      f32x4 c = tt ? acc1 : acc0;
      int col = (nt0 + tt) * 16 + c15;
#pragma unroll
      for (int r = 0; r < 4; r++) {
        float v = c[r] + dirv[r] * sPB[64 + col] + sPB[col];
        v = fmaxf(v, 0.f) * maskv[r];
        sX[mt * 16 + quad * 4 + r][col] = f2b(v);
      }
    }
  }
  __syncthreads();

  // ---- gi via MFMA ----
  {
    const int mt = w >> 1;
    const int ntb = (w & 1) * 3;
    short8 a[2];
#pragma unroll
    for (int kb = 0; kb < 2; kb++)
      a[kb] = *(const short8*)&sX[mt * 16 + c15][kb * 32 + quad * 8];
#pragma unroll
    for (int d = 0; d < 2; d++) {
#pragma unroll
      for (int t2 = 0; t2 < 3; t2++) {
        int nt = ntb + t2;
        f32x4 acc = {0.f,0.f,0.f,0.f};
#pragma unroll
        for (int kb = 0; kb < 2; kb++) {
          short8 bb = *(const short8*)(fragIH + ((d * 12 + kb * 6 + nt) * 64 + lane) * 8);
          acc = __builtin_amdgcn_mfma_f32_16x16x32_bf16(a[kb], bb, acc, 0, 0, 0);
        }
        int col = nt * 16 + c15;
        float bi = sBI[d][col];
#pragma unroll
        for (int r = 0; r < 4; r++)
          sgi[d][mt * 16 + quad * 4 + r][col] = f2b(acc[r] + bi);
      }
    }
  }

  // ---- sequential GRU (gh): Whh from LDS ----
  {
    const int u = tid & 31;
    const int d = (tid >> 5) & 1;
    const int slg = tid >> 6;
    sH[d][slg][u] = 0.f; sH[d][slg + 4][u] = 0.f;
    __syncthreads();
    for (int step = 0; step < 4; step++) {
      const int k = d ? (3 - step) : step;
      float ghr0 = sBH[d][u],      ghr1 = ghr0;
      float ghz0 = sBH[d][32 + u], ghz1 = ghz0;
      float ghn0 = sBH[d][64 + u], ghn1 = ghn0;
      for (int i = 0; i < 32; i++) {
        float w0 = b2f_u(sWhh[d][i][u]);
        float w1 = b2f_u(sWhh[d][i][32 + u]);
        float w2 = b2f_u(sWhh[d][i][64 + u]);
        float ha = sH[d][slg][i], hb = sH[d][slg + 4][i];
        ghr0 += ha * w0; ghz0 += ha * w1; ghn0 += ha * w2;
        ghr1 += hb * w0; ghz1 += hb * w1; ghn1 += hb * w2;
      }
      float r0 = sigm(b2f_u(sgi[d][slg * 4 + k][u]) + ghr0);
      float z0 = sigm(b2f_u(sgi[d][slg * 4 + k][32 + u]) + ghz0);
      float n0 = tanhf(b2f_u(sgi[d][slg * 4 + k][64 + u]) + r0 * ghn0);
      float hn0 = (1.f - z0) * n0 + z0 * sH[d][slg][u];
      float r1 = sigm(b2f_u(sgi[d][(slg + 4) * 4 + k][u]) + ghr1);
      float z1 = sigm(b2f_u(sgi[d][(slg + 4) * 4 + k][32 + u]) + ghz1);
      float n1 = tanhf(b2f_u(sgi[d][(slg + 4) * 4 + k][64 + u]) + r1 * ghn1);
      float hn1 = (1.f - z1) * n1 + z1 * sH[d][slg + 4][u];
      __syncthreads();
      sH[d][slg][u] = hn0; sH[d][slg + 4][u] = hn1;
      __syncthreads();
    }
  }

  for (int i = tid; i < 8 * 128; i += 256) {
    int s = i >> 7, cc = i & 127;
    sCat[s][cc] = f2b(emb[(b8 + s) * 5 * 128 + cc]);
  }
  for (int i = tid; i < 512; i += 256) {
    int s = i >> 6, j = i & 63;
    float hv = (j < 32) ? sH[0][s][j] : sH[1][s][j - 32];
    sCat[s][128 + j] = f2b(hv);
  }
  __syncthreads();

  {
    const int nt = w;
    f32x4 acc = {0.f,0.f,0.f,0.f};
#pragma unroll
    for (int kb = 0; kb < 6; kb++) {
      short8 a = *(const short8*)&sCat[c15][kb * 32 + quad * 8];
      short8 bb = *(const short8*)(fragO + ((kb * 4 + nt) * 64 + lane) * 8);
      acc = __builtin_amdgcn_mfma_f32_16x16x32_bf16(a, bb, acc, 0, 0, 0);
    }
    if (quad < 2) {
      int col = nt * 16 + c15;
#pragma unroll
      for (int r = 0; r < 4; r++) {
        int m = quad * 4 + r;
        out[(b8 + m) * 192 + 128 + col] = fmaxf(acc[r] + sBO[col], 0.f);
      }
    }
  }
  for (int i = tid; i < 8 * 128; i += 256) {
    int s = i >> 7, cc = i & 127;
    out[(b8 + s) * 192 + cc] = emb[(b8 + s) * 5 * 128 + cc];
  }
}

// ---------------------------------------------------------------------------
extern "C" void kernel_launch(void* const* d_in, const int* in_sizes, int n_in,
                              void* d_out, int out_size, void* d_ws, size_t ws_size,
                              hipStream_t stream) {
  const float* self_f  = (const float*)d_in[0];
  const float* nbr_f   = (const float*)d_in[1];
  const float* maskp   = (const float*)d_in[2];
  const float* dirsp   = (const float*)d_in[3];
  const float* W_coop  = (const float*)d_in[4];
  const float* as_coop = (const float*)d_in[5];
  const float* ad_coop = (const float*)d_in[6];
  const float* W_conf  = (const float*)d_in[7];
  const float* as_conf = (const float*)d_in[8];
  const float* ad_conf = (const float*)d_in[9];
  const float* W_fuse  = (const float*)d_in[10];
  const float* b_fuse  = (const float*)d_in[11];
  const float* W_proj  = (const float*)d_in[12];
  const float* b_proj  = (const float*)d_in[13];
  const float* Wih_f   = (const float*)d_in[14];
  const float* Whh_f   = (const float*)d_in[15];
  const float* bih_f   = (const float*)d_in[16];
  const float* bhh_f   = (const float*)d_in[17];
  const float* Wih_b   = (const float*)d_in[18];
  const float* Whh_b   = (const float*)d_in[19];
  const float* bih_b   = (const float*)d_in[20];
  const float* bhh_b   = (const float*)d_in[21];
  const float* W_out   = (const float*)d_in[22];
  const float* b_out   = (const float*)d_in[23];

  const int B = in_sizes[0] / 48;   // 8192
  char* ws = (char*)d_ws;
  unsigned short* fragB  = (unsigned short*)(ws);            // 65536 B
  unsigned short* fragW  = (unsigned short*)(ws + 65536);    // 16384 B
  float*          Wa     = (float*)(ws + 81920);             // 256 B
  unsigned short* fragP  = (unsigned short*)(ws + 82176);    // 16384 B
  unsigned short* fragIH = (unsigned short*)(ws + 98560);    // 24576 B
  unsigned short* fragO  = (unsigned short*)(ws + 123136);   // 24576 B
  float*          emb    = (float*)(ws + 147712);            // B*5*128*4

  prepack_kernel<<<37, 256, 0, stream>>>(
      W_fuse, W_coop, W_conf, as_coop, ad_coop, as_conf, ad_conf,
      W_proj, Wih_f, Wih_b, W_out,
      fragB, fragW, Wa, fragP, fragIH, fragO);

  gat_fuse_kernel<<<B * 5 / 2, 256, 0, stream>>>(
      self_f, nbr_f, Wa, fragW, fragB, b_fuse, emb);

  head_kernel<<<B / 8, 256, 0, stream>>>(
      emb, maskp, dirsp, W_proj, b_proj, fragP, fragIH,
      bih_f, bhh_f, bih_b, bhh_b, Whh_f, Whh_b,
      fragO, b_out, (float*)d_out);
}

// Round 12
// 252.160 us; speedup vs baseline: 24.9820x; 1.1165x over previous
//
#include <hip/hip_runtime.h>
#include <math.h>

typedef short short8 __attribute__((ext_vector_type(8)));
typedef float f32x4  __attribute__((ext_vector_type(4)));
typedef unsigned short u16x4 __attribute__((ext_vector_type(4)));

__device__ __forceinline__ unsigned short f2b(float f) {
  union { float f; unsigned int u; } x; x.f = f;
  return (unsigned short)((x.u + 0x7FFFu + ((x.u >> 16) & 1u)) >> 16);
}
__device__ __forceinline__ float b2f_u(unsigned short u) {
  union { unsigned int u; float f; } x; x.u = ((unsigned int)u) << 16;
  return x.f;
}
__device__ __forceinline__ float sigm(float x) { return 1.f / (1.f + __expf(-x)); }

// ---------------------------------------------------------------------------
// Prepack. fragWB = block-diagonal GAT projection B-frags:
//   B[k][n] (K 16->32 pad, N=128): k=(h,f); value W[h][f][o] iff h==n>>5.
// ---------------------------------------------------------------------------
__global__ __launch_bounds__(256) void prepack_kernel(
    const float* __restrict__ Wf,
    const float* __restrict__ Wc, const float* __restrict__ Wn,
    const float* __restrict__ as_c, const float* __restrict__ ad_c,
    const float* __restrict__ as_n, const float* __restrict__ ad_n,
    const float* __restrict__ Wproj,
    const float* __restrict__ Wih_f, const float* __restrict__ Wih_b,
    const float* __restrict__ Wout,
    unsigned short* __restrict__ fragB,
    unsigned short* __restrict__ fragWB,
    float* __restrict__ Wa,
    unsigned short* __restrict__ fragP,
    unsigned short* __restrict__ fragIH,
    unsigned short* __restrict__ fragO)
{
  int e = blockIdx.x * 256 + threadIdx.x;
  unsigned short tmp[8];
  if (e < 4096) {
    int kb = e >> 9, tile = (e >> 6) & 7, lane = e & 63;
    int n = tile * 16 + (lane & 15);
    int kbase = kb * 32 + (lane >> 4) * 8;
#pragma unroll
    for (int j = 0; j < 8; j++) tmp[j] = f2b(Wf[(kbase + j) * 128 + n]);
    *(short8*)(fragB + e * 8) = *(short8*)tmp;
  } else if (e < 5120) {                       // block-diag proj B (per stream)
    int i = e - 4096;
    int s = i >> 9, tile = (i >> 6) & 7, lane = i & 63;
    int c15 = lane & 15, quad = lane >> 4;
    int n = tile * 16 + c15;                   // 0..127
    int h = n >> 5, o = n & 31;
    const float* W = s ? Wn : Wc;
#pragma unroll
    for (int j = 0; j < 8; j++) {
      int k = quad * 8 + j;                    // 0..31; (k>>2)==h implies k<16
      tmp[j] = ((k >> 2) == h) ? f2b(W[h * 128 + (k & 3) * 32 + o])
                               : (unsigned short)0;
    }
    *(short8*)(fragWB + i * 8) = *(short8*)tmp;
  } else if (e < 5184) {
    int i = e - 5120;
    int s = i >> 5, d = (i >> 4) & 1, h = (i >> 2) & 3, f = i & 3;
    const float* W = s ? Wn : Wc;
    const float* a = s ? (d ? ad_n : as_n) : (d ? ad_c : as_c);
    float acc = 0.f;
#pragma unroll
    for (int o = 0; o < 32; o++) acc += W[h * 128 + f * 32 + o] * a[h * 32 + o];
    Wa[i] = acc;
  } else if (e < 6208) {
    int i = e - 5184;
    int kb = i >> 8, nt = (i >> 6) & 3, lane = i & 63;
    int c15 = lane & 15, quad = lane >> 4;
#pragma unroll
    for (int j = 0; j < 8; j++)
      tmp[j] = f2b(Wproj[(kb * 32 + quad * 8 + j) * 64 + nt * 16 + c15]);
    *(short8*)(fragP + i * 8) = *(short8*)tmp;
  } else if (e < 7744) {
    int i = e - 6208;
    int d = (i >= 768), r = i - d * 768;
    int kb = r / 384, nt = (r >> 6) % 6, lane = r & 63;
    int c15 = lane & 15, quad = lane >> 4;
    const float* W = d ? Wih_b : Wih_f;
#pragma unroll
    for (int j = 0; j < 8; j++)
      tmp[j] = f2b(W[(kb * 32 + quad * 8 + j) * 96 + nt * 16 + c15]);
    *(short8*)(fragIH + i * 8) = *(short8*)tmp;
  } else if (e < 9280) {
    int r = e - 7744;
    int kb = r >> 8, nt = (r >> 6) & 3, lane = r & 63;
    int c15 = lane & 15, quad = lane >> 4;
#pragma unroll
    for (int j = 0; j < 8; j++)
      tmp[j] = f2b(Wout[(kb * 32 + quad * 8 + j) * 64 + nt * 16 + c15]);
    *(short8*)(fragO + r * 8) = *(short8*)tmp;
  }
}

// ---------------------------------------------------------------------------
// Kernel 1: GAT + fuse via att-before-projection rewrite.
// out = (att @ x) @ blockdiag(W): no Wh, no register transpose.
// 2 nodes per 256-thread block; LDS ~22 KB -> 7 blocks/CU.
// ---------------------------------------------------------------------------
__global__ __launch_bounds__(256) void gat_fuse_kernel(
    const float* __restrict__ self_f, const float* __restrict__ nbr_f,
    const float* __restrict__ Wa,
    const unsigned short* __restrict__ fragWB,
    const unsigned short* __restrict__ fragB,
    const float* __restrict__ b_fuse,
    float* __restrict__ emb)
{
  const int tid = threadIdx.x;
  const int w = tid >> 6, lane = tid & 63, c15 = lane & 15, quad = lane >> 4;
  const int n0 = blockIdx.x * 2;
  const int ws = w & 1;        // stream
  const int wn = w >> 1;       // node

  __shared__ __align__(16) float sxf[2][12][4];                 // 384 B (f32 x)
  __shared__ float sWa[64];
  __shared__ float sed[2][2][4][12];
  __shared__ __align__(16) unsigned short sA[2][2][16][24];     // x_agg A-frag
  __shared__ __align__(16) unsigned short scatb[2][16][268];
  __shared__ float sbias[128];

  // ---- phase 0: stage ----
  if (tid < 128) sbias[tid] = b_fuse[tid];
  if (tid < 64) sWa[tid] = Wa[tid];
  if (tid < 96) {
    int nd = tid / 48, f = tid - nd * 48;
    int nn = n0 + nd, b = nn / 5, slot = nn - b * 5;
    float v = (slot == 0) ? self_f[b * 48 + f]
                          : nbr_f[(b * 4 + slot - 1) * 48 + f];
    sxf[nd][f >> 2][f & 3] = v;
  }
  __syncthreads();

  // ---- phase 1: logits via Wa trick ----
  float es_local = 0.f;
  if (tid < 192) {
    int g = tid / 96, r = tid - g * 96;
    int s = r / 48, r2 = r - s * 48;
    int h = r2 / 12, l = r2 - h * 12;
    float ed = 0.f;
#pragma unroll
    for (int f = 0; f < 4; f++) {
      float xv = sxf[g][l][f];
      es_local += xv * sWa[s * 32 + h * 4 + f];
      ed       += xv * sWa[s * 32 + 16 + h * 4 + f];
    }
    sed[g][s][h][l] = ed;
  }
  __syncthreads();

  // ---- phase 2: masked softmax + x_agg (att stays f32) ----
  if (tid < 192) {
    int g = tid / 96, r = tid - g * 96;
    int s = r / 48, r2 = r - s * 48;
    int h = r2 / 12, i = r2 - h * 12;
    int blk = i / 3;
    float ev[12];
    float m = -1e30f;
#pragma unroll
    for (int j = 0; j < 12; j++) {
      bool allowed = (s == 0) ? ((j / 3) == blk) : ((j / 3) != blk);
      float e = es_local + sed[g][s][h][j];
      e = e > 0.f ? e : 0.2f * e;
      if (!allowed) e = -1e30f;
      ev[j] = e;
      m = fmaxf(m, e);
    }
    float sum = 0.f;
#pragma unroll
    for (int j = 0; j < 12; j++) {
      float a = (ev[j] > -1e29f) ? __expf(ev[j] - m) : 0.f;
      ev[j] = a;
      sum += a;
    }
    float inv = 1.f / sum;
    float xa0 = 0.f, xa1 = 0.f, xa2 = 0.f, xa3 = 0.f;
#pragma unroll
    for (int j = 0; j < 12; j++) {
      float aj = ev[j] * inv;
      f32x4 xj = *(const f32x4*)&sxf[g][j][0];
      xa0 += aj * xj[0]; xa1 += aj * xj[1];
      xa2 += aj * xj[2]; xa3 += aj * xj[3];
    }
    u16x4 pk = { f2b(xa0), f2b(xa1), f2b(xa2), f2b(xa3) };
    *(u16x4*)&sA[g][s][i][h * 4] = pk;    // row i, k = h*4+f
  }
  __syncthreads();

  // ---- phase 3: projection GEMM (block-diag W), ELU -> scatb ----
  {
    const short8 z8 = {0,0,0,0,0,0,0,0};
    short8 a = z8;
    if (quad < 2) a = *(const short8*)&sA[wn][ws][c15][quad * 8];
#pragma unroll
    for (int tile = 0; tile < 8; tile++) {
      short8 bw = *(const short8*)(fragWB + ((ws * 8 + tile) * 64 + lane) * 8);
      f32x4 c = {0.f, 0.f, 0.f, 0.f};
      c = __builtin_amdgcn_mfma_f32_16x16x32_bf16(a, bw, c, 0, 0, 0);
      if (quad < 3) {
        int co = ws * 128 + tile * 16 + c15;
#pragma unroll
        for (int r = 0; r < 4; r++) {
          float v = c[r];
          v = v > 0.f ? v : (__expf(v) - 1.f);
          scatb[wn][quad * 4 + r][co] = f2b(v);
        }
      }
    }
  }
  __syncthreads();

  // ---- phase 4: fuse GEMM; wave w covers N-tiles {2w,2w+1}, both nodes ----
  {
    f32x4 acc[2][2];
#pragma unroll
    for (int nd = 0; nd < 2; nd++)
#pragma unroll
      for (int tt = 0; tt < 2; tt++) acc[nd][tt] = (f32x4){0.f,0.f,0.f,0.f};
#pragma unroll
    for (int kb = 0; kb < 8; kb++) {
      short8 a0 = *(const short8*)&scatb[0][c15][kb * 32 + (quad << 3)];
      short8 a1 = *(const short8*)&scatb[1][c15][kb * 32 + (quad << 3)];
#pragma unroll
      for (int tt = 0; tt < 2; tt++) {
        short8 bw = *(const short8*)(fragB + ((kb * 8 + 2 * w + tt) * 64 + lane) * 8);
        acc[0][tt] = __builtin_amdgcn_mfma_f32_16x16x32_bf16(a0, bw, acc[0][tt], 0, 0, 0);
        acc[1][tt] = __builtin_amdgcn_mfma_f32_16x16x32_bf16(a1, bw, acc[1][tt], 0, 0, 0);
      }
    }
    float tot[2][2];
#pragma unroll
    for (int nd = 0; nd < 2; nd++) {
#pragma unroll
      for (int tt = 0; tt < 2; tt++) {
        float p = 0.f;
        if (quad < 3) {
          float bcol = sbias[w * 32 + tt * 16 + c15];
#pragma unroll
          for (int r = 0; r < 4; r++) {
            float v = acc[nd][tt][r] + bcol;
            v = v > 0.f ? v : (__expf(v) - 1.f);
            p += v;
          }
        }
        p += __shfl_xor(p, 16);
        p += __shfl_xor(p, 32);
        tot[nd][tt] = p;
      }
    }
    int ndw = quad >> 1, ttw = quad & 1;
    float val = ndw ? (ttw ? tot[1][1] : tot[1][0])
                    : (ttw ? tot[0][1] : tot[0][0]);
    emb[(n0 + ndw) * 128 + w * 32 + ttw * 16 + c15] = val * (1.f / 12.f);
  }
}

// ---------------------------------------------------------------------------
// Kernel 2: head (unchanged from round 11).
// ---------------------------------------------------------------------------
__global__ __launch_bounds__(256) void head_kernel(
    const float* __restrict__ emb,
    const float* __restrict__ maskp, const float* __restrict__ dirsp,
    const float* __restrict__ W_proj, const float* __restrict__ b_proj,
    const unsigned short* __restrict__ fragP,
    const unsigned short* __restrict__ fragIH,
    const float* __restrict__ bih_f, const float* __restrict__ bhh_f,
    const float* __restrict__ bih_b, const float* __restrict__ bhh_b,
    const float* __restrict__ Whh_f, const float* __restrict__ Whh_b,
    const unsigned short* __restrict__ fragO,
    const float* __restrict__ b_out,
    float* __restrict__ out)
{
  const int b8 = blockIdx.x * 8;
  const int tid = threadIdx.x;
  const int w = tid >> 6, lane = tid & 63, c15 = lane & 15, quad = lane >> 4;

  __shared__ __align__(16) unsigned short sX[32][72];
  __shared__ __align__(16) unsigned short sgi[2][32][96];
  __shared__ float sH[2][8][32];
  __shared__ __align__(16) unsigned short sCat[16][200];
  __shared__ unsigned short sWhh[2][32][96];
  __shared__ float sPB[128];
  __shared__ float sBI[2][96], sBH[2][96], sBO[64];

  if (tid < 64) { sPB[tid] = b_proj[tid]; sPB[64 + tid] = W_proj[128 * 64 + tid]; sBO[tid] = b_out[tid]; }
  if (tid < 96) { sBI[0][tid] = bih_f[tid]; sBI[1][tid] = bih_b[tid];
                  sBH[0][tid] = bhh_f[tid]; sBH[1][tid] = bhh_b[tid]; }
  for (int i = tid; i < 3072; i += 256) {
    sWhh[0][0][i] = f2b(Whh_f[i]);
    sWhh[1][0][i] = f2b(Whh_b[i]);
  }
  __syncthreads();

  {
    const int mt = w >> 1;
    const int nt0 = (w & 1) * 2;
    const int sloc = mt * 4 + (c15 >> 2);
    const int nbr  = c15 & 3;
    const float* arow = emb + (((b8 + sloc) * 5) + 1 + nbr) * 128;
    short8 a[4];
#pragma unroll
    for (int kb = 0; kb < 4; kb++) {
      const float* p = arow + kb * 32 + quad * 8;
      f32x4 v0 = *(const f32x4*)p;
      f32x4 v1 = *(const f32x4*)(p + 4);
      unsigned short tmp[8];
      tmp[0]=f2b(v0[0]); tmp[1]=f2b(v0[1]); tmp[2]=f2b(v0[2]); tmp[3]=f2b(v0[3]);
      tmp[4]=f2b(v1[0]); tmp[5]=f2b(v1[1]); tmp[6]=f2b(v1[2]); tmp[7]=f2b(v1[3]);
      a[kb] = *(short8*)tmp;
    }
    f32x4 acc0 = {0.f,0.f,0.f,0.f}, acc1 = acc0;
#pragma unroll
    for (int kb = 0; kb < 4; kb++) {
      short8 b0 = *(const short8*)(fragP + ((kb * 4 + nt0    ) * 64 + lane) * 8);
      short8 b1 = *(const short8*)(fragP + ((kb * 4 + nt0 + 1) * 64 + lane) * 8);
      acc0 = __builtin_amdgcn_mfma_f32_16x16x32_bf16(a[kb], b0, acc0, 0, 0, 0);
      acc1 = __builtin_amdgcn_mfma_f32_16x16x32_bf16(a[kb], b1, acc1, 0, 0, 0);
    }
    const int sE = mt * 4 + quad;
    float dirv[4], maskv[4];
#pragma unroll
    for (int r = 0; r < 4; r++) {
      dirv[r]  = dirsp[(b8 + sE) * 4 + r];
      maskv[r] = maskp[(b8 + sE) * 4 + r];
    }
#pragma unroll
    for (int tt = 0; tt < 2; tt++) {
      f32x4 c = tt ? acc1 : acc0;
      int col = (nt0 + tt) * 16 + c15;
#pragma unroll
      for (int r = 0; r < 4; r++) {
        float v = c[r] + dirv[r] * sPB[64 + col] + sPB[col];
        v = fmaxf(v, 0.f) * maskv[r];
        sX[mt * 16 + quad * 4 + r][col] = f2b(v);
      }
    }
  }
  __syncthreads();

  {
    const int mt = w >> 1;
    const int ntb = (w & 1) * 3;
    short8 a[2];
#pragma unroll
    for (int kb = 0; kb < 2; kb++)
      a[kb] = *(const short8*)&sX[mt * 16 + c15][kb * 32 + quad * 8];
#pragma unroll
    for (int d = 0; d < 2; d++) {
#pragma unroll
      for (int t2 = 0; t2 < 3; t2++) {
        int nt = ntb + t2;
        f32x4 acc = {0.f,0.f,0.f,0.f};
#pragma unroll
        for (int kb = 0; kb < 2; kb++) {
          short8 bb = *(const short8*)(fragIH + ((d * 12 + kb * 6 + nt) * 64 + lane) * 8);
          acc = __builtin_amdgcn_mfma_f32_16x16x32_bf16(a[kb], bb, acc, 0, 0, 0);
        }
        int col = nt * 16 + c15;
        float bi = sBI[d][col];
#pragma unroll
        for (int r = 0; r < 4; r++)
          sgi[d][mt * 16 + quad * 4 + r][col] = f2b(acc[r] + bi);
      }
    }
  }

  {
    const int u = tid & 31;
    const int d = (tid >> 5) & 1;
    const int slg = tid >> 6;
    sH[d][slg][u] = 0.f; sH[d][slg + 4][u] = 0.f;
    __syncthreads();
    for (int step = 0; step < 4; step++) {
      const int k = d ? (3 - step) : step;
      float ghr0 = sBH[d][u],      ghr1 = ghr0;
      float ghz0 = sBH[d][32 + u], ghz1 = ghz0;
      float ghn0 = sBH[d][64 + u], ghn1 = ghn0;
      for (int i = 0; i < 32; i++) {
        float w0 = b2f_u(sWhh[d][i][u]);
        float w1 = b2f_u(sWhh[d][i][32 + u]);
        float w2 = b2f_u(sWhh[d][i][64 + u]);
        float ha = sH[d][slg][i], hb = sH[d][slg + 4][i];
        ghr0 += ha * w0; ghz0 += ha * w1; ghn0 += ha * w2;
        ghr1 += hb * w0; ghz1 += hb * w1; ghn1 += hb * w2;
      }
      float r0 = sigm(b2f_u(sgi[d][slg * 4 + k][u]) + ghr0);
      float z0 = sigm(b2f_u(sgi[d][slg * 4 + k][32 + u]) + ghz0);
      float n0 = tanhf(b2f_u(sgi[d][slg * 4 + k][64 + u]) + r0 * ghn0);
      float hn0 = (1.f - z0) * n0 + z0 * sH[d][slg][u];
      float r1 = sigm(b2f_u(sgi[d][(slg + 4) * 4 + k][u]) + ghr1);
      float z1 = sigm(b2f_u(sgi[d][(slg + 4) * 4 + k][32 + u]) + ghz1);
      float n1 = tanhf(b2f_u(sgi[d][(slg + 4) * 4 + k][64 + u]) + r1 * ghn1);
      float hn1 = (1.f - z1) * n1 + z1 * sH[d][slg + 4][u];
      __syncthreads();
      sH[d][slg][u] = hn0; sH[d][slg + 4][u] = hn1;
      __syncthreads();
    }
  }

  for (int i = tid; i < 8 * 128; i += 256) {
    int s = i >> 7, cc = i & 127;
    sCat[s][cc] = f2b(emb[(b8 + s) * 5 * 128 + cc]);
  }
  for (int i = tid; i < 512; i += 256) {
    int s = i >> 6, j = i & 63;
    float hv = (j < 32) ? sH[0][s][j] : sH[1][s][j - 32];
    sCat[s][128 + j] = f2b(hv);
  }
  __syncthreads();

  {
    const int nt = w;
    f32x4 acc = {0.f,0.f,0.f,0.f};
#pragma unroll
    for (int kb = 0; kb < 6; kb++) {
      short8 a = *(const short8*)&sCat[c15][kb * 32 + quad * 8];
      short8 bb = *(const short8*)(fragO + ((kb * 4 + nt) * 64 + lane) * 8);
      acc = __builtin_amdgcn_mfma_f32_16x16x32_bf16(a, bb, acc, 0, 0, 0);
    }
    if (quad < 2) {
      int col = nt * 16 + c15;
#pragma unroll
      for (int r = 0; r < 4; r++) {
        int m = quad * 4 + r;
        out[(b8 + m) * 192 + 128 + col] = fmaxf(acc[r] + sBO[col], 0.f);
      }
    }
  }
  for (int i = tid; i < 8 * 128; i += 256) {
    int s = i >> 7, cc = i & 127;
    out[(b8 + s) * 192 + cc] = emb[(b8 + s) * 5 * 128 + cc];
  }
}

// ---------------------------------------------------------------------------
extern "C" void kernel_launch(void* const* d_in, const int* in_sizes, int n_in,
                              void* d_out, int out_size, void* d_ws, size_t ws_size,
                              hipStream_t stream) {
  const float* self_f  = (const float*)d_in[0];
  const float* nbr_f   = (const float*)d_in[1];
  const float* maskp   = (const float*)d_in[2];
  const float* dirsp   = (const float*)d_in[3];
  const float* W_coop  = (const float*)d_in[4];
  const float* as_coop = (const float*)d_in[5];
  const float* ad_coop = (const float*)d_in[6];
  const float* W_conf  = (const float*)d_in[7];
  const float* as_conf = (const float*)d_in[8];
  const float* ad_conf = (const float*)d_in[9];
  const float* W_fuse  = (const float*)d_in[10];
  const float* b_fuse  = (const float*)d_in[11];
  const float* W_proj  = (const float*)d_in[12];
  const float* b_proj  = (const float*)d_in[13];
  const float* Wih_f   = (const float*)d_in[14];
  const float* Whh_f   = (const float*)d_in[15];
  const float* bih_f   = (const float*)d_in[16];
  const float* bhh_f   = (const float*)d_in[17];
  const float* Wih_b   = (const float*)d_in[18];
  const float* Whh_b   = (const float*)d_in[19];
  const float* bih_b   = (const float*)d_in[20];
  const float* bhh_b   = (const float*)d_in[21];
  const float* W_out   = (const float*)d_in[22];
  const float* b_out   = (const float*)d_in[23];

  const int B = in_sizes[0] / 48;   // 8192
  char* ws = (char*)d_ws;
  unsigned short* fragB  = (unsigned short*)(ws);            // 65536 B
  unsigned short* fragWB = (unsigned short*)(ws + 65536);    // 16384 B
  float*          Wa     = (float*)(ws + 81920);             // 256 B
  unsigned short* fragP  = (unsigned short*)(ws + 82176);    // 16384 B
  unsigned short* fragIH = (unsigned short*)(ws + 98560);    // 24576 B
  unsigned short* fragO  = (unsigned short*)(ws + 123136);   // 24576 B
  float*          emb    = (float*)(ws + 147712);            // B*5*128*4

  prepack_kernel<<<37, 256, 0, stream>>>(
      W_fuse, W_coop, W_conf, as_coop, ad_coop, as_conf, ad_conf,
      W_proj, Wih_f, Wih_b, W_out,
      fragB, fragWB, Wa, fragP, fragIH, fragO);

  gat_fuse_kernel<<<B * 5 / 2, 256, 0, stream>>>(
      self_f, nbr_f, Wa, fragWB, fragB, b_fuse, emb);

  head_kernel<<<B / 8, 256, 0, stream>>>(
      emb, maskp, dirsp, W_proj, b_proj, fragP, fragIH,
      bih_f, bhh_f, bih_b, bhh_b, Whh_f, Whh_b,
      fragO, b_out, (float*)d_out);
}

// Round 14
// 239.283 us; speedup vs baseline: 26.3264x; 1.0538x over previous
//
#include <hip/hip_runtime.h>
#include <math.h>

typedef short short8 __attribute__((ext_vector_type(8)));
typedef float f32x4  __attribute__((ext_vector_type(4)));
typedef unsigned short u16x4 __attribute__((ext_vector_type(4)));

__device__ __forceinline__ unsigned short f2b(float f) {
  union { float f; unsigned int u; } x; x.f = f;
  return (unsigned short)((x.u + 0x7FFFu + ((x.u >> 16) & 1u)) >> 16);
}
__device__ __forceinline__ float b2f_u(unsigned short u) {
  union { unsigned int u; float f; } x; x.u = ((unsigned int)u) << 16;
  return x.f;
}
__device__ __forceinline__ float sigm(float x) { return 1.f / (1.f + __expf(-x)); }

// ---------------------------------------------------------------------------
// Prepack. fragWB = block-diag GAT projection; fragHH = GRU Whh B-frags.
// ---------------------------------------------------------------------------
__global__ __launch_bounds__(256) void prepack_kernel(
    const float* __restrict__ Wf,
    const float* __restrict__ Wc, const float* __restrict__ Wn,
    const float* __restrict__ as_c, const float* __restrict__ ad_c,
    const float* __restrict__ as_n, const float* __restrict__ ad_n,
    const float* __restrict__ Wproj,
    const float* __restrict__ Wih_f, const float* __restrict__ Wih_b,
    const float* __restrict__ Wout,
    const float* __restrict__ Whh_f, const float* __restrict__ Whh_b,
    unsigned short* __restrict__ fragB,
    unsigned short* __restrict__ fragWB,
    float* __restrict__ Wa,
    unsigned short* __restrict__ fragP,
    unsigned short* __restrict__ fragIH,
    unsigned short* __restrict__ fragO,
    unsigned short* __restrict__ fragHH)
{
  int e = blockIdx.x * 256 + threadIdx.x;
  unsigned short tmp[8];
  if (e < 4096) {
    int kb = e >> 9, tile = (e >> 6) & 7, lane = e & 63;
    int n = tile * 16 + (lane & 15);
    int kbase = kb * 32 + (lane >> 4) * 8;
#pragma unroll
    for (int j = 0; j < 8; j++) tmp[j] = f2b(Wf[(kbase + j) * 128 + n]);
    *(short8*)(fragB + e * 8) = *(short8*)tmp;
  } else if (e < 5120) {
    int i = e - 4096;
    int s = i >> 9, tile = (i >> 6) & 7, lane = i & 63;
    int c15 = lane & 15, quad = lane >> 4;
    int n = tile * 16 + c15;
    int h = n >> 5, o = n & 31;
    const float* W = s ? Wn : Wc;
#pragma unroll
    for (int j = 0; j < 8; j++) {
      int k = quad * 8 + j;
      tmp[j] = ((k >> 2) == h) ? f2b(W[h * 128 + (k & 3) * 32 + o])
                               : (unsigned short)0;
    }
    *(short8*)(fragWB + i * 8) = *(short8*)tmp;
  } else if (e < 5184) {
    int i = e - 5120;
    int s = i >> 5, d = (i >> 4) & 1, h = (i >> 2) & 3, f = i & 3;
    const float* W = s ? Wn : Wc;
    const float* a = s ? (d ? ad_n : as_n) : (d ? ad_c : as_c);
    float acc = 0.f;
#pragma unroll
    for (int o = 0; o < 32; o++) acc += W[h * 128 + f * 32 + o] * a[h * 32 + o];
    Wa[i] = acc;
  } else if (e < 6208) {
    int i = e - 5184;
    int kb = i >> 8, nt = (i >> 6) & 3, lane = i & 63;
    int c15 = lane & 15, quad = lane >> 4;
#pragma unroll
    for (int j = 0; j < 8; j++)
      tmp[j] = f2b(Wproj[(kb * 32 + quad * 8 + j) * 64 + nt * 16 + c15]);
    *(short8*)(fragP + i * 8) = *(short8*)tmp;
  } else if (e < 7744) {
    int i = e - 6208;
    int d = (i >= 768), r = i - d * 768;
    int kb = r / 384, nt = (r >> 6) % 6, lane = r & 63;
    int c15 = lane & 15, quad = lane >> 4;
    const float* W = d ? Wih_b : Wih_f;
#pragma unroll
    for (int j = 0; j < 8; j++)
      tmp[j] = f2b(W[(kb * 32 + quad * 8 + j) * 96 + nt * 16 + c15]);
    *(short8*)(fragIH + i * 8) = *(short8*)tmp;
  } else if (e < 9280) {
    int r = e - 7744;
    int kb = r >> 8, nt = (r >> 6) & 3, lane = r & 63;
    int c15 = lane & 15, quad = lane >> 4;
#pragma unroll
    for (int j = 0; j < 8; j++)
      tmp[j] = f2b(Wout[(kb * 32 + quad * 8 + j) * 64 + nt * 16 + c15]);
    *(short8*)(fragO + r * 8) = *(short8*)tmp;
  } else if (e < 10048) {                     // Whh B-frags (K=32, N=96) x2 dirs
    int i = e - 9280;
    int d = i / 384, r = i - d * 384;
    int nt = r >> 6, lane = r & 63;
    int c15 = lane & 15, quad = lane >> 4;
    const float* W = d ? Whh_b : Whh_f;
#pragma unroll
    for (int j = 0; j < 8; j++)
      tmp[j] = f2b(W[(quad * 8 + j) * 96 + nt * 16 + c15]);
    *(short8*)(fragHH + i * 8) = *(short8*)tmp;
  }
}

// ---------------------------------------------------------------------------
// Kernel 1: GAT + fuse (unchanged from round 12 — 132 µs, 71% occupancy).
// ---------------------------------------------------------------------------
__global__ __launch_bounds__(256) void gat_fuse_kernel(
    const float* __restrict__ self_f, const float* __restrict__ nbr_f,
    const float* __restrict__ Wa,
    const unsigned short* __restrict__ fragWB,
    const unsigned short* __restrict__ fragB,
    const float* __restrict__ b_fuse,
    float* __restrict__ emb)
{
  const int tid = threadIdx.x;
  const int w = tid >> 6, lane = tid & 63, c15 = lane & 15, quad = lane >> 4;
  const int n0 = blockIdx.x * 2;
  const int ws = w & 1;
  const int wn = w >> 1;

  __shared__ __align__(16) float sxf[2][12][4];
  __shared__ float sWa[64];
  __shared__ float sed[2][2][4][12];
  __shared__ __align__(16) unsigned short sA[2][2][16][24];
  __shared__ __align__(16) unsigned short scatb[2][16][268];
  __shared__ float sbias[128];

  if (tid < 128) sbias[tid] = b_fuse[tid];
  if (tid < 64) sWa[tid] = Wa[tid];
  if (tid < 96) {
    int nd = tid / 48, f = tid - nd * 48;
    int nn = n0 + nd, b = nn / 5, slot = nn - b * 5;
    float v = (slot == 0) ? self_f[b * 48 + f]
                          : nbr_f[(b * 4 + slot - 1) * 48 + f];
    sxf[nd][f >> 2][f & 3] = v;
  }
  __syncthreads();

  float es_local = 0.f;
  if (tid < 192) {
    int g = tid / 96, r = tid - g * 96;
    int s = r / 48, r2 = r - s * 48;
    int h = r2 / 12, l = r2 - h * 12;
    float ed = 0.f;
#pragma unroll
    for (int f = 0; f < 4; f++) {
      float xv = sxf[g][l][f];
      es_local += xv * sWa[s * 32 + h * 4 + f];
      ed       += xv * sWa[s * 32 + 16 + h * 4 + f];
    }
    sed[g][s][h][l] = ed;
  }
  __syncthreads();

  if (tid < 192) {
    int g = tid / 96, r = tid - g * 96;
    int s = r / 48, r2 = r - s * 48;
    int h = r2 / 12, i = r2 - h * 12;
    int blk = i / 3;
    float ev[12];
    float m = -1e30f;
#pragma unroll
    for (int j = 0; j < 12; j++) {
      bool allowed = (s == 0) ? ((j / 3) == blk) : ((j / 3) != blk);
      float e = es_local + sed[g][s][h][j];
      e = e > 0.f ? e : 0.2f * e;
      if (!allowed) e = -1e30f;
      ev[j] = e;
      m = fmaxf(m, e);
    }
    float sum = 0.f;
#pragma unroll
    for (int j = 0; j < 12; j++) {
      float a = (ev[j] > -1e29f) ? __expf(ev[j] - m) : 0.f;
      ev[j] = a;
      sum += a;
    }
    float inv = 1.f / sum;
    float xa0 = 0.f, xa1 = 0.f, xa2 = 0.f, xa3 = 0.f;
#pragma unroll
    for (int j = 0; j < 12; j++) {
      float aj = ev[j] * inv;
      f32x4 xj = *(const f32x4*)&sxf[g][j][0];
      xa0 += aj * xj[0]; xa1 += aj * xj[1];
      xa2 += aj * xj[2]; xa3 += aj * xj[3];
    }
    u16x4 pk = { f2b(xa0), f2b(xa1), f2b(xa2), f2b(xa3) };
    *(u16x4*)&sA[g][s][i][h * 4] = pk;
  }
  __syncthreads();

  {
    const short8 z8 = {0,0,0,0,0,0,0,0};
    short8 a = z8;
    if (quad < 2) a = *(const short8*)&sA[wn][ws][c15][quad * 8];
#pragma unroll
    for (int tile = 0; tile < 8; tile++) {
      short8 bw = *(const short8*)(fragWB + ((ws * 8 + tile) * 64 + lane) * 8);
      f32x4 c = {0.f, 0.f, 0.f, 0.f};
      c = __builtin_amdgcn_mfma_f32_16x16x32_bf16(a, bw, c, 0, 0, 0);
      if (quad < 3) {
        int co = ws * 128 + tile * 16 + c15;
#pragma unroll
        for (int r = 0; r < 4; r++) {
          float v = c[r];
          v = v > 0.f ? v : (__expf(v) - 1.f);
          scatb[wn][quad * 4 + r][co] = f2b(v);
        }
      }
    }
  }
  __syncthreads();

  {
    f32x4 acc[2][2];
#pragma unroll
    for (int nd = 0; nd < 2; nd++)
#pragma unroll
      for (int tt = 0; tt < 2; tt++) acc[nd][tt] = (f32x4){0.f,0.f,0.f,0.f};
#pragma unroll
    for (int kb = 0; kb < 8; kb++) {
      short8 a0 = *(const short8*)&scatb[0][c15][kb * 32 + (quad << 3)];
      short8 a1 = *(const short8*)&scatb[1][c15][kb * 32 + (quad << 3)];
#pragma unroll
      for (int tt = 0; tt < 2; tt++) {
        short8 bw = *(const short8*)(fragB + ((kb * 8 + 2 * w + tt) * 64 + lane) * 8);
        acc[0][tt] = __builtin_amdgcn_mfma_f32_16x16x32_bf16(a0, bw, acc[0][tt], 0, 0, 0);
        acc[1][tt] = __builtin_amdgcn_mfma_f32_16x16x32_bf16(a1, bw, acc[1][tt], 0, 0, 0);
      }
    }
    float tot[2][2];
#pragma unroll
    for (int nd = 0; nd < 2; nd++) {
#pragma unroll
      for (int tt = 0; tt < 2; tt++) {
        float p = 0.f;
        if (quad < 3) {
          float bcol = sbias[w * 32 + tt * 16 + c15];
#pragma unroll
          for (int r = 0; r < 4; r++) {
            float v = acc[nd][tt][r] + bcol;
            v = v > 0.f ? v : (__expf(v) - 1.f);
            p += v;
          }
        }
        p += __shfl_xor(p, 16);
        p += __shfl_xor(p, 32);
        tot[nd][tt] = p;
      }
    }
    int ndw = quad >> 1, ttw = quad & 1;
    float val = ndw ? (ttw ? tot[1][1] : tot[1][0])
                    : (ttw ? tot[0][1] : tot[0][0]);
    emb[(n0 + ndw) * 128 + w * 32 + ttw * 16 + c15] = val * (1.f / 12.f);
  }
}

// ---------------------------------------------------------------------------
// Kernel 2: head; GRU recurrence matmul on MFMA (fragHH), state h kept f32.
// FIX vs round 13: zero ALL 512 dwords of sHb (both directions), not 256.
// ---------------------------------------------------------------------------
__global__ __launch_bounds__(256) void head_kernel(
    const float* __restrict__ emb,
    const float* __restrict__ maskp, const float* __restrict__ dirsp,
    const float* __restrict__ W_proj, const float* __restrict__ b_proj,
    const unsigned short* __restrict__ fragP,
    const unsigned short* __restrict__ fragIH,
    const unsigned short* __restrict__ fragHH,
    const float* __restrict__ bih_f, const float* __restrict__ bhh_f,
    const float* __restrict__ bih_b, const float* __restrict__ bhh_b,
    const unsigned short* __restrict__ fragO,
    const float* __restrict__ b_out,
    float* __restrict__ out)
{
  const int b8 = blockIdx.x * 8;
  const int tid = threadIdx.x;
  const int w = tid >> 6, lane = tid & 63, c15 = lane & 15, quad = lane >> 4;

  __shared__ __align__(16) unsigned short sX[32][72];      // 4608 B
  __shared__ __align__(16) unsigned short sgi[2][32][96];  // 12288 B
  __shared__ float sH[2][8][32];                           // 2048 B  (f32 state)
  __shared__ __align__(16) unsigned short sHb[2][16][32];  // 2048 B  (bf16 A-frag)
  __shared__ float sgh[2][8][96];                          // 6144 B
  __shared__ __align__(16) unsigned short sCat[16][200];   // 6400 B
  __shared__ float sPB[128];
  __shared__ float sBI[2][96], sBH[2][96], sBO[64];

  if (tid < 64) { sPB[tid] = b_proj[tid]; sPB[64 + tid] = W_proj[128 * 64 + tid]; sBO[tid] = b_out[tid]; }
  if (tid < 96) { sBI[0][tid] = bih_f[tid]; sBI[1][tid] = bih_b[tid];
                  sBH[0][tid] = bhh_f[tid]; sBH[1][tid] = bhh_b[tid]; }
  // zero H state: sHb is 2*16*32 u16 = 512 dwords (round-13 bug: only 256 zeroed)
  {
    unsigned int* hb = (unsigned int*)sHb;
    hb[tid] = 0u; hb[tid + 256] = 0u;
    float* hz = (float*)sH;
    for (int i = tid; i < 512; i += 256) hz[i] = 0.f;
  }
  __syncthreads();

  // ---- proj via MFMA ----
  {
    const int mt = w >> 1;
    const int nt0 = (w & 1) * 2;
    const int sloc = mt * 4 + (c15 >> 2);
    const int nbr  = c15 & 3;
    const float* arow = emb + (((b8 + sloc) * 5) + 1 + nbr) * 128;
    short8 a[4];
#pragma unroll
    for (int kb = 0; kb < 4; kb++) {
      const float* p = arow + kb * 32 + quad * 8;
      f32x4 v0 = *(const f32x4*)p;
      f32x4 v1 = *(const f32x4*)(p + 4);
      unsigned short tmp[8];
      tmp[0]=f2b(v0[0]); tmp[1]=f2b(v0[1]); tmp[2]=f2b(v0[2]); tmp[3]=f2b(v0[3]);
      tmp[4]=f2b(v1[0]); tmp[5]=f2b(v1[1]); tmp[6]=f2b(v1[2]); tmp[7]=f2b(v1[3]);
      a[kb] = *(short8*)tmp;
    }
    f32x4 acc0 = {0.f,0.f,0.f,0.f}, acc1 = acc0;
#pragma unroll
    for (int kb = 0; kb < 4; kb++) {
      short8 b0 = *(const short8*)(fragP + ((kb * 4 + nt0    ) * 64 + lane) * 8);
      short8 b1 = *(const short8*)(fragP + ((kb * 4 + nt0 + 1) * 64 + lane) * 8);
      acc0 = __builtin_amdgcn_mfma_f32_16x16x32_bf16(a[kb], b0, acc0, 0, 0, 0);
      acc1 = __builtin_amdgcn_mfma_f32_16x16x32_bf16(a[kb], b1, acc1, 0, 0, 0);
    }
    const int sE = mt * 4 + quad;
    float dirv[4], maskv[4];
#pragma unroll
    for (int r = 0; r < 4; r++) {
      dirv[r]  = dirsp[(b8 + sE) * 4 + r];
      maskv[r] = maskp[(b8 + sE) * 4 + r];
    }
#pragma unroll
    for (int tt = 0; tt < 2; tt++) {
      f32x4 c = tt ? acc1 : acc0;
      int col = (nt0 + tt) * 16 + c15;
#pragma unroll
      for (int r = 0; r < 4; r++) {
        float v = c[r] + dirv[r] * sPB[64 + col] + sPB[col];
        v = fmaxf(v, 0.f) * maskv[r];
        sX[mt * 16 + quad * 4 + r][col] = f2b(v);
      }
    }
  }
  __syncthreads();

  // ---- gi via MFMA ----
  {
    const int mt = w >> 1;
    const int ntb = (w & 1) * 3;
    short8 a[2];
#pragma unroll
    for (int kb = 0; kb < 2; kb++)
      a[kb] = *(const short8*)&sX[mt * 16 + c15][kb * 32 + quad * 8];
#pragma unroll
    for (int d = 0; d < 2; d++) {
#pragma unroll
      for (int t2 = 0; t2 < 3; t2++) {
        int nt = ntb + t2;
        f32x4 acc = {0.f,0.f,0.f,0.f};
#pragma unroll
        for (int kb = 0; kb < 2; kb++) {
          short8 bb = *(const short8*)(fragIH + ((d * 12 + kb * 6 + nt) * 64 + lane) * 8);
          acc = __builtin_amdgcn_mfma_f32_16x16x32_bf16(a[kb], bb, acc, 0, 0, 0);
        }
        int col = nt * 16 + c15;
        float bi = sBI[d][col];
#pragma unroll
        for (int r = 0; r < 4; r++)
          sgi[d][mt * 16 + quad * 4 + r][col] = f2b(acc[r] + bi);
      }
    }
  }
  __syncthreads();

  // ---- sequential GRU via MFMA: gh = H @ Whh per step/dir ----
  {
    const int d_mfma = w >> 1;            // wave's direction
    const int nt0 = (w & 1) * 3;          // 3 N-tiles of 16
    const int u = tid & 31;               // update item: (s,u) both dirs
    const int s = (tid >> 5) & 7;
    const int grow = s * 4;               // sgi row base for sample s
    for (int step = 0; step < 4; step++) {
      short8 a = *(const short8*)&sHb[d_mfma][c15][quad * 8];
#pragma unroll
      for (int t2 = 0; t2 < 3; t2++) {
        short8 bb = *(const short8*)(fragHH + ((d_mfma * 6 + nt0 + t2) * 64 + lane) * 8);
        f32x4 c = {0.f,0.f,0.f,0.f};
        c = __builtin_amdgcn_mfma_f32_16x16x32_bf16(a, bb, c, 0, 0, 0);
        if (quad < 2) {
          int col = (nt0 + t2) * 16 + c15;
#pragma unroll
          for (int r = 0; r < 4; r++)
            sgh[d_mfma][quad * 4 + r][col] = c[r];
        }
      }
      __syncthreads();
#pragma unroll
      for (int d = 0; d < 2; d++) {
        int k = d ? (3 - step) : step;
        int row = grow + k;
        float ghr = sgh[d][s][u]      + sBH[d][u];
        float ghz = sgh[d][s][32 + u] + sBH[d][32 + u];
        float ghn = sgh[d][s][64 + u] + sBH[d][64 + u];
        float r = sigm(b2f_u(sgi[d][row][u]) + ghr);
        float z = sigm(b2f_u(sgi[d][row][32 + u]) + ghz);
        float n = tanhf(b2f_u(sgi[d][row][64 + u]) + r * ghn);
        float h = (1.f - z) * n + z * sH[d][s][u];
        sH[d][s][u] = h;
        sHb[d][s][u] = f2b(h);
      }
      __syncthreads();
    }
  }

  // ---- build sCat = [self_emb | h_f | h_b] ----
  for (int i = tid; i < 8 * 128; i += 256) {
    int s = i >> 7, cc = i & 127;
    sCat[s][cc] = f2b(emb[(b8 + s) * 5 * 128 + cc]);
  }
  for (int i = tid; i < 512; i += 256) {
    int s = i >> 6, j = i & 63;
    float hv = (j < 32) ? sH[0][s][j] : sH[1][s][j - 32];
    sCat[s][128 + j] = f2b(hv);
  }
  __syncthreads();

  // ---- out head via MFMA ----
  {
    const int nt = w;
    f32x4 acc = {0.f,0.f,0.f,0.f};
#pragma unroll
    for (int kb = 0; kb < 6; kb++) {
      short8 a = *(const short8*)&sCat[c15][kb * 32 + quad * 8];
      short8 bb = *(const short8*)(fragO + ((kb * 4 + nt) * 64 + lane) * 8);
      acc = __builtin_amdgcn_mfma_f32_16x16x32_bf16(a, bb, acc, 0, 0, 0);
    }
    if (quad < 2) {
      int col = nt * 16 + c15;
#pragma unroll
      for (int r = 0; r < 4; r++) {
        int m = quad * 4 + r;
        out[(b8 + m) * 192 + 128 + col] = fmaxf(acc[r] + sBO[col], 0.f);
      }
    }
  }
  for (int i = tid; i < 8 * 128; i += 256) {
    int s = i >> 7, cc = i & 127;
    out[(b8 + s) * 192 + cc] = emb[(b8 + s) * 5 * 128 + cc];
  }
}

// ---------------------------------------------------------------------------
extern "C" void kernel_launch(void* const* d_in, const int* in_sizes, int n_in,
                              void* d_out, int out_size, void* d_ws, size_t ws_size,
                              hipStream_t stream) {
  const float* self_f  = (const float*)d_in[0];
  const float* nbr_f   = (const float*)d_in[1];
  const float* maskp   = (const float*)d_in[2];
  const float* dirsp   = (const float*)d_in[3];
  const float* W_coop  = (const float*)d_in[4];
  const float* as_coop = (const float*)d_in[5];
  const float* ad_coop = (const float*)d_in[6];
  const float* W_conf  = (const float*)d_in[7];
  const float* as_conf = (const float*)d_in[8];
  const float* ad_conf = (const float*)d_in[9];
  const float* W_fuse  = (const float*)d_in[10];
  const float* b_fuse  = (const float*)d_in[11];
  const float* W_proj  = (const float*)d_in[12];
  const float* b_proj  = (const float*)d_in[13];
  const float* Wih_f   = (const float*)d_in[14];
  const float* Whh_f   = (const float*)d_in[15];
  const float* bih_f   = (const float*)d_in[16];
  const float* bhh_f   = (const float*)d_in[17];
  const float* Wih_b   = (const float*)d_in[18];
  const float* Whh_b   = (const float*)d_in[19];
  const float* bih_b   = (const float*)d_in[20];
  const float* bhh_b   = (const float*)d_in[21];
  const float* W_out   = (const float*)d_in[22];
  const float* b_out   = (const float*)d_in[23];

  const int B = in_sizes[0] / 48;   // 8192
  char* ws = (char*)d_ws;
  unsigned short* fragB  = (unsigned short*)(ws);            // 65536 B
  unsigned short* fragWB = (unsigned short*)(ws + 65536);    // 16384 B
  float*          Wa     = (float*)(ws + 81920);             // 256 B
  unsigned short* fragP  = (unsigned short*)(ws + 82176);    // 16384 B
  unsigned short* fragIH = (unsigned short*)(ws + 98560);    // 24576 B
  unsigned short* fragO  = (unsigned short*)(ws + 123136);   // 24576 B
  unsigned short* fragHH = (unsigned short*)(ws + 147712);   // 12288 B
  float*          emb    = (float*)(ws + 160000);            // B*5*128*4

  prepack_kernel<<<40, 256, 0, stream>>>(
      W_fuse, W_coop, W_conf, as_coop, ad_coop, as_conf, ad_conf,
      W_proj, Wih_f, Wih_b, W_out, Whh_f, Whh_b,
      fragB, fragWB, Wa, fragP, fragIH, fragO, fragHH);

  gat_fuse_kernel<<<B * 5 / 2, 256, 0, stream>>>(
      self_f, nbr_f, Wa, fragWB, fragB, b_fuse, emb);

  head_kernel<<<B / 8, 256, 0, stream>>>(
      emb, maskp, dirsp, W_proj, b_proj, fragP, fragIH, fragHH,
      bih_f, bhh_f, bih_b, bhh_b,
      fragO, b_out, (float*)d_out);
}